// Round 1
// baseline (5730.429 us; speedup 1.0000x reference)
//
#include <hip/hip_runtime.h>
#include <math.h>

// FEGCL_46127948759594 — E(3)-equivariant GCL on MI355X.
// N=50000 nodes, E=800000 edges, INF=ONF=64, HNF=128, ein=136.
// Strategy: fused edge kernel (64 edges/block, bf16 MFMA 16x16x32, weights
// pre-swizzled to fragment layout), f32 atomic segment sums, node kernel.

#define N_NODES 50000
#define N_EDGES 800000

typedef __attribute__((ext_vector_type(4))) float f32x4;
typedef __attribute__((ext_vector_type(8))) short bf16x8;
typedef __attribute__((ext_vector_type(4))) unsigned short u16x4;
typedef __attribute__((ext_vector_type(8))) unsigned short u16x8;

static __device__ __forceinline__ unsigned short f2bf(float f) {
  unsigned int u = __builtin_bit_cast(unsigned int, f);
  u += 0x7fffu + ((u >> 16) & 1u);   // round-to-nearest-even
  return (unsigned short)(u >> 16);
}
static __device__ __forceinline__ float bf2f(unsigned short s) {
  unsigned int u = ((unsigned int)s) << 16;
  return __builtin_bit_cast(float, u);
}
static __device__ __forceinline__ float silu_f(float x) {
  return x / (1.0f + __expf(-x));
}

// ---------------------------------------------------------------- prep ----
__global__ void qinv_kernel(const float* __restrict__ quat, float* __restrict__ qi) {
  int n = blockIdx.x * blockDim.x + threadIdx.x;
  if (n >= N_NODES) return;
  float x = quat[n*4+0], y = quat[n*4+1], z = quat[n*4+2], w = quat[n*4+3];
  float inv = 1.0f / (x*x + y*y + z*z + w*w);
  qi[n*4+0] = -x*inv; qi[n*4+1] = -y*inv; qi[n*4+2] = -z*inv; qi[n*4+3] = w*inv;
}

// Swizzle a row-major [K][NOUT] f32 weight into MFMA-fragment-ordered bf16:
// block (kt,ct): 64 lanes x 8 bf16, lane l holds W[kt*32+(l>>4)*8+j][ct*16+(l&15)].
__global__ void swz_kernel(const float* __restrict__ src, unsigned short* __restrict__ dst,
                           int K, int NOUT, int KT, int NCT) {
  int idx = blockIdx.x * blockDim.x + threadIdx.x;
  if (idx >= KT * NCT * 64) return;
  int lane = idx & 63, blk = idx >> 6;
  int ct = blk % NCT, kt = blk / NCT;
  int col = ct * 16 + (lane & 15);
  int kb = kt * 32 + (lane >> 4) * 8;
  u16x8 o;
  #pragma unroll
  for (int j = 0; j < 8; ++j) {
    int k = kb + j;
    o[j] = (k < K) ? f2bf(src[(size_t)k * NOUT + col]) : (unsigned short)0;
  }
  *(u16x8*)(dst + (size_t)idx * 8) = o;
}

// 64x16-rows-per-wave GEMM helper: acc[8] covers 128 output cols.
template <int KT>
static __device__ __forceinline__ void mm8(const unsigned short* __restrict__ arow, int lk,
                                           const unsigned short* __restrict__ Wb, int lane,
                                           f32x4 acc[8]) {
  const f32x4 zero = {0.f, 0.f, 0.f, 0.f};
  #pragma unroll
  for (int ct = 0; ct < 8; ++ct) acc[ct] = zero;
  #pragma unroll
  for (int kt = 0; kt < KT; ++kt) {
    bf16x8 a = *(const bf16x8*)(arow + kt*32 + lk*8);
    const u16x8* bb = (const u16x8*)Wb + (size_t)(kt*8)*64 + lane;
    #pragma unroll
    for (int ct = 0; ct < 8; ++ct) {
      bf16x8 b = *(const bf16x8*)(bb + (size_t)ct*64);
      acc[ct] = __builtin_amdgcn_mfma_f32_16x16x32_bf16(a, b, acc[ct], 0, 0, 0);
    }
  }
}

// ---------------------------------------------------------------- edge ----
__global__ __launch_bounds__(256, 2) void edge_kernel(
    const float* __restrict__ h, const int* __restrict__ ei,
    const float* __restrict__ coord, const float* __restrict__ quat,
    const float* __restrict__ qi,
    const unsigned short* __restrict__ We1b, const unsigned short* __restrict__ We2b,
    const unsigned short* __restrict__ Wc1b, const unsigned short* __restrict__ Wq1b,
    const float* __restrict__ be1, const float* __restrict__ be2,
    const float* __restrict__ bc1, const float* __restrict__ wc2,
    const float* __restrict__ bq1, const float* __restrict__ Wq2,
    const float* __restrict__ bq2,
    float* __restrict__ agg, float* __restrict__ transS,
    float* __restrict__ tanS, float* __restrict__ cnt)
{
  __shared__ unsigned short A_[64][168];  // ein, K padded 136->160, stride 168 (2-way banks)
  __shared__ unsigned short H_[64][136];  // hidden1
  __shared__ unsigned short F_[64][136];  // edge_feat
  __shared__ float csc[64];
  __shared__ float tanv[64][3];
  __shared__ float cdv[64][3];

  const int tid = threadIdx.x;
  const int e0 = blockIdx.x * 64;

  // ---- phase 0: build A = [h[row] | h[col] | radial | quat_prod | unit_vecs | 0pad]
  {
    const int e = tid >> 2, sub = tid & 3;
    const int ge = e0 + e;
    const int r = ei[ge], c = ei[N_EDGES + ge];
    const float* hs = h + (size_t)(sub < 2 ? r : c) * 64 + (sub & 1) * 32;
    const int cb = sub * 32;
    #pragma unroll
    for (int j = 0; j < 32; j += 4) {
      f32x4 v = *(const f32x4*)(hs + j);
      u16x4 p;
      p[0] = f2bf(v[0]); p[1] = f2bf(v[1]); p[2] = f2bf(v[2]); p[3] = f2bf(v[3]);
      *(u16x4*)&A_[e][cb + j] = p;
    }
  }
  if (tid < 64) {
    const int e = tid, ge = e0 + e;
    const int r = ei[ge], c = ei[N_EDGES + ge];
    const float cdx = coord[r*3+0] - coord[c*3+0];
    const float cdy = coord[r*3+1] - coord[c*3+1];
    const float cdz = coord[r*3+2] - coord[c*3+2];
    const float radial = cdx*cdx + cdy*cdy + cdz*cdz;
    const float nrm = sqrtf(radial) + 1e-8f;
    const float qix = qi[r*4+0], qiy = qi[r*4+1], qiz = qi[r*4+2], qiw = qi[r*4+3];
    const float qcx = quat[c*4+0], qcy = quat[c*4+1], qcz = quat[c*4+2], qcw = quat[c*4+3];
    // qmul(qi[row], quat[col])
    const float qpx = qiw*qcx + qix*qcw + qiy*qcz - qiz*qcy;
    const float qpy = qiw*qcy - qix*qcz + qiy*qcw + qiz*qcx;
    const float qpz = qiw*qcz + qix*qcy - qiy*qcx + qiz*qcw;
    const float qpw = qiw*qcw - qix*qcx - qiy*qcy - qiz*qcz;
    // unit_vecs = -rot_apply(qi[row], cd/nrm)
    const float vx = cdx / nrm, vy = cdy / nrm, vz = cdz / nrm;
    const float tx = 2.f*(qiy*vz - qiz*vy);
    const float ty = 2.f*(qiz*vx - qix*vz);
    const float tz = 2.f*(qix*vy - qiy*vx);
    const float ux = -(vx + qiw*tx + (qiy*tz - qiz*ty));
    const float uy = -(vy + qiw*ty + (qiz*tx - qix*tz));
    const float uz = -(vz + qiw*tz + (qix*ty - qiy*tx));
    A_[e][128] = f2bf(radial);
    A_[e][129] = f2bf(qpx); A_[e][130] = f2bf(qpy);
    A_[e][131] = f2bf(qpz); A_[e][132] = f2bf(qpw);
    A_[e][133] = f2bf(ux);  A_[e][134] = f2bf(uy); A_[e][135] = f2bf(uz);
    for (int j = 136; j < 160; ++j) A_[e][j] = 0;
    cdv[e][0] = cdx; cdv[e][1] = cdy; cdv[e][2] = cdz;
  }
  __syncthreads();

  const int wv = tid >> 6, lane = tid & 63;
  const int lr = lane & 15, lk = lane >> 4;
  f32x4 acc[8];

  // ---- GEMM1: silu(ein @ We1 + be1) -> H_
  mm8<5>(&A_[wv*16 + lr][0], lk, We1b, lane, acc);
  #pragma unroll
  for (int ct = 0; ct < 8; ++ct) {
    const int col = ct*16 + lr;
    const float b = be1[col];
    #pragma unroll
    for (int i = 0; i < 4; ++i)
      H_[wv*16 + lk*4 + i][col] = f2bf(silu_f(acc[ct][i] + b));
  }
  __syncthreads();

  // ---- GEMM2: silu(H @ We2 + be2) -> F_ (edge_feat)
  mm8<4>(&H_[wv*16 + lr][0], lk, We2b, lane, acc);
  #pragma unroll
  for (int ct = 0; ct < 8; ++ct) {
    const int col = ct*16 + lr;
    const float b = be2[col];
    #pragma unroll
    for (int i = 0; i < 4; ++i)
      F_[wv*16 + lk*4 + i][col] = f2bf(silu_f(acc[ct][i] + b));
  }
  __syncthreads();

  // ---- GEMM3: (silu(F @ Wc1 + bc1)) . wc2 -> per-edge scalar
  float pc[4] = {0.f, 0.f, 0.f, 0.f};
  mm8<4>(&F_[wv*16 + lr][0], lk, Wc1b, lane, acc);
  #pragma unroll
  for (int ct = 0; ct < 8; ++ct) {
    const int col = ct*16 + lr;
    const float b = bc1[col], w = wc2[col];
    #pragma unroll
    for (int i = 0; i < 4; ++i)
      pc[i] += silu_f(acc[ct][i] + b) * w;
  }

  // ---- GEMM4: silu(F @ Wq1 + bq1) @ Wq2 + bq2 -> per-edge 3-vec
  float pq0[4] = {0.f,0.f,0.f,0.f}, pq1[4] = {0.f,0.f,0.f,0.f}, pq2[4] = {0.f,0.f,0.f,0.f};
  mm8<4>(&F_[wv*16 + lr][0], lk, Wq1b, lane, acc);
  #pragma unroll
  for (int ct = 0; ct < 8; ++ct) {
    const int col = ct*16 + lr;
    const float b = bq1[col];
    const float w0 = Wq2[col*3+0], w1 = Wq2[col*3+1], w2 = Wq2[col*3+2];
    #pragma unroll
    for (int i = 0; i < 4; ++i) {
      const float v = silu_f(acc[ct][i] + b);
      pq0[i] += v*w0; pq1[i] += v*w1; pq2[i] += v*w2;
    }
  }
  // reduce across the 16 lanes (lane&15) that hold different col-slices
  #pragma unroll
  for (int i = 0; i < 4; ++i) {
    #pragma unroll
    for (int m = 1; m < 16; m <<= 1) {
      pc[i]  += __shfl_xor(pc[i],  m);
      pq0[i] += __shfl_xor(pq0[i], m);
      pq1[i] += __shfl_xor(pq1[i], m);
      pq2[i] += __shfl_xor(pq2[i], m);
    }
  }
  if (lr == 0) {
    #pragma unroll
    for (int i = 0; i < 4; ++i) {
      const int row = wv*16 + lk*4 + i;
      csc[row]     = pc[i];
      tanv[row][0] = pq0[i] + bq2[0];
      tanv[row][1] = pq1[i] + bq2[1];
      tanv[row][2] = pq2[i] + bq2[2];
    }
  }
  __syncthreads();

  // ---- phase 5: segment-sum atomics
  {
    const int e = tid >> 2, ge = e0 + e;
    const int r = ei[ge];
    float* aggr = agg + (size_t)r * 128 + (tid & 3) * 32;
    const unsigned short* fr = &F_[e][(tid & 3) * 32];
    #pragma unroll
    for (int j = 0; j < 32; ++j)
      atomicAdd(aggr + j, bf2f(fr[j]));
  }
  if (tid < 64) {
    const int e = tid, ge = e0 + e;
    const int r = ei[ge];
    const float cs = csc[e];
    atomicAdd(&transS[r*3+0], cdv[e][0]*cs);
    atomicAdd(&transS[r*3+1], cdv[e][1]*cs);
    atomicAdd(&transS[r*3+2], cdv[e][2]*cs);
    atomicAdd(&tanS[r*3+0], tanv[e][0]);
    atomicAdd(&tanS[r*3+1], tanv[e][1]);
    atomicAdd(&tanS[r*3+2], tanv[e][2]);
    atomicAdd(&cnt[r], 1.0f);
  }
}

// ---------------------------------------------------------------- node ----
__global__ __launch_bounds__(256, 2) void node_kernel(
    const float* __restrict__ h, const float* __restrict__ coord,
    const float* __restrict__ quat,
    const float* __restrict__ agg, const float* __restrict__ transS,
    const float* __restrict__ tanS, const float* __restrict__ cnt,
    const unsigned short* __restrict__ Wn1b, const unsigned short* __restrict__ Wn2b,
    const float* __restrict__ bn1, const float* __restrict__ bn2,
    float* __restrict__ out_h, float* __restrict__ out_c, float* __restrict__ out_q)
{
  __shared__ unsigned short A_[64][200];  // nin = [h(64)|agg(128)], K=192, stride 200
  __shared__ unsigned short H_[64][136];
  const int tid = threadIdx.x;
  const int n0 = blockIdx.x * 64;
  {
    const int rl = tid >> 2, sub = tid & 3;
    const int n = n0 + rl;
    const int cb = sub * 48;
    if (n < N_NODES) {
      for (int j = 0; j < 48; ++j) {
        const int col = cb + j;
        const float v = (col < 64) ? h[(size_t)n*64 + col]
                                   : agg[(size_t)n*128 + (col - 64)];
        A_[rl][col] = f2bf(v);
      }
    } else {
      for (int j = 0; j < 48; ++j) A_[rl][cb + j] = 0;
    }
  }
  __syncthreads();

  const int wv = tid >> 6, lane = tid & 63;
  const int lr = lane & 15, lk = lane >> 4;
  f32x4 acc[8];

  mm8<6>(&A_[wv*16 + lr][0], lk, Wn1b, lane, acc);
  #pragma unroll
  for (int ct = 0; ct < 8; ++ct) {
    const int col = ct*16 + lr;
    const float b = bn1[col];
    #pragma unroll
    for (int i = 0; i < 4; ++i)
      H_[wv*16 + lk*4 + i][col] = f2bf(silu_f(acc[ct][i] + b));
  }
  __syncthreads();

  // hidden @ Wn2 (128 -> 64)
  const f32x4 zero = {0.f, 0.f, 0.f, 0.f};
  f32x4 acc2[4];
  #pragma unroll
  for (int ct = 0; ct < 4; ++ct) acc2[ct] = zero;
  #pragma unroll
  for (int kt = 0; kt < 4; ++kt) {
    bf16x8 a = *(const bf16x8*)&H_[wv*16 + lr][kt*32 + lk*8];
    const u16x8* bb = (const u16x8*)Wn2b + (size_t)(kt*4)*64 + lane;
    #pragma unroll
    for (int ct = 0; ct < 4; ++ct) {
      bf16x8 b = *(const bf16x8*)(bb + (size_t)ct*64);
      acc2[ct] = __builtin_amdgcn_mfma_f32_16x16x32_bf16(a, b, acc2[ct], 0, 0, 0);
    }
  }
  #pragma unroll
  for (int ct = 0; ct < 4; ++ct) {
    const int col = ct*16 + lr;
    const float b = bn2[col];
    #pragma unroll
    for (int i = 0; i < 4; ++i) {
      const int n = n0 + wv*16 + lk*4 + i;
      if (n < N_NODES)
        out_h[(size_t)n*64 + col] = h[(size_t)n*64 + col] + acc2[ct][i] + b;
    }
  }

  // coord + quat update (one thread per node)
  if (tid < 64) {
    const int n = n0 + tid;
    if (n < N_NODES) {
      const float cm = fmaxf(cnt[n], 1.0f);
      const float inv = 1.0f / cm;
      out_c[n*3+0] = coord[n*3+0] + transS[n*3+0]*inv;
      out_c[n*3+1] = coord[n*3+1] + transS[n*3+1]*inv;
      out_c[n*3+2] = coord[n*3+2] + transS[n*3+2]*inv;
      const float ix = tanS[n*3+0]*inv, iy = tanS[n*3+1]*inv, iz = tanS[n*3+2]*inv;
      const float rr = sqrtf(ix*ix + iy*iy + iz*iz);
      const float s = sinf(rr) / rr;   // u*sin(r) with u=im/r
      const float rx = ix*s, ry = iy*s, rz = iz*s, rw = cosf(rr);
      const float px = quat[n*4+0], py = quat[n*4+1], pz = quat[n*4+2], pw = quat[n*4+3];
      out_q[n*4+0] = pw*rx + px*rw + py*rz - pz*ry;
      out_q[n*4+1] = pw*ry - px*rz + py*rw + pz*rx;
      out_q[n*4+2] = pw*rz + px*ry - py*rx + pz*rw;
      out_q[n*4+3] = pw*rw - px*rx - py*ry - pz*rz;
    }
  }
}

// -------------------------------------------------------------- launch ----
extern "C" void kernel_launch(void* const* d_in, const int* in_sizes, int n_in,
                              void* d_out, int out_size, void* d_ws, size_t ws_size,
                              hipStream_t stream) {
  (void)in_sizes; (void)n_in; (void)out_size; (void)ws_size;
  const float* h     = (const float*)d_in[0];
  const int*   ei    = (const int*)d_in[1];
  const float* coord = (const float*)d_in[2];
  const float* quat  = (const float*)d_in[3];
  const float* We1 = (const float*)d_in[4];  const float* be1 = (const float*)d_in[5];
  const float* We2 = (const float*)d_in[6];  const float* be2 = (const float*)d_in[7];
  const float* Wn1 = (const float*)d_in[8];  const float* bn1 = (const float*)d_in[9];
  const float* Wn2 = (const float*)d_in[10]; const float* bn2 = (const float*)d_in[11];
  const float* Wc1 = (const float*)d_in[12]; const float* bc1 = (const float*)d_in[13];
  const float* wc2 = (const float*)d_in[14];
  const float* Wq1 = (const float*)d_in[15]; const float* bq1 = (const float*)d_in[16];
  const float* Wq2 = (const float*)d_in[17]; const float* bq2 = (const float*)d_in[18];

  char* ws = (char*)d_ws;
  float* agg    = (float*)(ws);              // N*128*4 = 25,600,000
  float* transS = (float*)(ws + 25600000);   // N*3*4   =    600,000
  float* tanS   = (float*)(ws + 26200000);   // N*3*4   =    600,000
  float* cnt    = (float*)(ws + 26800000);   // N*4     =    200,000
  float* qi     = (float*)(ws + 27000000);   // N*4*4   =    800,000
  unsigned short* We1b = (unsigned short*)(ws + 27800000);
  unsigned short* We2b = We1b + 5*8*64*8;
  unsigned short* Wc1b = We2b + 4*8*64*8;
  unsigned short* Wq1b = Wc1b + 4*8*64*8;
  unsigned short* Wn1b = Wq1b + 4*8*64*8;
  unsigned short* Wn2b = Wn1b + 6*8*64*8;    // end ~ 28.0 MB

  hipMemsetAsync(ws, 0, 27000000, stream);   // zero the accumulators
  qinv_kernel<<<(N_NODES + 255)/256, 256, 0, stream>>>(quat, qi);
  swz_kernel<<<(5*8*64 + 255)/256, 256, 0, stream>>>(We1, We1b, 136, 128, 5, 8);
  swz_kernel<<<(4*8*64 + 255)/256, 256, 0, stream>>>(We2, We2b, 128, 128, 4, 8);
  swz_kernel<<<(4*8*64 + 255)/256, 256, 0, stream>>>(Wc1, Wc1b, 128, 128, 4, 8);
  swz_kernel<<<(4*8*64 + 255)/256, 256, 0, stream>>>(Wq1, Wq1b, 128, 128, 4, 8);
  swz_kernel<<<(6*8*64 + 255)/256, 256, 0, stream>>>(Wn1, Wn1b, 192, 128, 6, 8);
  swz_kernel<<<(4*4*64 + 255)/256, 256, 0, stream>>>(Wn2, Wn2b, 128, 64, 4, 4);

  edge_kernel<<<N_EDGES/64, 256, 0, stream>>>(
      h, ei, coord, quat, qi, We1b, We2b, Wc1b, Wq1b,
      be1, be2, bc1, wc2, bq1, Wq2, bq2, agg, transS, tanS, cnt);

  float* out_h = (float*)d_out;
  float* out_c = out_h + (size_t)N_NODES*64;
  float* out_q = out_c + (size_t)N_NODES*3;
  node_kernel<<<(N_NODES + 63)/64, 256, 0, stream>>>(
      h, coord, quat, agg, transS, tanS, cnt, Wn1b, Wn2b, bn1, bn2,
      out_h, out_c, out_q);
}

// Round 4
// 987.319 us; speedup vs baseline: 5.8040x; 5.8040x over previous
//
#include <hip/hip_runtime.h>
#include <hip/hip_bf16.h>
#include <math.h>

// FEGCL_46127948759594 — E(3)-equivariant GCL on MI355X.
// R4: fit workspace in ~18.8MB (R2/R3 likely wrote past ws_size: weights at
// 31.4-31.6MB corrupted adjacent allocations -> quat err / tripwire fail).
// agg stored as packed bf16 pairs (12.8MB) with CAS pair-add; all other
// structure identical to R3 (whose first-call output was fully correct).

#define N_NODES 50000
#define N_EDGES 800000
#define ASTR 168   // A/F row stride in shorts (aliased buffers, same stride)
#define HSTR 136   // H row stride in shorts

typedef __attribute__((ext_vector_type(4))) float f32x4;
typedef __attribute__((ext_vector_type(8))) short bf16x8;
typedef __attribute__((ext_vector_type(4))) unsigned short u16x4;
typedef __attribute__((ext_vector_type(8))) unsigned short u16x8;

static __device__ __forceinline__ unsigned short f2bf(float f) {
  return __builtin_bit_cast(unsigned short, __float2bfloat16(f));
}
static __device__ __forceinline__ float bf2f(unsigned short s) {
  unsigned int u = ((unsigned int)s) << 16;
  return __builtin_bit_cast(float, u);
}
static __device__ __forceinline__ float silu_f(float x) {
  return x / (1.0f + __expf(-x));
}
// CAS-based packed-bf16 pair atomic add (no dependence on pk_add_bf16 ISA).
static __device__ __forceinline__ void atomic_add_bf162(unsigned int* addr,
                                                        float lo, float hi) {
  unsigned int old = *addr, assumed;
  do {
    assumed = old;
    float clo = bf2f((unsigned short)(assumed & 0xffffu)) + lo;
    float chi = bf2f((unsigned short)(assumed >> 16)) + hi;
    unsigned int nv = ((unsigned int)f2bf(chi) << 16) | (unsigned int)f2bf(clo);
    old = atomicCAS(addr, assumed, nv);
  } while (old != assumed);
}

// ---------------------------------------------------------------- prep ----
__global__ void qinv_kernel(const float* __restrict__ quat, float* __restrict__ qi) {
  int n = blockIdx.x * blockDim.x + threadIdx.x;
  if (n >= N_NODES) return;
  float x = quat[n*4+0], y = quat[n*4+1], z = quat[n*4+2], w = quat[n*4+3];
  float inv = 1.0f / (x*x + y*y + z*z + w*w);
  qi[n*4+0] = -x*inv; qi[n*4+1] = -y*inv; qi[n*4+2] = -z*inv; qi[n*4+3] = w*inv;
}

__global__ void hist_kernel(const int* __restrict__ ei, int* __restrict__ cursor) {
  int e = blockIdx.x * blockDim.x + threadIdx.x;
  if (e < N_EDGES) atomicAdd(&cursor[ei[e]], 1);
}

// single block, 1024 threads; cursor holds deg on entry, start offset on exit.
__global__ void scan_kernel(int* __restrict__ cursor, int* __restrict__ offsets) {
  __shared__ int s[1024];
  const int t = threadIdx.x;
  const int C = 49;                       // 1024*49 = 50176 >= 50000
  const int base = t * C;
  int sum = 0;
  for (int i = 0; i < C; ++i) {
    int n = base + i;
    if (n < N_NODES) sum += cursor[n];
  }
  s[t] = sum;
  __syncthreads();
  for (int d = 1; d < 1024; d <<= 1) {
    int v = (t >= d) ? s[t - d] : 0;
    __syncthreads();
    s[t] += v;
    __syncthreads();
  }
  int run = s[t] - sum;                   // exclusive prefix
  for (int i = 0; i < C; ++i) {
    int n = base + i;
    if (n < N_NODES) {
      int d = cursor[n];
      offsets[n] = run;
      cursor[n] = run;
      run += d;
    }
  }
  if (t == 1023) offsets[N_NODES] = run;  // == N_EDGES
}

__global__ void scatter_kernel(const int* __restrict__ ei, int* __restrict__ cursor,
                               int* __restrict__ perm) {
  int e = blockIdx.x * blockDim.x + threadIdx.x;
  if (e < N_EDGES) {
    int r = ei[e];
    int pos = atomicAdd(&cursor[r], 1);
    perm[pos] = e;
  }
}

// Swizzle row-major [K][NOUT] f32 weight into MFMA-fragment-ordered bf16.
__global__ void swz_kernel(const float* __restrict__ src, unsigned short* __restrict__ dst,
                           int K, int NOUT, int KT, int NCT) {
  int idx = blockIdx.x * blockDim.x + threadIdx.x;
  if (idx >= KT * NCT * 64) return;
  int lane = idx & 63, blk = idx >> 6;
  int ct = blk % NCT, kt = blk / NCT;
  int col = ct * 16 + (lane & 15);
  int kb = kt * 32 + (lane >> 4) * 8;
  u16x8 o;
  #pragma unroll
  for (int j = 0; j < 8; ++j) {
    int k = kb + j;
    o[j] = (k < K) ? f2bf(src[(size_t)k * NOUT + col]) : (unsigned short)0;
  }
  *(u16x8*)(dst + (size_t)idx * 8) = o;
}

// 16-rows-per-wave GEMM helper: acc[8] covers 128 output cols.
template <int KT>
static __device__ __forceinline__ void mm8(const unsigned short* __restrict__ arow, int lk,
                                           const unsigned short* __restrict__ Wb, int lane,
                                           f32x4 acc[8]) {
  const f32x4 zero = {0.f, 0.f, 0.f, 0.f};
  #pragma unroll
  for (int ct = 0; ct < 8; ++ct) acc[ct] = zero;
  #pragma unroll
  for (int kt = 0; kt < KT; ++kt) {
    bf16x8 a = *(const bf16x8*)(arow + kt*32 + lk*8);
    const u16x8* bb = (const u16x8*)Wb + (size_t)(kt*8)*64 + lane;
    #pragma unroll
    for (int ct = 0; ct < 8; ++ct) {
      bf16x8 b = *(const bf16x8*)(bb + (size_t)ct*64);
      acc[ct] = __builtin_amdgcn_mfma_f32_16x16x32_bf16(a, b, acc[ct], 0, 0, 0);
    }
  }
}

// ---------------------------------------------------------------- edge ----
__global__ __launch_bounds__(256, 3) void edge_kernel(
    const float* __restrict__ h, const int* __restrict__ ei,
    const float* __restrict__ coord, const float* __restrict__ quat,
    const float* __restrict__ qi, const int* __restrict__ perm,
    const unsigned short* __restrict__ We1b, const unsigned short* __restrict__ We2b,
    const unsigned short* __restrict__ Wc1b, const unsigned short* __restrict__ Wq1b,
    const float* __restrict__ be1, const float* __restrict__ be2,
    const float* __restrict__ bc1, const float* __restrict__ wc2,
    const float* __restrict__ bq1, const float* __restrict__ Wq2,
    const float* __restrict__ bq2,
    unsigned int* __restrict__ agg32, float* __restrict__ transS,
    float* __restrict__ tanS, float* __restrict__ cnt)
{
  // A [64][ASTR] (ein, K padded 136->160) aliased with F [64][ASTR] (edge_feat),
  // then H [64][HSTR]. Per-wave 16-row bands are private -> no inter-GEMM syncs.
  __shared__ __align__(16) unsigned short smem[64*ASTR + 64*HSTR];
  unsigned short* AF = smem;
  unsigned short* Hb = smem + 64*ASTR;
  __shared__ float csc[64];
  __shared__ float tanv[64][3];
  __shared__ float cdv[64][3];
  __shared__ int rows_s[64];

  const int tid = threadIdx.x;
  const int e0 = blockIdx.x * 64;

  // ---- build A = [h[row] | h[col] | radial | quat_prod | unit_vecs | 0pad]
  {
    const int e = tid >> 2, sub = tid & 3;          // e stays in this wave's band
    const int ge = perm[e0 + e];
    const int r = ei[ge], c = ei[N_EDGES + ge];
    const float* hs = h + (size_t)(sub < 2 ? r : c) * 64 + (sub & 1) * 32;
    const int cb = sub * 32;
    #pragma unroll
    for (int j = 0; j < 32; j += 4) {
      f32x4 v = *(const f32x4*)(hs + j);
      u16x4 p;
      p[0] = f2bf(v[0]); p[1] = f2bf(v[1]); p[2] = f2bf(v[2]); p[3] = f2bf(v[3]);
      *(u16x4*)&AF[e*ASTR + cb + j] = p;
    }
  }
  if (tid < 64) {
    const int e = tid;
    const int ge = perm[e0 + e];
    const int r = ei[ge], c = ei[N_EDGES + ge];
    const float cdx = coord[r*3+0] - coord[c*3+0];
    const float cdy = coord[r*3+1] - coord[c*3+1];
    const float cdz = coord[r*3+2] - coord[c*3+2];
    const float radial = cdx*cdx + cdy*cdy + cdz*cdz;
    const float nrm = sqrtf(radial) + 1e-8f;
    const float qix = qi[r*4+0], qiy = qi[r*4+1], qiz = qi[r*4+2], qiw = qi[r*4+3];
    const float qcx = quat[c*4+0], qcy = quat[c*4+1], qcz = quat[c*4+2], qcw = quat[c*4+3];
    const float qpx = qiw*qcx + qix*qcw + qiy*qcz - qiz*qcy;
    const float qpy = qiw*qcy - qix*qcz + qiy*qcw + qiz*qcx;
    const float qpz = qiw*qcz + qix*qcy - qiy*qcx + qiz*qcw;
    const float qpw = qiw*qcw - qix*qcx - qiy*qcy - qiz*qcz;
    const float vx = cdx / nrm, vy = cdy / nrm, vz = cdz / nrm;
    const float tx = 2.f*(qiy*vz - qiz*vy);
    const float ty = 2.f*(qiz*vx - qix*vz);
    const float tz = 2.f*(qix*vy - qiy*vx);
    const float ux = -(vx + qiw*tx + (qiy*tz - qiz*ty));
    const float uy = -(vy + qiw*ty + (qiz*tx - qix*tz));
    const float uz = -(vz + qiw*tz + (qix*ty - qiy*tx));
    AF[e*ASTR + 128] = f2bf(radial);
    AF[e*ASTR + 129] = f2bf(qpx); AF[e*ASTR + 130] = f2bf(qpy);
    AF[e*ASTR + 131] = f2bf(qpz); AF[e*ASTR + 132] = f2bf(qpw);
    AF[e*ASTR + 133] = f2bf(ux);  AF[e*ASTR + 134] = f2bf(uy);
    AF[e*ASTR + 135] = f2bf(uz);
    for (int j = 136; j < 160; ++j) AF[e*ASTR + j] = 0;
    cdv[e][0] = cdx; cdv[e][1] = cdy; cdv[e][2] = cdz;
    rows_s[e] = r;
  }
  __syncthreads();

  const int wv = tid >> 6, lane = tid & 63;
  const int lr = lane & 15, lk = lane >> 4;
  const int rowA = wv*16 + lr;       // A-operand row for this lane
  const int rowC = wv*16 + lk*4;     // C-fragment base row for this lane
  f32x4 acc[8];

  // ---- GEMM1: silu(ein @ We1 + be1) -> H   (per-wave private rows, no sync)
  mm8<5>(AF + rowA*ASTR, lk, We1b, lane, acc);
  #pragma unroll
  for (int ct = 0; ct < 8; ++ct) {
    const int col = ct*16 + lr;
    const float b = be1[col];
    #pragma unroll
    for (int i = 0; i < 4; ++i)
      Hb[(rowC + i)*HSTR + col] = f2bf(silu_f(acc[ct][i] + b));
  }

  // ---- GEMM2: silu(H @ We2 + be2) -> F (aliased over A, same stride/rows)
  mm8<4>(Hb + rowA*HSTR, lk, We2b, lane, acc);
  #pragma unroll
  for (int ct = 0; ct < 8; ++ct) {
    const int col = ct*16 + lr;
    const float b = be2[col];
    #pragma unroll
    for (int i = 0; i < 4; ++i)
      AF[(rowC + i)*ASTR + col] = f2bf(silu_f(acc[ct][i] + b));
  }

  // ---- GEMM3: (silu(F @ Wc1 + bc1)) . wc2 -> per-edge scalar
  float pc[4] = {0.f, 0.f, 0.f, 0.f};
  mm8<4>(AF + rowA*ASTR, lk, Wc1b, lane, acc);
  #pragma unroll
  for (int ct = 0; ct < 8; ++ct) {
    const int col = ct*16 + lr;
    const float b = bc1[col], w = wc2[col];
    #pragma unroll
    for (int i = 0; i < 4; ++i)
      pc[i] += silu_f(acc[ct][i] + b) * w;
  }

  // ---- GEMM4: silu(F @ Wq1 + bq1) @ Wq2 + bq2 -> per-edge 3-vec
  float pq0[4] = {0.f,0.f,0.f,0.f}, pq1[4] = {0.f,0.f,0.f,0.f}, pq2[4] = {0.f,0.f,0.f,0.f};
  mm8<4>(AF + rowA*ASTR, lk, Wq1b, lane, acc);
  #pragma unroll
  for (int ct = 0; ct < 8; ++ct) {
    const int col = ct*16 + lr;
    const float b = bq1[col];
    const float w0 = Wq2[col*3+0], w1 = Wq2[col*3+1], w2 = Wq2[col*3+2];
    #pragma unroll
    for (int i = 0; i < 4; ++i) {
      const float v = silu_f(acc[ct][i] + b);
      pq0[i] += v*w0; pq1[i] += v*w1; pq2[i] += v*w2;
    }
  }
  #pragma unroll
  for (int i = 0; i < 4; ++i) {
    #pragma unroll
    for (int m = 1; m < 16; m <<= 1) {
      pc[i]  += __shfl_xor(pc[i],  m);
      pq0[i] += __shfl_xor(pq0[i], m);
      pq1[i] += __shfl_xor(pq1[i], m);
      pq2[i] += __shfl_xor(pq2[i], m);
    }
  }
  if (lr == 0) {
    #pragma unroll
    for (int i = 0; i < 4; ++i) {
      const int row = rowC + i;
      csc[row]     = pc[i];
      tanv[row][0] = pq0[i] + bq2[0];
      tanv[row][1] = pq1[i] + bq2[1];
      tanv[row][2] = pq2[i] + bq2[2];
    }
  }
  __syncthreads();

  // ---- aggregation.
  // Columns: threads 0..127 segmented-reduce agg (bf16-pair CAS adds) over the
  // block's row-sorted edges; pair p = tid&63 covers cols {2p,2p+1}, half-split
  // over e for parallelism. Scalars (R1-proven): wave 3 per-edge atomics.
  if (tid < 128) {
    const int p = tid & 63;
    const int eBeg = (tid >> 6) * 32, eEnd = eBeg + 32;
    float rl_ = 0.f, rh_ = 0.f;
    int prev = rows_s[eBeg];
    for (int e = eBeg; e < eEnd; ++e) {
      const int r = rows_s[e];
      if (r != prev) {
        atomic_add_bf162(&agg32[(size_t)prev*64 + p], rl_, rh_);
        rl_ = 0.f; rh_ = 0.f; prev = r;
      }
      const unsigned int u = *(const unsigned int*)&AF[e*ASTR + 2*p];
      rl_ += bf2f((unsigned short)(u & 0xffffu));
      rh_ += bf2f((unsigned short)(u >> 16));
    }
    atomic_add_bf162(&agg32[(size_t)prev*64 + p], rl_, rh_);
  } else if (tid >= 192) {
    const int e = tid - 192;
    const int r = rows_s[e];
    const float cs = csc[e];
    atomicAdd(&transS[r*3+0], cdv[e][0]*cs);
    atomicAdd(&transS[r*3+1], cdv[e][1]*cs);
    atomicAdd(&transS[r*3+2], cdv[e][2]*cs);
    atomicAdd(&tanS[r*3+0], tanv[e][0]);
    atomicAdd(&tanS[r*3+1], tanv[e][1]);
    atomicAdd(&tanS[r*3+2], tanv[e][2]);
    atomicAdd(&cnt[r], 1.0f);
  }
}

// ---------------------------------------------------------------- node ----
__global__ __launch_bounds__(256, 3) void node_kernel(
    const float* __restrict__ h, const float* __restrict__ coord,
    const float* __restrict__ quat,
    const unsigned short* __restrict__ aggb, const float* __restrict__ transS,
    const float* __restrict__ tanS, const float* __restrict__ cnt,
    const unsigned short* __restrict__ Wn1b, const unsigned short* __restrict__ Wn2b,
    const float* __restrict__ bn1, const float* __restrict__ bn2,
    float* __restrict__ out_h, float* __restrict__ out_c, float* __restrict__ out_q)
{
  __shared__ unsigned short A_[64][200];  // nin = [h(64)|agg(128)], K=192
  __shared__ unsigned short H_[64][136];
  const int tid = threadIdx.x;
  const int n0 = blockIdx.x * 64;
  {
    const int rl = tid >> 2, sub = tid & 3;
    const int n = n0 + rl;
    const int cb = sub * 48;
    if (n < N_NODES) {
      for (int j = 0; j < 48; ++j) {
        const int col = cb + j;
        A_[rl][col] = (col < 64) ? f2bf(h[(size_t)n*64 + col])
                                 : aggb[(size_t)n*128 + (col - 64)];
      }
    } else {
      for (int j = 0; j < 48; ++j) A_[rl][cb + j] = 0;
    }
  }
  __syncthreads();

  const int wv = tid >> 6, lane = tid & 63;
  const int lr = lane & 15, lk = lane >> 4;
  f32x4 acc[8];

  mm8<6>(&A_[wv*16 + lr][0], lk, Wn1b, lane, acc);
  #pragma unroll
  for (int ct = 0; ct < 8; ++ct) {
    const int col = ct*16 + lr;
    const float b = bn1[col];
    #pragma unroll
    for (int i = 0; i < 4; ++i)
      H_[wv*16 + lk*4 + i][col] = f2bf(silu_f(acc[ct][i] + b));
  }
  __syncthreads();

  const f32x4 zero = {0.f, 0.f, 0.f, 0.f};
  f32x4 acc2[4];
  #pragma unroll
  for (int ct = 0; ct < 4; ++ct) acc2[ct] = zero;
  #pragma unroll
  for (int kt = 0; kt < 4; ++kt) {
    bf16x8 a = *(const bf16x8*)&H_[wv*16 + lr][kt*32 + lk*8];
    const u16x8* bb = (const u16x8*)Wn2b + (size_t)(kt*4)*64 + lane;
    #pragma unroll
    for (int ct = 0; ct < 4; ++ct) {
      bf16x8 b = *(const bf16x8*)(bb + (size_t)ct*64);
      acc2[ct] = __builtin_amdgcn_mfma_f32_16x16x32_bf16(a, b, acc2[ct], 0, 0, 0);
    }
  }
  #pragma unroll
  for (int ct = 0; ct < 4; ++ct) {
    const int col = ct*16 + lr;
    const float b = bn2[col];
    #pragma unroll
    for (int i = 0; i < 4; ++i) {
      const int n = n0 + wv*16 + lk*4 + i;
      if (n < N_NODES)
        out_h[(size_t)n*64 + col] = h[(size_t)n*64 + col] + acc2[ct][i] + b;
    }
  }

  if (tid < 64) {
    const int n = n0 + tid;
    if (n < N_NODES) {
      const float cm = fmaxf(cnt[n], 1.0f);
      const float inv = 1.0f / cm;
      out_c[n*3+0] = coord[n*3+0] + transS[n*3+0]*inv;
      out_c[n*3+1] = coord[n*3+1] + transS[n*3+1]*inv;
      out_c[n*3+2] = coord[n*3+2] + transS[n*3+2]*inv;
      const float ix = tanS[n*3+0]*inv, iy = tanS[n*3+1]*inv, iz = tanS[n*3+2]*inv;
      const float rr = sqrtf(ix*ix + iy*iy + iz*iz);
      const float s = sinf(rr) / rr;
      const float rx = ix*s, ry = iy*s, rz = iz*s, rw = cosf(rr);
      const float px = quat[n*4+0], py = quat[n*4+1], pz = quat[n*4+2], pw = quat[n*4+3];
      out_q[n*4+0] = pw*rx + px*rw + py*rz - pz*ry;
      out_q[n*4+1] = pw*ry - px*rz + py*rw + pz*rx;
      out_q[n*4+2] = pw*rz + px*ry - py*rx + pz*rw;
      out_q[n*4+3] = pw*rw - px*rx - py*ry - pz*rz;
    }
  }
}

// -------------------------------------------------------------- launch ----
extern "C" void kernel_launch(void* const* d_in, const int* in_sizes, int n_in,
                              void* d_out, int out_size, void* d_ws, size_t ws_size,
                              hipStream_t stream) {
  (void)in_sizes; (void)n_in; (void)out_size; (void)ws_size;
  const float* h     = (const float*)d_in[0];
  const int*   ei    = (const int*)d_in[1];
  const float* coord = (const float*)d_in[2];
  const float* quat  = (const float*)d_in[3];
  const float* We1 = (const float*)d_in[4];  const float* be1 = (const float*)d_in[5];
  const float* We2 = (const float*)d_in[6];  const float* be2 = (const float*)d_in[7];
  const float* Wn1 = (const float*)d_in[8];  const float* bn1 = (const float*)d_in[9];
  const float* Wn2 = (const float*)d_in[10]; const float* bn2 = (const float*)d_in[11];
  const float* Wc1 = (const float*)d_in[12]; const float* bc1 = (const float*)d_in[13];
  const float* wc2 = (const float*)d_in[14];
  const float* Wq1 = (const float*)d_in[15]; const float* bq1 = (const float*)d_in[16];
  const float* Wq2 = (const float*)d_in[17]; const float* bq2 = (const float*)d_in[18];

  // Compact layout — total ~18.8 MB (R1 proved >=28.0 MB is safe).
  char* ws = (char*)d_ws;
  unsigned int* agg32  = (unsigned int*)(ws);           // bf16x2 [N][64]: 12,800,000
  unsigned short* aggb = (unsigned short*)(ws);         // same bytes as bf16 [N][128]
  float* transS = (float*)(ws + 12800000);              //    600,000
  float* tanS   = (float*)(ws + 13400000);              //    600,000
  float* cnt    = (float*)(ws + 14000000);              //    200,000
  int*   cursor = (int*)  (ws + 14200000);              //    200,000 (memset ends 14.4MB)
  int*   offs   = (int*)  (ws + 14400000);              //    200,004
  int*   perm   = (int*)  (ws + 14600064);              //  3,200,000
  float* qi     = (float*)(ws + 17800064);              //    800,000
  unsigned short* We1b = (unsigned short*)(ws + 18600064);
  unsigned short* We2b = We1b + 5*8*64*8;
  unsigned short* Wc1b = We2b + 4*8*64*8;
  unsigned short* Wq1b = Wc1b + 4*8*64*8;
  unsigned short* Wn1b = Wq1b + 4*8*64*8;
  unsigned short* Wn2b = Wn1b + 6*8*64*8;               // ends ~18.81 MB

  hipMemsetAsync(ws, 0, 14400000, stream);  // agg+transS+tanS+cnt+cursor
  qinv_kernel<<<(N_NODES + 255)/256, 256, 0, stream>>>(quat, qi);
  swz_kernel<<<(5*8*64 + 255)/256, 256, 0, stream>>>(We1, We1b, 136, 128, 5, 8);
  swz_kernel<<<(4*8*64 + 255)/256, 256, 0, stream>>>(We2, We2b, 128, 128, 4, 8);
  swz_kernel<<<(4*8*64 + 255)/256, 256, 0, stream>>>(Wc1, Wc1b, 128, 128, 4, 8);
  swz_kernel<<<(4*8*64 + 255)/256, 256, 0, stream>>>(Wq1, Wq1b, 128, 128, 4, 8);
  swz_kernel<<<(6*8*64 + 255)/256, 256, 0, stream>>>(Wn1, Wn1b, 192, 128, 6, 8);
  swz_kernel<<<(4*4*64 + 255)/256, 256, 0, stream>>>(Wn2, Wn2b, 128, 64, 4, 4);
  hist_kernel<<<(N_EDGES + 255)/256, 256, 0, stream>>>(ei, cursor);
  scan_kernel<<<1, 1024, 0, stream>>>(cursor, offs);
  scatter_kernel<<<(N_EDGES + 255)/256, 256, 0, stream>>>(ei, cursor, perm);

  edge_kernel<<<N_EDGES/64, 256, 0, stream>>>(
      h, ei, coord, quat, qi, perm, We1b, We2b, Wc1b, Wq1b,
      be1, be2, bc1, wc2, bq1, Wq2, bq2, agg32, transS, tanS, cnt);

  float* out_h = (float*)d_out;
  float* out_c = out_h + (size_t)N_NODES*64;
  float* out_q = out_c + (size_t)N_NODES*3;
  node_kernel<<<(N_NODES + 63)/64, 256, 0, stream>>>(
      h, coord, quat, aggb, transS, tanS, cnt, Wn1b, Wn2b, bn1, bn2,
      out_h, out_c, out_q);
}

// Round 5
// 968.388 us; speedup vs baseline: 5.9175x; 1.0195x over previous
//
#include <hip/hip_runtime.h>
#include <hip/hip_bf16.h>
#include <math.h>

// FEGCL_46127948759594 — E(3)-equivariant GCL on MI355X.
// R5: swap MFMA operands (weights=A, activations=B). C-fragment becomes
// row-contiguous per edge -> b64 epilogue writes, float4 bias loads, 2-step
// shuffle reductions, per-wave scalar atomics + per-wave column CAS reduce
// (second barrier deleted). Workspace layout identical to R4 (proven safe).

#define N_NODES 50000
#define N_EDGES 800000
#define ASTR 172   // A/F row stride in shorts (8B-aligned rows, conflict-trimmed)
#define HSTR 140   // H row stride in shorts
#define NSTR 204   // node A stride
#define NHSTR 140  // node H stride

typedef __attribute__((ext_vector_type(4))) float f32x4;
typedef __attribute__((ext_vector_type(8))) short bf16x8;
typedef __attribute__((ext_vector_type(4))) unsigned short u16x4;
typedef __attribute__((ext_vector_type(8))) unsigned short u16x8;

static __device__ __forceinline__ unsigned short f2bf(float f) {
  return __builtin_bit_cast(unsigned short, __float2bfloat16(f));
}
static __device__ __forceinline__ float bf2f(unsigned short s) {
  unsigned int u = ((unsigned int)s) << 16;
  return __builtin_bit_cast(float, u);
}
static __device__ __forceinline__ float silu_f(float x) {
  return x / (1.0f + __expf(-x));
}
// CAS-based packed-bf16 pair atomic add.
static __device__ __forceinline__ void atomic_add_bf162(unsigned int* addr,
                                                        float lo, float hi) {
  unsigned int old = *addr, assumed;
  do {
    assumed = old;
    float clo = bf2f((unsigned short)(assumed & 0xffffu)) + lo;
    float chi = bf2f((unsigned short)(assumed >> 16)) + hi;
    unsigned int nv = ((unsigned int)f2bf(chi) << 16) | (unsigned int)f2bf(clo);
    old = atomicCAS(addr, assumed, nv);
  } while (old != assumed);
}

// ---------------------------------------------------------------- prep ----
__global__ void qinv_kernel(const float* __restrict__ quat, float* __restrict__ qi) {
  int n = blockIdx.x * blockDim.x + threadIdx.x;
  if (n >= N_NODES) return;
  float x = quat[n*4+0], y = quat[n*4+1], z = quat[n*4+2], w = quat[n*4+3];
  float inv = 1.0f / (x*x + y*y + z*z + w*w);
  qi[n*4+0] = -x*inv; qi[n*4+1] = -y*inv; qi[n*4+2] = -z*inv; qi[n*4+3] = w*inv;
}

__global__ void hist_kernel(const int* __restrict__ ei, int* __restrict__ cursor) {
  int e = blockIdx.x * blockDim.x + threadIdx.x;
  if (e < N_EDGES) atomicAdd(&cursor[ei[e]], 1);
}

__global__ void scan_kernel(int* __restrict__ cursor, int* __restrict__ offsets) {
  __shared__ int s[1024];
  const int t = threadIdx.x;
  const int C = 49;
  const int base = t * C;
  int sum = 0;
  for (int i = 0; i < C; ++i) {
    int n = base + i;
    if (n < N_NODES) sum += cursor[n];
  }
  s[t] = sum;
  __syncthreads();
  for (int d = 1; d < 1024; d <<= 1) {
    int v = (t >= d) ? s[t - d] : 0;
    __syncthreads();
    s[t] += v;
    __syncthreads();
  }
  int run = s[t] - sum;
  for (int i = 0; i < C; ++i) {
    int n = base + i;
    if (n < N_NODES) {
      int d = cursor[n];
      offsets[n] = run;
      cursor[n] = run;
      run += d;
    }
  }
  if (t == 1023) offsets[N_NODES] = run;
}

__global__ void scatter_kernel(const int* __restrict__ ei, int* __restrict__ cursor,
                               int* __restrict__ perm) {
  int e = blockIdx.x * blockDim.x + threadIdx.x;
  if (e < N_EDGES) {
    int r = ei[e];
    int pos = atomicAdd(&cursor[r], 1);
    perm[pos] = e;
  }
}

// Swizzle row-major [K][NOUT] f32 weight into MFMA-fragment-ordered bf16.
__global__ void swz_kernel(const float* __restrict__ src, unsigned short* __restrict__ dst,
                           int K, int NOUT, int KT, int NCT) {
  int idx = blockIdx.x * blockDim.x + threadIdx.x;
  if (idx >= KT * NCT * 64) return;
  int lane = idx & 63, blk = idx >> 6;
  int ct = blk % NCT, kt = blk / NCT;
  int col = ct * 16 + (lane & 15);
  int kb = kt * 32 + (lane >> 4) * 8;
  u16x8 o;
  #pragma unroll
  for (int j = 0; j < 8; ++j) {
    int k = kb + j;
    o[j] = (k < K) ? f2bf(src[(size_t)k * NOUT + col]) : (unsigned short)0;
  }
  *(u16x8*)(dst + (size_t)idx * 8) = o;
}

// Weights-as-A GEMM: acc[ct] covers outcol tile ct; D col = edge (lane&15),
// D rows = outcols ct*16 + (lane>>4)*4 + i.
template <int KT, int NCT>
static __device__ __forceinline__ void mmW(const unsigned short* __restrict__ arow, int lk,
                                           const unsigned short* __restrict__ Wb, int lane,
                                           f32x4* acc) {
  const f32x4 zero = {0.f, 0.f, 0.f, 0.f};
  #pragma unroll
  for (int ct = 0; ct < NCT; ++ct) acc[ct] = zero;
  #pragma unroll
  for (int kt = 0; kt < KT; ++kt) {
    bf16x8 act = *(const bf16x8*)(arow + kt*32 + lk*8);
    const u16x8* bb = (const u16x8*)Wb + (size_t)(kt*NCT)*64 + lane;
    #pragma unroll
    for (int ct = 0; ct < NCT; ++ct) {
      bf16x8 w = *(const bf16x8*)(bb + (size_t)ct*64);
      acc[ct] = __builtin_amdgcn_mfma_f32_16x16x32_bf16(w, act, acc[ct], 0, 0, 0);
    }
  }
}

// ---------------------------------------------------------------- edge ----
__global__ __launch_bounds__(256, 3) void edge_kernel(
    const float* __restrict__ h, const int* __restrict__ ei,
    const float* __restrict__ coord, const float* __restrict__ quat,
    const float* __restrict__ qi, const int* __restrict__ perm,
    const unsigned short* __restrict__ We1b, const unsigned short* __restrict__ We2b,
    const unsigned short* __restrict__ Wc1b, const unsigned short* __restrict__ Wq1b,
    const float* __restrict__ be1, const float* __restrict__ be2,
    const float* __restrict__ bc1, const float* __restrict__ wc2,
    const float* __restrict__ bq1, const float* __restrict__ Wq2,
    const float* __restrict__ bq2,
    unsigned int* __restrict__ agg32, float* __restrict__ transS,
    float* __restrict__ tanS, float* __restrict__ cnt)
{
  __shared__ __align__(16) unsigned short smem[64*ASTR + 64*HSTR];
  unsigned short* AF = smem;              // ein (K pad 136->160), later edge_feat
  unsigned short* Hb = smem + 64*ASTR;    // hidden1
  __shared__ float cdv[64][3];
  __shared__ int rows_s[64];

  const int tid = threadIdx.x;
  const int e0 = blockIdx.x * 64;

  // ---- build A = [h[row] | h[col] | radial | quat_prod | unit_vecs | 0pad]
  {
    const int e = tid >> 2, sub = tid & 3;          // e stays in this wave's band
    const int ge = perm[e0 + e];
    const int r = ei[ge], c = ei[N_EDGES + ge];
    const float* hs = h + (size_t)(sub < 2 ? r : c) * 64 + (sub & 1) * 32;
    const int cb = sub * 32;
    #pragma unroll
    for (int j = 0; j < 32; j += 4) {
      f32x4 v = *(const f32x4*)(hs + j);
      u16x4 p;
      p[0] = f2bf(v[0]); p[1] = f2bf(v[1]); p[2] = f2bf(v[2]); p[3] = f2bf(v[3]);
      *(u16x4*)&AF[e*ASTR + cb + j] = p;
    }
  }
  if (tid < 64) {
    const int e = tid;
    const int ge = perm[e0 + e];
    const int r = ei[ge], c = ei[N_EDGES + ge];
    const float cdx = coord[r*3+0] - coord[c*3+0];
    const float cdy = coord[r*3+1] - coord[c*3+1];
    const float cdz = coord[r*3+2] - coord[c*3+2];
    const float radial = cdx*cdx + cdy*cdy + cdz*cdz;
    const float nrm = sqrtf(radial) + 1e-8f;
    const float qix = qi[r*4+0], qiy = qi[r*4+1], qiz = qi[r*4+2], qiw = qi[r*4+3];
    const float qcx = quat[c*4+0], qcy = quat[c*4+1], qcz = quat[c*4+2], qcw = quat[c*4+3];
    const float qpx = qiw*qcx + qix*qcw + qiy*qcz - qiz*qcy;
    const float qpy = qiw*qcy - qix*qcz + qiy*qcw + qiz*qcx;
    const float qpz = qiw*qcz + qix*qcy - qiy*qcx + qiz*qcw;
    const float qpw = qiw*qcw - qix*qcx - qiy*qcy - qiz*qcz;
    const float vx = cdx / nrm, vy = cdy / nrm, vz = cdz / nrm;
    const float tx = 2.f*(qiy*vz - qiz*vy);
    const float ty = 2.f*(qiz*vx - qix*vz);
    const float tz = 2.f*(qix*vy - qiy*vx);
    const float ux = -(vx + qiw*tx + (qiy*tz - qiz*ty));
    const float uy = -(vy + qiw*ty + (qiz*tx - qix*tz));
    const float uz = -(vz + qiw*tz + (qix*ty - qiy*tx));
    AF[e*ASTR + 128] = f2bf(radial);
    AF[e*ASTR + 129] = f2bf(qpx); AF[e*ASTR + 130] = f2bf(qpy);
    AF[e*ASTR + 131] = f2bf(qpz); AF[e*ASTR + 132] = f2bf(qpw);
    AF[e*ASTR + 133] = f2bf(ux);  AF[e*ASTR + 134] = f2bf(uy);
    AF[e*ASTR + 135] = f2bf(uz);
    for (int j = 136; j < 160; ++j) AF[e*ASTR + j] = 0;
    cdv[e][0] = cdx; cdv[e][1] = cdy; cdv[e][2] = cdz;
    rows_s[e] = r;
  }
  __syncthreads();

  const int wv = tid >> 6, lane = tid & 63;
  const int lr = lane & 15, lk = lane >> 4;
  const int erow = wv*16 + lr;       // this lane's edge row (B-read and C-write)
  f32x4 acc[8];

  // ---- GEMM1: silu(ein @ We1 + be1) -> H  (per-wave private rows, no sync)
  mmW<5,8>(AF + erow*ASTR, lk, We1b, lane, acc);
  #pragma unroll
  for (int ct = 0; ct < 8; ++ct) {
    const int ocb = ct*16 + lk*4;
    const f32x4 b4 = *(const f32x4*)&be1[ocb];
    u16x4 pk;
    #pragma unroll
    for (int i = 0; i < 4; ++i) pk[i] = f2bf(silu_f(acc[ct][i] + b4[i]));
    *(u16x4*)&Hb[erow*HSTR + ocb] = pk;
  }

  // ---- GEMM2: silu(H @ We2 + be2) -> F (aliased over A)
  mmW<4,8>(Hb + erow*HSTR, lk, We2b, lane, acc);
  #pragma unroll
  for (int ct = 0; ct < 8; ++ct) {
    const int ocb = ct*16 + lk*4;
    const f32x4 b4 = *(const f32x4*)&be2[ocb];
    u16x4 pk;
    #pragma unroll
    for (int i = 0; i < 4; ++i) pk[i] = f2bf(silu_f(acc[ct][i] + b4[i]));
    *(u16x4*)&AF[erow*ASTR + ocb] = pk;
  }

  // ---- GEMM3: (silu(F @ Wc1 + bc1)) . wc2 -> per-edge scalar
  float pcs = 0.f;
  mmW<4,8>(AF + erow*ASTR, lk, Wc1b, lane, acc);
  #pragma unroll
  for (int ct = 0; ct < 8; ++ct) {
    const int ocb = ct*16 + lk*4;
    const f32x4 b4 = *(const f32x4*)&bc1[ocb];
    const f32x4 w4 = *(const f32x4*)&wc2[ocb];
    #pragma unroll
    for (int i = 0; i < 4; ++i) pcs += silu_f(acc[ct][i] + b4[i]) * w4[i];
  }
  pcs += __shfl_xor(pcs, 16);
  pcs += __shfl_xor(pcs, 32);

  // ---- GEMM4: silu(F @ Wq1 + bq1) @ Wq2 + bq2 -> per-edge 3-vec
  float p0 = 0.f, p1 = 0.f, p2 = 0.f;
  mmW<4,8>(AF + erow*ASTR, lk, Wq1b, lane, acc);
  #pragma unroll
  for (int ct = 0; ct < 8; ++ct) {
    const int ocb = ct*16 + lk*4;
    const f32x4 b4 = *(const f32x4*)&bq1[ocb];
    const float* wq = &Wq2[ocb*3];
    const f32x4 qa = *(const f32x4*)(wq);
    const f32x4 qb = *(const f32x4*)(wq + 4);
    const f32x4 qc = *(const f32x4*)(wq + 8);
    const float v0 = silu_f(acc[ct][0] + b4[0]);
    const float v1 = silu_f(acc[ct][1] + b4[1]);
    const float v2 = silu_f(acc[ct][2] + b4[2]);
    const float v3 = silu_f(acc[ct][3] + b4[3]);
    p0 += v0*qa[0] + v1*qa[3] + v2*qb[2] + v3*qc[1];
    p1 += v0*qa[1] + v1*qb[0] + v2*qb[3] + v3*qc[2];
    p2 += v0*qa[2] + v1*qb[1] + v2*qc[0] + v3*qc[3];
  }
  p0 += __shfl_xor(p0, 16);  p0 += __shfl_xor(p0, 32);
  p1 += __shfl_xor(p1, 16);  p1 += __shfl_xor(p1, 32);
  p2 += __shfl_xor(p2, 16);  p2 += __shfl_xor(p2, 32);

  // ---- per-wave scalar atomics (all lanes hold full sums for edge erow)
  {
    const int r = rows_s[erow];
    if (lk == 0) {
      atomicAdd(&transS[r*3+0], cdv[erow][0]*pcs);
      atomicAdd(&tanS[r*3+0], p0 + bq2[0]);
    } else if (lk == 1) {
      atomicAdd(&transS[r*3+1], cdv[erow][1]*pcs);
      atomicAdd(&tanS[r*3+1], p1 + bq2[1]);
    } else if (lk == 2) {
      atomicAdd(&transS[r*3+2], cdv[erow][2]*pcs);
      atomicAdd(&tanS[r*3+2], p2 + bq2[2]);
    } else {
      atomicAdd(&cnt[r], 1.0f);
    }
  }

  // ---- per-wave column CAS reduce over own 16 row-sorted edges (no barrier)
  {
    const int p = lane;                 // pair p covers cols {2p, 2p+1}
    float rl_ = 0.f, rh_ = 0.f;
    int prev = rows_s[wv*16];
    #pragma unroll 4
    for (int k2 = 0; k2 < 16; ++k2) {
      const int e = wv*16 + k2;
      const int r = rows_s[e];
      if (r != prev) {
        atomic_add_bf162(&agg32[(size_t)prev*64 + p], rl_, rh_);
        rl_ = 0.f; rh_ = 0.f; prev = r;
      }
      const unsigned int u = *(const unsigned int*)&AF[e*ASTR + 2*p];
      rl_ += bf2f((unsigned short)(u & 0xffffu));
      rh_ += bf2f((unsigned short)(u >> 16));
    }
    atomic_add_bf162(&agg32[(size_t)prev*64 + p], rl_, rh_);
  }
}

// ---------------------------------------------------------------- node ----
__global__ __launch_bounds__(256, 3) void node_kernel(
    const float* __restrict__ h, const float* __restrict__ coord,
    const float* __restrict__ quat,
    const unsigned short* __restrict__ aggb, const float* __restrict__ transS,
    const float* __restrict__ tanS, const float* __restrict__ cnt,
    const unsigned short* __restrict__ Wn1b, const unsigned short* __restrict__ Wn2b,
    const float* __restrict__ bn1, const float* __restrict__ bn2,
    float* __restrict__ out_h, float* __restrict__ out_c, float* __restrict__ out_q)
{
  __shared__ unsigned short A_[64][NSTR];   // nin = [h(64)|agg(128)], K=192
  __shared__ unsigned short H_[64][NHSTR];
  const int tid = threadIdx.x;
  const int n0 = blockIdx.x * 64;
  {
    const int rl_ = tid >> 2, sub = tid & 3;
    const int n = n0 + rl_;
    const int cb = sub * 48;
    if (n < N_NODES) {
      for (int j = 0; j < 48; ++j) {
        const int col = cb + j;
        A_[rl_][col] = (col < 64) ? f2bf(h[(size_t)n*64 + col])
                                  : aggb[(size_t)n*128 + (col - 64)];
      }
    } else {
      for (int j = 0; j < 48; ++j) A_[rl_][cb + j] = 0;
    }
  }
  __syncthreads();

  const int wv = tid >> 6, lane = tid & 63;
  const int lr = lane & 15, lk = lane >> 4;
  const int nrow = wv*16 + lr;
  f32x4 acc[8];

  mmW<6,8>(&A_[nrow][0], lk, Wn1b, lane, acc);
  #pragma unroll
  for (int ct = 0; ct < 8; ++ct) {
    const int ocb = ct*16 + lk*4;
    const f32x4 b4 = *(const f32x4*)&bn1[ocb];
    u16x4 pk;
    #pragma unroll
    for (int i = 0; i < 4; ++i) pk[i] = f2bf(silu_f(acc[ct][i] + b4[i]));
    *(u16x4*)&H_[nrow][ocb] = pk;
  }

  // hidden @ Wn2 (128 -> 64)
  f32x4 acc2[4];
  mmW<4,4>(&H_[nrow][0], lk, Wn2b, lane, acc2);
  const int n = n0 + nrow;
  if (n < N_NODES) {
    #pragma unroll
    for (int ct = 0; ct < 4; ++ct) {
      const int ocb = ct*16 + lk*4;
      const f32x4 b4 = *(const f32x4*)&bn2[ocb];
      const f32x4 h4 = *(const f32x4*)&h[(size_t)n*64 + ocb];
      f32x4 o;
      #pragma unroll
      for (int i = 0; i < 4; ++i) o[i] = h4[i] + acc2[ct][i] + b4[i];
      *(f32x4*)&out_h[(size_t)n*64 + ocb] = o;
    }
  }

  if (tid < 64) {
    const int nn = n0 + tid;
    if (nn < N_NODES) {
      const float cm = fmaxf(cnt[nn], 1.0f);
      const float inv = 1.0f / cm;
      out_c[nn*3+0] = coord[nn*3+0] + transS[nn*3+0]*inv;
      out_c[nn*3+1] = coord[nn*3+1] + transS[nn*3+1]*inv;
      out_c[nn*3+2] = coord[nn*3+2] + transS[nn*3+2]*inv;
      const float ix = tanS[nn*3+0]*inv, iy = tanS[nn*3+1]*inv, iz = tanS[nn*3+2]*inv;
      const float rr = sqrtf(ix*ix + iy*iy + iz*iz);
      const float s = sinf(rr) / rr;
      const float rx = ix*s, ry = iy*s, rz = iz*s, rw = cosf(rr);
      const float px = quat[nn*4+0], py = quat[nn*4+1], pz = quat[nn*4+2], pw = quat[nn*4+3];
      out_q[nn*4+0] = pw*rx + px*rw + py*rz - pz*ry;
      out_q[nn*4+1] = pw*ry - px*rz + py*rw + pz*rx;
      out_q[nn*4+2] = pw*rz + px*ry - py*rx + pz*rw;
      out_q[nn*4+3] = pw*rw - px*rx - py*ry - pz*rz;
    }
  }
}

// -------------------------------------------------------------- launch ----
extern "C" void kernel_launch(void* const* d_in, const int* in_sizes, int n_in,
                              void* d_out, int out_size, void* d_ws, size_t ws_size,
                              hipStream_t stream) {
  (void)in_sizes; (void)n_in; (void)out_size; (void)ws_size;
  const float* h     = (const float*)d_in[0];
  const int*   ei    = (const int*)d_in[1];
  const float* coord = (const float*)d_in[2];
  const float* quat  = (const float*)d_in[3];
  const float* We1 = (const float*)d_in[4];  const float* be1 = (const float*)d_in[5];
  const float* We2 = (const float*)d_in[6];  const float* be2 = (const float*)d_in[7];
  const float* Wn1 = (const float*)d_in[8];  const float* bn1 = (const float*)d_in[9];
  const float* Wn2 = (const float*)d_in[10]; const float* bn2 = (const float*)d_in[11];
  const float* Wc1 = (const float*)d_in[12]; const float* bc1 = (const float*)d_in[13];
  const float* wc2 = (const float*)d_in[14];
  const float* Wq1 = (const float*)d_in[15]; const float* bq1 = (const float*)d_in[16];
  const float* Wq2 = (const float*)d_in[17]; const float* bq2 = (const float*)d_in[18];

  // Compact layout — total ~18.8 MB (R4-proven).
  char* ws = (char*)d_ws;
  unsigned int* agg32  = (unsigned int*)(ws);           // bf16x2 [N][64]: 12,800,000
  unsigned short* aggb = (unsigned short*)(ws);         // same bytes as bf16 [N][128]
  float* transS = (float*)(ws + 12800000);              //    600,000
  float* tanS   = (float*)(ws + 13400000);              //    600,000
  float* cnt    = (float*)(ws + 14000000);              //    200,000
  int*   cursor = (int*)  (ws + 14200000);              //    200,000 (memset ends 14.4MB)
  int*   offs   = (int*)  (ws + 14400000);              //    200,004
  int*   perm   = (int*)  (ws + 14600064);              //  3,200,000
  float* qi     = (float*)(ws + 17800064);              //    800,000
  unsigned short* We1b = (unsigned short*)(ws + 18600064);
  unsigned short* We2b = We1b + 5*8*64*8;
  unsigned short* Wc1b = We2b + 4*8*64*8;
  unsigned short* Wq1b = Wc1b + 4*8*64*8;
  unsigned short* Wn1b = Wq1b + 4*8*64*8;
  unsigned short* Wn2b = Wn1b + 6*8*64*8;               // ends ~18.81 MB

  hipMemsetAsync(ws, 0, 14400000, stream);  // agg+transS+tanS+cnt+cursor
  qinv_kernel<<<(N_NODES + 255)/256, 256, 0, stream>>>(quat, qi);
  swz_kernel<<<(5*8*64 + 255)/256, 256, 0, stream>>>(We1, We1b, 136, 128, 5, 8);
  swz_kernel<<<(4*8*64 + 255)/256, 256, 0, stream>>>(We2, We2b, 128, 128, 4, 8);
  swz_kernel<<<(4*8*64 + 255)/256, 256, 0, stream>>>(Wc1, Wc1b, 128, 128, 4, 8);
  swz_kernel<<<(4*8*64 + 255)/256, 256, 0, stream>>>(Wq1, Wq1b, 128, 128, 4, 8);
  swz_kernel<<<(6*8*64 + 255)/256, 256, 0, stream>>>(Wn1, Wn1b, 192, 128, 6, 8);
  swz_kernel<<<(4*4*64 + 255)/256, 256, 0, stream>>>(Wn2, Wn2b, 128, 64, 4, 4);
  hist_kernel<<<(N_EDGES + 255)/256, 256, 0, stream>>>(ei, cursor);
  scan_kernel<<<1, 1024, 0, stream>>>(cursor, offs);
  scatter_kernel<<<(N_EDGES + 255)/256, 256, 0, stream>>>(ei, cursor, perm);

  edge_kernel<<<N_EDGES/64, 256, 0, stream>>>(
      h, ei, coord, quat, qi, perm, We1b, We2b, Wc1b, Wq1b,
      be1, be2, bc1, wc2, bq1, Wq2, bq2, agg32, transS, tanS, cnt);

  float* out_h = (float*)d_out;
  float* out_c = out_h + (size_t)N_NODES*64;
  float* out_q = out_c + (size_t)N_NODES*3;
  node_kernel<<<(N_NODES + 63)/64, 256, 0, stream>>>(
      h, coord, quat, aggb, transS, tanS, cnt, Wn1b, Wn2b, bn1, bn2,
      out_h, out_c, out_q);
}

// Round 6
// 671.392 us; speedup vs baseline: 8.5351x; 1.4424x over previous
//
#include <hip/hip_runtime.h>
#include <hip/hip_bf16.h>
#include <math.h>

// FEGCL_46127948759594 — E(3)-equivariant GCL on MI355X.
// R6: fully wave-local edge kernel (no barriers, no rows_s/cdv LDS),
// per-wave distributed build, segmented shuffle-scan -> tail-lane scalar
// atomics (kills 16-way same-address bursts), 4 blocks/CU, setprio on MFMA.

#define N_NODES 50000
#define N_EDGES 800000
#define ASTR 172   // A/F row stride in shorts
#define HSTR 140   // H row stride in shorts
#define NSTR 204   // node A stride
#define NHSTR 140  // node H stride

typedef __attribute__((ext_vector_type(4))) float f32x4;
typedef __attribute__((ext_vector_type(8))) short bf16x8;
typedef __attribute__((ext_vector_type(4))) unsigned short u16x4;
typedef __attribute__((ext_vector_type(8))) unsigned short u16x8;

static __device__ __forceinline__ unsigned short f2bf(float f) {
  return __builtin_bit_cast(unsigned short, __float2bfloat16(f));
}
static __device__ __forceinline__ float bf2f(unsigned short s) {
  unsigned int u = ((unsigned int)s) << 16;
  return __builtin_bit_cast(float, u);
}
static __device__ __forceinline__ float silu_f(float x) {
  return x / (1.0f + __expf(-x));
}
static __device__ __forceinline__ void atomic_add_bf162(unsigned int* addr,
                                                        float lo, float hi) {
  unsigned int old = *addr, assumed;
  do {
    assumed = old;
    float clo = bf2f((unsigned short)(assumed & 0xffffu)) + lo;
    float chi = bf2f((unsigned short)(assumed >> 16)) + hi;
    unsigned int nv = ((unsigned int)f2bf(chi) << 16) | (unsigned int)f2bf(clo);
    old = atomicCAS(addr, assumed, nv);
  } while (old != assumed);
}

// ---------------------------------------------------------------- prep ----
__global__ void qinv_kernel(const float* __restrict__ quat, float* __restrict__ qi) {
  int n = blockIdx.x * blockDim.x + threadIdx.x;
  if (n >= N_NODES) return;
  float x = quat[n*4+0], y = quat[n*4+1], z = quat[n*4+2], w = quat[n*4+3];
  float inv = 1.0f / (x*x + y*y + z*z + w*w);
  qi[n*4+0] = -x*inv; qi[n*4+1] = -y*inv; qi[n*4+2] = -z*inv; qi[n*4+3] = w*inv;
}

__global__ void hist_kernel(const int* __restrict__ ei, int* __restrict__ cursor) {
  int e = blockIdx.x * blockDim.x + threadIdx.x;
  if (e < N_EDGES) atomicAdd(&cursor[ei[e]], 1);
}

__global__ void scan_kernel(int* __restrict__ cursor, int* __restrict__ offsets) {
  __shared__ int s[1024];
  const int t = threadIdx.x;
  const int C = 49;
  const int base = t * C;
  int sum = 0;
  for (int i = 0; i < C; ++i) {
    int n = base + i;
    if (n < N_NODES) sum += cursor[n];
  }
  s[t] = sum;
  __syncthreads();
  for (int d = 1; d < 1024; d <<= 1) {
    int v = (t >= d) ? s[t - d] : 0;
    __syncthreads();
    s[t] += v;
    __syncthreads();
  }
  int run = s[t] - sum;
  for (int i = 0; i < C; ++i) {
    int n = base + i;
    if (n < N_NODES) {
      int d = cursor[n];
      offsets[n] = run;
      cursor[n] = run;
      run += d;
    }
  }
  if (t == 1023) offsets[N_NODES] = run;
}

__global__ void scatter_kernel(const int* __restrict__ ei, int* __restrict__ cursor,
                               int* __restrict__ perm) {
  int e = blockIdx.x * blockDim.x + threadIdx.x;
  if (e < N_EDGES) {
    int r = ei[e];
    int pos = atomicAdd(&cursor[r], 1);
    perm[pos] = e;
  }
}

__global__ void swz_kernel(const float* __restrict__ src, unsigned short* __restrict__ dst,
                           int K, int NOUT, int KT, int NCT) {
  int idx = blockIdx.x * blockDim.x + threadIdx.x;
  if (idx >= KT * NCT * 64) return;
  int lane = idx & 63, blk = idx >> 6;
  int ct = blk % NCT, kt = blk / NCT;
  int col = ct * 16 + (lane & 15);
  int kb = kt * 32 + (lane >> 4) * 8;
  u16x8 o;
  #pragma unroll
  for (int j = 0; j < 8; ++j) {
    int k = kb + j;
    o[j] = (k < K) ? f2bf(src[(size_t)k * NOUT + col]) : (unsigned short)0;
  }
  *(u16x8*)(dst + (size_t)idx * 8) = o;
}

// Weights-as-A GEMM (R5-proven): D col = edge (lane&15),
// D rows = outcols ct*16 + (lane>>4)*4 + i.
template <int KT, int NCT>
static __device__ __forceinline__ void mmW(const unsigned short* __restrict__ arow, int lk,
                                           const unsigned short* __restrict__ Wb, int lane,
                                           f32x4* acc) {
  const f32x4 zero = {0.f, 0.f, 0.f, 0.f};
  #pragma unroll
  for (int ct = 0; ct < NCT; ++ct) acc[ct] = zero;
  __builtin_amdgcn_s_setprio(1);
  #pragma unroll
  for (int kt = 0; kt < KT; ++kt) {
    bf16x8 act = *(const bf16x8*)(arow + kt*32 + lk*8);
    const u16x8* bb = (const u16x8*)Wb + (size_t)(kt*NCT)*64 + lane;
    #pragma unroll
    for (int ct = 0; ct < NCT; ++ct) {
      bf16x8 w = *(const bf16x8*)(bb + (size_t)ct*64);
      acc[ct] = __builtin_amdgcn_mfma_f32_16x16x32_bf16(w, act, acc[ct], 0, 0, 0);
    }
  }
  __builtin_amdgcn_s_setprio(0);
}

// ---------------------------------------------------------------- edge ----
__global__ __launch_bounds__(256, 4) void edge_kernel(
    const float* __restrict__ h, const int* __restrict__ ei,
    const float* __restrict__ coord, const float* __restrict__ quat,
    const float* __restrict__ qi, const int* __restrict__ perm,
    const unsigned short* __restrict__ We1b, const unsigned short* __restrict__ We2b,
    const unsigned short* __restrict__ Wc1b, const unsigned short* __restrict__ Wq1b,
    const float* __restrict__ be1, const float* __restrict__ be2,
    const float* __restrict__ bc1, const float* __restrict__ wc2,
    const float* __restrict__ bq1, const float* __restrict__ Wq2,
    const float* __restrict__ bq2,
    unsigned int* __restrict__ agg32, float* __restrict__ transS,
    float* __restrict__ tanS, float* __restrict__ cnt)
{
  // All LDS rows are wave-private (wave wv owns rows wv*16..wv*16+15) ->
  // ZERO barriers; same-wave cross-lane LDS RAW ordered by compiler lgkmcnt.
  __shared__ __align__(16) unsigned short smem[64*ASTR + 64*HSTR];  // 39936 B
  unsigned short* AF = smem;
  unsigned short* Hb = smem + 64*ASTR;

  const int tid = threadIdx.x;
  const int wv = tid >> 6, lane = tid & 63;
  const int lr = lane & 15, lk = lane >> 4;
  const int erow = wv*16 + lr;       // this lane's edge row
  const int e0 = blockIdx.x * 64;

  const int ge = perm[e0 + erow];
  const int r = ei[ge], c = ei[N_EDGES + ge];

  // ---- h staging: lane (lr,lk) writes 32-col chunk lk of edge erow
  {
    const float* hs = h + (size_t)(lk < 2 ? r : c) * 64 + (lk & 1) * 32;
    const int cb = lk * 32;
    #pragma unroll
    for (int j = 0; j < 32; j += 4) {
      f32x4 v = *(const f32x4*)(hs + j);
      u16x4 p;
      p[0] = f2bf(v[0]); p[1] = f2bf(v[1]); p[2] = f2bf(v[2]); p[3] = f2bf(v[3]);
      *(u16x4*)&AF[erow*ASTR + cb + j] = p;
    }
  }
  // coord diff (all lanes keep all 3 for the scalar phase)
  const float cdx = coord[r*3+0] - coord[c*3+0];
  const float cdy = coord[r*3+1] - coord[c*3+1];
  const float cdz = coord[r*3+2] - coord[c*3+2];
  if (lk == 0) {
    // geometry features for this wave's edge erow (16 lanes, parallel)
    const float radial = cdx*cdx + cdy*cdy + cdz*cdz;
    const float nrm = sqrtf(radial) + 1e-8f;
    const f32x4 q4 = *(const f32x4*)&qi[r*4];
    const f32x4 qc4 = *(const f32x4*)&quat[c*4];
    const float qix = q4[0], qiy = q4[1], qiz = q4[2], qiw = q4[3];
    const float qcx = qc4[0], qcy = qc4[1], qcz = qc4[2], qcw = qc4[3];
    const float qpx = qiw*qcx + qix*qcw + qiy*qcz - qiz*qcy;
    const float qpy = qiw*qcy - qix*qcz + qiy*qcw + qiz*qcx;
    const float qpz = qiw*qcz + qix*qcy - qiy*qcx + qiz*qcw;
    const float qpw = qiw*qcw - qix*qcx - qiy*qcy - qiz*qcz;
    const float vx = cdx / nrm, vy = cdy / nrm, vz = cdz / nrm;
    const float tx = 2.f*(qiy*vz - qiz*vy);
    const float ty = 2.f*(qiz*vx - qix*vz);
    const float tz = 2.f*(qix*vy - qiy*vx);
    const float ux = -(vx + qiw*tx + (qiy*tz - qiz*ty));
    const float uy = -(vy + qiw*ty + (qiz*tx - qix*tz));
    const float uz = -(vz + qiw*tz + (qix*ty - qiy*tx));
    u16x4 f0, f1;
    f0[0] = f2bf(radial); f0[1] = f2bf(qpx); f0[2] = f2bf(qpy); f0[3] = f2bf(qpz);
    f1[0] = f2bf(qpw);    f1[1] = f2bf(ux);  f1[2] = f2bf(uy);  f1[3] = f2bf(uz);
    *(u16x4*)&AF[erow*ASTR + 128] = f0;
    *(u16x4*)&AF[erow*ASTR + 132] = f1;
    const u16x4 z4 = {0, 0, 0, 0};
    #pragma unroll
    for (int j = 136; j < 160; j += 4) *(u16x4*)&AF[erow*ASTR + j] = z4;
  }

  f32x4 acc[8];

  // ---- GEMM1: silu(ein @ We1 + be1) -> H
  mmW<5,8>(AF + erow*ASTR, lk, We1b, lane, acc);
  #pragma unroll
  for (int ct = 0; ct < 8; ++ct) {
    const int ocb = ct*16 + lk*4;
    const f32x4 b4 = *(const f32x4*)&be1[ocb];
    u16x4 pk;
    #pragma unroll
    for (int i = 0; i < 4; ++i) pk[i] = f2bf(silu_f(acc[ct][i] + b4[i]));
    *(u16x4*)&Hb[erow*HSTR + ocb] = pk;
  }

  // ---- GEMM2: silu(H @ We2 + be2) -> F (aliased over A)
  mmW<4,8>(Hb + erow*HSTR, lk, We2b, lane, acc);
  #pragma unroll
  for (int ct = 0; ct < 8; ++ct) {
    const int ocb = ct*16 + lk*4;
    const f32x4 b4 = *(const f32x4*)&be2[ocb];
    u16x4 pk;
    #pragma unroll
    for (int i = 0; i < 4; ++i) pk[i] = f2bf(silu_f(acc[ct][i] + b4[i]));
    *(u16x4*)&AF[erow*ASTR + ocb] = pk;
  }

  // ---- GEMM3: (silu(F @ Wc1 + bc1)) . wc2 -> per-edge scalar
  float pcs = 0.f;
  mmW<4,8>(AF + erow*ASTR, lk, Wc1b, lane, acc);
  #pragma unroll
  for (int ct = 0; ct < 8; ++ct) {
    const int ocb = ct*16 + lk*4;
    const f32x4 b4 = *(const f32x4*)&bc1[ocb];
    const f32x4 w4 = *(const f32x4*)&wc2[ocb];
    #pragma unroll
    for (int i = 0; i < 4; ++i) pcs += silu_f(acc[ct][i] + b4[i]) * w4[i];
  }
  pcs += __shfl_xor(pcs, 16);
  pcs += __shfl_xor(pcs, 32);

  // ---- GEMM4: silu(F @ Wq1 + bq1) @ Wq2 -> per-edge 3-vec
  float p0 = 0.f, p1 = 0.f, p2 = 0.f;
  mmW<4,8>(AF + erow*ASTR, lk, Wq1b, lane, acc);
  #pragma unroll
  for (int ct = 0; ct < 8; ++ct) {
    const int ocb = ct*16 + lk*4;
    const f32x4 b4 = *(const f32x4*)&bq1[ocb];
    const float* wq = &Wq2[ocb*3];
    const f32x4 qa = *(const f32x4*)(wq);
    const f32x4 qb = *(const f32x4*)(wq + 4);
    const f32x4 qc = *(const f32x4*)(wq + 8);
    const float v0 = silu_f(acc[ct][0] + b4[0]);
    const float v1 = silu_f(acc[ct][1] + b4[1]);
    const float v2 = silu_f(acc[ct][2] + b4[2]);
    const float v3 = silu_f(acc[ct][3] + b4[3]);
    p0 += v0*qa[0] + v1*qa[3] + v2*qb[2] + v3*qc[1];
    p1 += v0*qa[1] + v1*qb[0] + v2*qb[3] + v3*qc[2];
    p2 += v0*qa[2] + v1*qb[1] + v2*qc[0] + v3*qc[3];
  }
  p0 += __shfl_xor(p0, 16);  p0 += __shfl_xor(p0, 32);
  p1 += __shfl_xor(p1, 16);  p1 += __shfl_xor(p1, 32);
  p2 += __shfl_xor(p2, 16);  p2 += __shfl_xor(p2, 32);

  // ---- scalar side: segmented scan over the wave's 16 row-sorted edges,
  // one atomic per (segment x scalar) from the tail lane.
  {
    const int rUp = __shfl_up(r, 1, 16);
    const int rDn = __shfl_down(r, 1, 16);
    const bool head = (lr == 0) || (rUp != r);
    const bool tail = (lr == 15) || (rDn != r);
    float v1, v2;
    if (lk == 3) { v1 = 1.0f; v2 = 0.f; }
    else {
      const float cdj = (lk == 0) ? cdx : ((lk == 1) ? cdy : cdz);
      const float pj  = (lk == 0) ? p0  : ((lk == 1) ? p1  : p2);
      v1 = cdj * pcs;
      v2 = pj + bq2[lk];
    }
    int f = head ? 1 : 0;
    #pragma unroll
    for (int d = 1; d < 16; d <<= 1) {
      const float o1 = __shfl_up(v1, d, 16);
      const float o2 = __shfl_up(v2, d, 16);
      const int   of = __shfl_up(f,  d, 16);
      if (lr >= d) {
        if (!f) { v1 += o1; v2 += o2; }
        f |= of;
      }
    }
    if (tail) {
      if (lk == 3) {
        atomicAdd(&cnt[r], v1);
      } else {
        atomicAdd(&transS[r*3 + lk], v1);
        atomicAdd(&tanS[r*3 + lk], v2);
      }
    }
  }

  // ---- column reduce: per-wave segmented accumulate of F into agg (bf16 CAS)
  {
    float rl_ = 0.f, rh_ = 0.f;
    int prev = __shfl(r, 0, 16);
    #pragma unroll
    for (int k2 = 0; k2 < 16; ++k2) {
      const int rr = __shfl(r, k2, 16);
      if (rr != prev) {
        atomic_add_bf162(&agg32[(size_t)prev*64 + lane], rl_, rh_);
        rl_ = 0.f; rh_ = 0.f; prev = rr;
      }
      const unsigned int u = *(const unsigned int*)&AF[(wv*16 + k2)*ASTR + 2*lane];
      rl_ += bf2f((unsigned short)(u & 0xffffu));
      rh_ += bf2f((unsigned short)(u >> 16));
    }
    atomic_add_bf162(&agg32[(size_t)prev*64 + lane], rl_, rh_);
  }
}

// ---------------------------------------------------------------- node ----
__global__ __launch_bounds__(256, 3) void node_kernel(
    const float* __restrict__ h, const float* __restrict__ coord,
    const float* __restrict__ quat,
    const unsigned short* __restrict__ aggb, const float* __restrict__ transS,
    const float* __restrict__ tanS, const float* __restrict__ cnt,
    const unsigned short* __restrict__ Wn1b, const unsigned short* __restrict__ Wn2b,
    const float* __restrict__ bn1, const float* __restrict__ bn2,
    float* __restrict__ out_h, float* __restrict__ out_c, float* __restrict__ out_q)
{
  __shared__ unsigned short A_[64][NSTR];   // [h(64)|agg(128)], wave-private rows
  __shared__ unsigned short H_[64][NHSTR];
  const int tid = threadIdx.x;
  const int n0 = blockIdx.x * 64;

  // build: 4 lanes/row; sub0/1: h halves (f32x4->bf16), sub2/3: agg halves (copy)
  {
    const int row = tid >> 2, sub = tid & 3;
    const int n = n0 + row;
    if (n < N_NODES) {
      if (sub < 2) {
        const float* hp = h + (size_t)n*64 + sub*32;
        #pragma unroll
        for (int j = 0; j < 32; j += 4) {
          f32x4 v = *(const f32x4*)(hp + j);
          u16x4 p;
          p[0] = f2bf(v[0]); p[1] = f2bf(v[1]); p[2] = f2bf(v[2]); p[3] = f2bf(v[3]);
          *(u16x4*)&A_[row][sub*32 + j] = p;
        }
      } else {
        const unsigned short* ap = aggb + (size_t)n*128 + (sub - 2)*64;
        #pragma unroll
        for (int j = 0; j < 64; j += 8)
          *(u16x8*)&A_[row][64 + (sub - 2)*64 + j] = *(const u16x8*)(ap + j);
      }
    } else {
      const u16x4 z4 = {0, 0, 0, 0};
      if (sub < 2) {
        #pragma unroll
        for (int j = 0; j < 32; j += 4) *(u16x4*)&A_[row][sub*32 + j] = z4;
      } else {
        #pragma unroll
        for (int j = 0; j < 64; j += 4) *(u16x4*)&A_[row][64 + (sub - 2)*64 + j] = z4;
      }
    }
  }

  const int wv = tid >> 6, lane = tid & 63;
  const int lr = lane & 15, lk = lane >> 4;
  const int nrow = wv*16 + lr;
  f32x4 acc[8];

  mmW<6,8>(&A_[nrow][0], lk, Wn1b, lane, acc);
  #pragma unroll
  for (int ct = 0; ct < 8; ++ct) {
    const int ocb = ct*16 + lk*4;
    const f32x4 b4 = *(const f32x4*)&bn1[ocb];
    u16x4 pk;
    #pragma unroll
    for (int i = 0; i < 4; ++i) pk[i] = f2bf(silu_f(acc[ct][i] + b4[i]));
    *(u16x4*)&H_[nrow][ocb] = pk;
  }

  f32x4 acc2[4];
  mmW<4,4>(&H_[nrow][0], lk, Wn2b, lane, acc2);
  const int n = n0 + nrow;
  if (n < N_NODES) {
    #pragma unroll
    for (int ct = 0; ct < 4; ++ct) {
      const int ocb = ct*16 + lk*4;
      const f32x4 b4 = *(const f32x4*)&bn2[ocb];
      const f32x4 h4 = *(const f32x4*)&h[(size_t)n*64 + ocb];
      f32x4 o;
      #pragma unroll
      for (int i = 0; i < 4; ++i) o[i] = h4[i] + acc2[ct][i] + b4[i];
      *(f32x4*)&out_h[(size_t)n*64 + ocb] = o;
    }
  }

  if (tid < 64) {
    const int nn = n0 + tid;
    if (nn < N_NODES) {
      const float cm = fmaxf(cnt[nn], 1.0f);
      const float inv = 1.0f / cm;
      out_c[nn*3+0] = coord[nn*3+0] + transS[nn*3+0]*inv;
      out_c[nn*3+1] = coord[nn*3+1] + transS[nn*3+1]*inv;
      out_c[nn*3+2] = coord[nn*3+2] + transS[nn*3+2]*inv;
      const float ix = tanS[nn*3+0]*inv, iy = tanS[nn*3+1]*inv, iz = tanS[nn*3+2]*inv;
      const float rr = sqrtf(ix*ix + iy*iy + iz*iz);
      const float s = sinf(rr) / rr;
      const float rx = ix*s, ry = iy*s, rz = iz*s, rw = cosf(rr);
      const float px = quat[nn*4+0], py = quat[nn*4+1], pz = quat[nn*4+2], pw = quat[nn*4+3];
      out_q[nn*4+0] = pw*rx + px*rw + py*rz - pz*ry;
      out_q[nn*4+1] = pw*ry - px*rz + py*rw + pz*rx;
      out_q[nn*4+2] = pw*rz + px*ry - py*rx + pz*rw;
      out_q[nn*4+3] = pw*rw - px*rx - py*ry - pz*rz;
    }
  }
}

// -------------------------------------------------------------- launch ----
extern "C" void kernel_launch(void* const* d_in, const int* in_sizes, int n_in,
                              void* d_out, int out_size, void* d_ws, size_t ws_size,
                              hipStream_t stream) {
  (void)in_sizes; (void)n_in; (void)out_size; (void)ws_size;
  const float* h     = (const float*)d_in[0];
  const int*   ei    = (const int*)d_in[1];
  const float* coord = (const float*)d_in[2];
  const float* quat  = (const float*)d_in[3];
  const float* We1 = (const float*)d_in[4];  const float* be1 = (const float*)d_in[5];
  const float* We2 = (const float*)d_in[6];  const float* be2 = (const float*)d_in[7];
  const float* Wn1 = (const float*)d_in[8];  const float* bn1 = (const float*)d_in[9];
  const float* Wn2 = (const float*)d_in[10]; const float* bn2 = (const float*)d_in[11];
  const float* Wc1 = (const float*)d_in[12]; const float* bc1 = (const float*)d_in[13];
  const float* wc2 = (const float*)d_in[14];
  const float* Wq1 = (const float*)d_in[15]; const float* bq1 = (const float*)d_in[16];
  const float* Wq2 = (const float*)d_in[17]; const float* bq2 = (const float*)d_in[18];

  // Compact layout — total ~18.8 MB (R4-proven safe).
  char* ws = (char*)d_ws;
  unsigned int* agg32  = (unsigned int*)(ws);           // bf16x2 [N][64]: 12,800,000
  unsigned short* aggb = (unsigned short*)(ws);         // same bytes as bf16 [N][128]
  float* transS = (float*)(ws + 12800000);              //    600,000
  float* tanS   = (float*)(ws + 13400000);              //    600,000
  float* cnt    = (float*)(ws + 14000000);              //    200,000
  int*   cursor = (int*)  (ws + 14200000);              //    200,000 (memset ends 14.4MB)
  int*   offs   = (int*)  (ws + 14400000);              //    200,004
  int*   perm   = (int*)  (ws + 14600064);              //  3,200,000
  float* qi     = (float*)(ws + 17800064);              //    800,000
  unsigned short* We1b = (unsigned short*)(ws + 18600064);
  unsigned short* We2b = We1b + 5*8*64*8;
  unsigned short* Wc1b = We2b + 4*8*64*8;
  unsigned short* Wq1b = Wc1b + 4*8*64*8;
  unsigned short* Wn1b = Wq1b + 4*8*64*8;
  unsigned short* Wn2b = Wn1b + 6*8*64*8;               // ends ~18.81 MB

  hipMemsetAsync(ws, 0, 14400000, stream);  // agg+transS+tanS+cnt+cursor
  qinv_kernel<<<(N_NODES + 255)/256, 256, 0, stream>>>(quat, qi);
  swz_kernel<<<(5*8*64 + 255)/256, 256, 0, stream>>>(We1, We1b, 136, 128, 5, 8);
  swz_kernel<<<(4*8*64 + 255)/256, 256, 0, stream>>>(We2, We2b, 128, 128, 4, 8);
  swz_kernel<<<(4*8*64 + 255)/256, 256, 0, stream>>>(Wc1, Wc1b, 128, 128, 4, 8);
  swz_kernel<<<(4*8*64 + 255)/256, 256, 0, stream>>>(Wq1, Wq1b, 128, 128, 4, 8);
  swz_kernel<<<(6*8*64 + 255)/256, 256, 0, stream>>>(Wn1, Wn1b, 192, 128, 6, 8);
  swz_kernel<<<(4*4*64 + 255)/256, 256, 0, stream>>>(Wn2, Wn2b, 128, 64, 4, 4);
  hist_kernel<<<(N_EDGES + 255)/256, 256, 0, stream>>>(ei, cursor);
  scan_kernel<<<1, 1024, 0, stream>>>(cursor, offs);
  scatter_kernel<<<(N_EDGES + 255)/256, 256, 0, stream>>>(ei, cursor, perm);

  edge_kernel<<<N_EDGES/64, 256, 0, stream>>>(
      h, ei, coord, quat, qi, perm, We1b, We2b, Wc1b, Wq1b,
      be1, be2, bc1, wc2, bq1, Wq2, bq2, agg32, transS, tanS, cnt);

  float* out_h = (float*)d_out;
  float* out_c = out_h + (size_t)N_NODES*64;
  float* out_q = out_c + (size_t)N_NODES*3;
  node_kernel<<<(N_NODES + 63)/64, 256, 0, stream>>>(
      h, coord, quat, aggb, transS, tanS, cnt, Wn1b, Wn2b, bn1, bn2,
      out_h, out_c, out_q);
}

// Round 7
// 658.678 us; speedup vs baseline: 8.6999x; 1.0193x over previous
//
#include <hip/hip_runtime.h>
#include <hip/hip_bf16.h>
#include <math.h>

// FEGCL_46127948759594 — E(3)-equivariant GCL on MI355X.
// R7: silu via v_rcp (kills precise-divide sequences, ~8 VALU ops/silu saved),
// in-place H/F over A (one LDS buffer, 22KB -> 6 blocks/CU), qinv = conj(quat)
// inline (input quats are normalized; qinv kernel + qi buffer deleted).

#define N_NODES 50000
#define N_EDGES 800000
#define ASTR 172   // single A/H/F row stride in shorts
#define NSTR 204   // node A stride (in-place H too)

typedef __attribute__((ext_vector_type(4))) float f32x4;
typedef __attribute__((ext_vector_type(8))) short bf16x8;
typedef __attribute__((ext_vector_type(4))) unsigned short u16x4;
typedef __attribute__((ext_vector_type(8))) unsigned short u16x8;

static __device__ __forceinline__ unsigned short f2bf(float f) {
  return __builtin_bit_cast(unsigned short, __float2bfloat16(f));
}
static __device__ __forceinline__ float bf2f(unsigned short s) {
  unsigned int u = ((unsigned int)s) << 16;
  return __builtin_bit_cast(float, u);
}
// silu via v_rcp_f32: ~5 VALU ops, 1-ulp rcp (bf16-irrelevant), correct at +-inf.
static __device__ __forceinline__ float silu_f(float x) {
  return x * __builtin_amdgcn_rcpf(1.0f + __expf(-x));
}
static __device__ __forceinline__ void atomic_add_bf162(unsigned int* addr,
                                                        float lo, float hi) {
  unsigned int old = *addr, assumed;
  do {
    assumed = old;
    float clo = bf2f((unsigned short)(assumed & 0xffffu)) + lo;
    float chi = bf2f((unsigned short)(assumed >> 16)) + hi;
    unsigned int nv = ((unsigned int)f2bf(chi) << 16) | (unsigned int)f2bf(clo);
    old = atomicCAS(addr, assumed, nv);
  } while (old != assumed);
}

// ---------------------------------------------------------------- prep ----
__global__ void hist_kernel(const int* __restrict__ ei, int* __restrict__ cursor) {
  int e = blockIdx.x * blockDim.x + threadIdx.x;
  if (e < N_EDGES) atomicAdd(&cursor[ei[e]], 1);
}

__global__ void scan_kernel(int* __restrict__ cursor, int* __restrict__ offsets) {
  __shared__ int s[1024];
  const int t = threadIdx.x;
  const int C = 49;
  const int base = t * C;
  int sum = 0;
  for (int i = 0; i < C; ++i) {
    int n = base + i;
    if (n < N_NODES) sum += cursor[n];
  }
  s[t] = sum;
  __syncthreads();
  for (int d = 1; d < 1024; d <<= 1) {
    int v = (t >= d) ? s[t - d] : 0;
    __syncthreads();
    s[t] += v;
    __syncthreads();
  }
  int run = s[t] - sum;
  for (int i = 0; i < C; ++i) {
    int n = base + i;
    if (n < N_NODES) {
      int d = cursor[n];
      offsets[n] = run;
      cursor[n] = run;
      run += d;
    }
  }
  if (t == 1023) offsets[N_NODES] = run;
}

__global__ void scatter_kernel(const int* __restrict__ ei, int* __restrict__ cursor,
                               int* __restrict__ perm) {
  int e = blockIdx.x * blockDim.x + threadIdx.x;
  if (e < N_EDGES) {
    int r = ei[e];
    int pos = atomicAdd(&cursor[r], 1);
    perm[pos] = e;
  }
}

__global__ void swz_kernel(const float* __restrict__ src, unsigned short* __restrict__ dst,
                           int K, int NOUT, int KT, int NCT) {
  int idx = blockIdx.x * blockDim.x + threadIdx.x;
  if (idx >= KT * NCT * 64) return;
  int lane = idx & 63, blk = idx >> 6;
  int ct = blk % NCT, kt = blk / NCT;
  int col = ct * 16 + (lane & 15);
  int kb = kt * 32 + (lane >> 4) * 8;
  u16x8 o;
  #pragma unroll
  for (int j = 0; j < 8; ++j) {
    int k = kb + j;
    o[j] = (k < K) ? f2bf(src[(size_t)k * NOUT + col]) : (unsigned short)0;
  }
  *(u16x8*)(dst + (size_t)idx * 8) = o;
}

// Weights-as-A GEMM (R5-proven): D col = edge (lane&15),
// D rows = outcols ct*16 + (lane>>4)*4 + i.
template <int KT, int NCT>
static __device__ __forceinline__ void mmW(const unsigned short* __restrict__ arow, int lk,
                                           const unsigned short* __restrict__ Wb, int lane,
                                           f32x4* acc) {
  const f32x4 zero = {0.f, 0.f, 0.f, 0.f};
  #pragma unroll
  for (int ct = 0; ct < NCT; ++ct) acc[ct] = zero;
  __builtin_amdgcn_s_setprio(1);
  #pragma unroll
  for (int kt = 0; kt < KT; ++kt) {
    bf16x8 act = *(const bf16x8*)(arow + kt*32 + lk*8);
    const u16x8* bb = (const u16x8*)Wb + (size_t)(kt*NCT)*64 + lane;
    #pragma unroll
    for (int ct = 0; ct < NCT; ++ct) {
      bf16x8 w = *(const bf16x8*)(bb + (size_t)ct*64);
      acc[ct] = __builtin_amdgcn_mfma_f32_16x16x32_bf16(w, act, acc[ct], 0, 0, 0);
    }
  }
  __builtin_amdgcn_s_setprio(0);
}

// ---------------------------------------------------------------- edge ----
__global__ __launch_bounds__(256, 6) void edge_kernel(
    const float* __restrict__ h, const int* __restrict__ ei,
    const float* __restrict__ coord, const float* __restrict__ quat,
    const int* __restrict__ perm,
    const unsigned short* __restrict__ We1b, const unsigned short* __restrict__ We2b,
    const unsigned short* __restrict__ Wc1b, const unsigned short* __restrict__ Wq1b,
    const float* __restrict__ be1, const float* __restrict__ be2,
    const float* __restrict__ bc1, const float* __restrict__ wc2,
    const float* __restrict__ bq1, const float* __restrict__ Wq2,
    const float* __restrict__ bq2,
    unsigned int* __restrict__ agg32, float* __restrict__ transS,
    float* __restrict__ tanS, float* __restrict__ cnt)
{
  // ONE LDS region: ein (160 cols) -> H (128, in-place) -> F (128, in-place).
  // In-place is order-safe: every epilogue value depends (via the MFMA acc
  // chain) on ALL of the wave's ds_reads of that buffer, and per-wave LDS ops
  // execute in program order. All rows wave-private -> zero barriers.
  __shared__ __align__(16) unsigned short AF[64 * ASTR];  // 22016 B

  const int tid = threadIdx.x;
  const int wv = tid >> 6, lane = tid & 63;
  const int lr = lane & 15, lk = lane >> 4;
  const int erow = wv*16 + lr;
  const int e0 = blockIdx.x * 64;

  const int ge = perm[e0 + erow];
  const int r = ei[ge], c = ei[N_EDGES + ge];

  // ---- h staging: lane (lr,lk) writes 32-col chunk lk of edge erow
  {
    const float* hs = h + (size_t)(lk < 2 ? r : c) * 64 + (lk & 1) * 32;
    const int cb = lk * 32;
    #pragma unroll
    for (int j = 0; j < 32; j += 4) {
      f32x4 v = *(const f32x4*)(hs + j);
      u16x4 p;
      p[0] = f2bf(v[0]); p[1] = f2bf(v[1]); p[2] = f2bf(v[2]); p[3] = f2bf(v[3]);
      *(u16x4*)&AF[erow*ASTR + cb + j] = p;
    }
  }
  const float cdx = coord[r*3+0] - coord[c*3+0];
  const float cdy = coord[r*3+1] - coord[c*3+1];
  const float cdz = coord[r*3+2] - coord[c*3+2];
  if (lk == 0) {
    // geometry for this wave's edge erow; qinv = conj(quat[r]) (unit quats)
    const float radial = cdx*cdx + cdy*cdy + cdz*cdz;
    const float nrm = sqrtf(radial) + 1e-8f;
    const f32x4 qr4 = *(const f32x4*)&quat[r*4];
    const f32x4 qc4 = *(const f32x4*)&quat[c*4];
    const float qix = -qr4[0], qiy = -qr4[1], qiz = -qr4[2], qiw = qr4[3];
    const float qcx = qc4[0], qcy = qc4[1], qcz = qc4[2], qcw = qc4[3];
    const float qpx = qiw*qcx + qix*qcw + qiy*qcz - qiz*qcy;
    const float qpy = qiw*qcy - qix*qcz + qiy*qcw + qiz*qcx;
    const float qpz = qiw*qcz + qix*qcy - qiy*qcx + qiz*qcw;
    const float qpw = qiw*qcw - qix*qcx - qiy*qcy - qiz*qcz;
    const float rinv = __builtin_amdgcn_rcpf(nrm);
    const float vx = cdx*rinv, vy = cdy*rinv, vz = cdz*rinv;
    const float tx = 2.f*(qiy*vz - qiz*vy);
    const float ty = 2.f*(qiz*vx - qix*vz);
    const float tz = 2.f*(qix*vy - qiy*vx);
    const float ux = -(vx + qiw*tx + (qiy*tz - qiz*ty));
    const float uy = -(vy + qiw*ty + (qiz*tx - qix*tz));
    const float uz = -(vz + qiw*tz + (qix*ty - qiy*tx));
    u16x4 f0, f1;
    f0[0] = f2bf(radial); f0[1] = f2bf(qpx); f0[2] = f2bf(qpy); f0[3] = f2bf(qpz);
    f1[0] = f2bf(qpw);    f1[1] = f2bf(ux);  f1[2] = f2bf(uy);  f1[3] = f2bf(uz);
    *(u16x4*)&AF[erow*ASTR + 128] = f0;
    *(u16x4*)&AF[erow*ASTR + 132] = f1;
    const u16x4 z4 = {0, 0, 0, 0};
    #pragma unroll
    for (int j = 136; j < 160; j += 4) *(u16x4*)&AF[erow*ASTR + j] = z4;
  }

  f32x4 acc[8];

  // ---- GEMM1: silu(ein @ We1 + be1) -> H (in place over A[0:128])
  mmW<5,8>(AF + erow*ASTR, lk, We1b, lane, acc);
  #pragma unroll
  for (int ct = 0; ct < 8; ++ct) {
    const int ocb = ct*16 + lk*4;
    const f32x4 b4 = *(const f32x4*)&be1[ocb];
    u16x4 pk;
    #pragma unroll
    for (int i = 0; i < 4; ++i) pk[i] = f2bf(silu_f(acc[ct][i] + b4[i]));
    *(u16x4*)&AF[erow*ASTR + ocb] = pk;
  }

  // ---- GEMM2: silu(H @ We2 + be2) -> F (in place again)
  mmW<4,8>(AF + erow*ASTR, lk, We2b, lane, acc);
  #pragma unroll
  for (int ct = 0; ct < 8; ++ct) {
    const int ocb = ct*16 + lk*4;
    const f32x4 b4 = *(const f32x4*)&be2[ocb];
    u16x4 pk;
    #pragma unroll
    for (int i = 0; i < 4; ++i) pk[i] = f2bf(silu_f(acc[ct][i] + b4[i]));
    *(u16x4*)&AF[erow*ASTR + ocb] = pk;
  }

  // ---- GEMM3: (silu(F @ Wc1 + bc1)) . wc2 -> per-edge scalar
  float pcs = 0.f;
  mmW<4,8>(AF + erow*ASTR, lk, Wc1b, lane, acc);
  #pragma unroll
  for (int ct = 0; ct < 8; ++ct) {
    const int ocb = ct*16 + lk*4;
    const f32x4 b4 = *(const f32x4*)&bc1[ocb];
    const f32x4 w4 = *(const f32x4*)&wc2[ocb];
    #pragma unroll
    for (int i = 0; i < 4; ++i) pcs += silu_f(acc[ct][i] + b4[i]) * w4[i];
  }
  pcs += __shfl_xor(pcs, 16);
  pcs += __shfl_xor(pcs, 32);

  // ---- GEMM4: silu(F @ Wq1 + bq1) @ Wq2 -> per-edge 3-vec
  float p0 = 0.f, p1 = 0.f, p2 = 0.f;
  mmW<4,8>(AF + erow*ASTR, lk, Wq1b, lane, acc);
  #pragma unroll
  for (int ct = 0; ct < 8; ++ct) {
    const int ocb = ct*16 + lk*4;
    const f32x4 b4 = *(const f32x4*)&bq1[ocb];
    const float* wq = &Wq2[ocb*3];
    const f32x4 qa = *(const f32x4*)(wq);
    const f32x4 qb = *(const f32x4*)(wq + 4);
    const f32x4 qc = *(const f32x4*)(wq + 8);
    const float v0 = silu_f(acc[ct][0] + b4[0]);
    const float v1 = silu_f(acc[ct][1] + b4[1]);
    const float v2 = silu_f(acc[ct][2] + b4[2]);
    const float v3 = silu_f(acc[ct][3] + b4[3]);
    p0 += v0*qa[0] + v1*qa[3] + v2*qb[2] + v3*qc[1];
    p1 += v0*qa[1] + v1*qb[0] + v2*qb[3] + v3*qc[2];
    p2 += v0*qa[2] + v1*qb[1] + v2*qc[0] + v3*qc[3];
  }
  p0 += __shfl_xor(p0, 16);  p0 += __shfl_xor(p0, 32);
  p1 += __shfl_xor(p1, 16);  p1 += __shfl_xor(p1, 32);
  p2 += __shfl_xor(p2, 16);  p2 += __shfl_xor(p2, 32);

  // ---- scalar side: 16-lane segmented scan, tail-lane atomics
  {
    const int rUp = __shfl_up(r, 1, 16);
    const int rDn = __shfl_down(r, 1, 16);
    const bool head = (lr == 0) || (rUp != r);
    const bool tail = (lr == 15) || (rDn != r);
    float v1, v2;
    if (lk == 3) { v1 = 1.0f; v2 = 0.f; }
    else {
      const float cdj = (lk == 0) ? cdx : ((lk == 1) ? cdy : cdz);
      const float pj  = (lk == 0) ? p0  : ((lk == 1) ? p1  : p2);
      v1 = cdj * pcs;
      v2 = pj + bq2[lk];
    }
    int f = head ? 1 : 0;
    #pragma unroll
    for (int d = 1; d < 16; d <<= 1) {
      const float o1 = __shfl_up(v1, d, 16);
      const float o2 = __shfl_up(v2, d, 16);
      const int   of = __shfl_up(f,  d, 16);
      if (lr >= d) {
        if (!f) { v1 += o1; v2 += o2; }
        f |= of;
      }
    }
    if (tail) {
      if (lk == 3) {
        atomicAdd(&cnt[r], v1);
      } else {
        atomicAdd(&transS[r*3 + lk], v1);
        atomicAdd(&tanS[r*3 + lk], v2);
      }
    }
  }

  // ---- column reduce: per-wave segmented accumulate of F into agg (bf16 CAS)
  {
    float rl_ = 0.f, rh_ = 0.f;
    int prev = __shfl(r, 0, 16);
    #pragma unroll
    for (int k2 = 0; k2 < 16; ++k2) {
      const int rr = __shfl(r, k2, 16);
      if (rr != prev) {
        atomic_add_bf162(&agg32[(size_t)prev*64 + lane], rl_, rh_);
        rl_ = 0.f; rh_ = 0.f; prev = rr;
      }
      const unsigned int u = *(const unsigned int*)&AF[(wv*16 + k2)*ASTR + 2*lane];
      rl_ += bf2f((unsigned short)(u & 0xffffu));
      rh_ += bf2f((unsigned short)(u >> 16));
    }
    atomic_add_bf162(&agg32[(size_t)prev*64 + lane], rl_, rh_);
  }
}

// ---------------------------------------------------------------- node ----
__global__ __launch_bounds__(256, 4) void node_kernel(
    const float* __restrict__ h, const float* __restrict__ coord,
    const float* __restrict__ quat,
    const unsigned short* __restrict__ aggb, const float* __restrict__ transS,
    const float* __restrict__ tanS, const float* __restrict__ cnt,
    const unsigned short* __restrict__ Wn1b, const unsigned short* __restrict__ Wn2b,
    const float* __restrict__ bn1, const float* __restrict__ bn2,
    float* __restrict__ out_h, float* __restrict__ out_c, float* __restrict__ out_q)
{
  __shared__ unsigned short A_[64][NSTR];   // [h(64)|agg(128)], H in place
  const int tid = threadIdx.x;
  const int n0 = blockIdx.x * 64;

  {
    const int row = tid >> 2, sub = tid & 3;
    const int n = n0 + row;
    if (n < N_NODES) {
      if (sub < 2) {
        const float* hp = h + (size_t)n*64 + sub*32;
        #pragma unroll
        for (int j = 0; j < 32; j += 4) {
          f32x4 v = *(const f32x4*)(hp + j);
          u16x4 p;
          p[0] = f2bf(v[0]); p[1] = f2bf(v[1]); p[2] = f2bf(v[2]); p[3] = f2bf(v[3]);
          *(u16x4*)&A_[row][sub*32 + j] = p;
        }
      } else {
        const unsigned short* ap = aggb + (size_t)n*128 + (sub - 2)*64;
        #pragma unroll
        for (int j = 0; j < 64; j += 8)
          *(u16x8*)&A_[row][64 + (sub - 2)*64 + j] = *(const u16x8*)(ap + j);
      }
    } else {
      const u16x4 z4 = {0, 0, 0, 0};
      if (sub < 2) {
        #pragma unroll
        for (int j = 0; j < 32; j += 4) *(u16x4*)&A_[row][sub*32 + j] = z4;
      } else {
        #pragma unroll
        for (int j = 0; j < 64; j += 4) *(u16x4*)&A_[row][64 + (sub - 2)*64 + j] = z4;
      }
    }
  }
  __syncthreads();   // build used 4 lanes/row across wave boundaries

  const int wv = tid >> 6, lane = tid & 63;
  const int lr = lane & 15, lk = lane >> 4;
  const int nrow = wv*16 + lr;
  f32x4 acc[8];

  mmW<6,8>(&A_[nrow][0], lk, Wn1b, lane, acc);
  #pragma unroll
  for (int ct = 0; ct < 8; ++ct) {
    const int ocb = ct*16 + lk*4;
    const f32x4 b4 = *(const f32x4*)&bn1[ocb];
    u16x4 pk;
    #pragma unroll
    for (int i = 0; i < 4; ++i) pk[i] = f2bf(silu_f(acc[ct][i] + b4[i]));
    *(u16x4*)&A_[nrow][ocb] = pk;    // H in place over A[0:128]
  }

  f32x4 acc2[4];
  mmW<4,4>(&A_[nrow][0], lk, Wn2b, lane, acc2);
  const int n = n0 + nrow;
  if (n < N_NODES) {
    #pragma unroll
    for (int ct = 0; ct < 4; ++ct) {
      const int ocb = ct*16 + lk*4;
      const f32x4 b4 = *(const f32x4*)&bn2[ocb];
      const f32x4 h4 = *(const f32x4*)&h[(size_t)n*64 + ocb];
      f32x4 o;
      #pragma unroll
      for (int i = 0; i < 4; ++i) o[i] = h4[i] + acc2[ct][i] + b4[i];
      *(f32x4*)&out_h[(size_t)n*64 + ocb] = o;
    }
  }

  if (tid < 64) {
    const int nn = n0 + tid;
    if (nn < N_NODES) {
      const float cm = fmaxf(cnt[nn], 1.0f);
      const float inv = 1.0f / cm;
      out_c[nn*3+0] = coord[nn*3+0] + transS[nn*3+0]*inv;
      out_c[nn*3+1] = coord[nn*3+1] + transS[nn*3+1]*inv;
      out_c[nn*3+2] = coord[nn*3+2] + transS[nn*3+2]*inv;
      const float ix = tanS[nn*3+0]*inv, iy = tanS[nn*3+1]*inv, iz = tanS[nn*3+2]*inv;
      const float rr = sqrtf(ix*ix + iy*iy + iz*iz);
      const float s = sinf(rr) / rr;
      const float rx = ix*s, ry = iy*s, rz = iz*s, rw = cosf(rr);
      const float px = quat[nn*4+0], py = quat[nn*4+1], pz = quat[nn*4+2], pw = quat[nn*4+3];
      out_q[nn*4+0] = pw*rx + px*rw + py*rz - pz*ry;
      out_q[nn*4+1] = pw*ry - px*rz + py*rw + pz*rx;
      out_q[nn*4+2] = pw*rz + px*ry - py*rx + pz*rw;
      out_q[nn*4+3] = pw*rw - px*rx - py*ry - pz*rz;
    }
  }
}

// -------------------------------------------------------------- launch ----
extern "C" void kernel_launch(void* const* d_in, const int* in_sizes, int n_in,
                              void* d_out, int out_size, void* d_ws, size_t ws_size,
                              hipStream_t stream) {
  (void)in_sizes; (void)n_in; (void)out_size; (void)ws_size;
  const float* h     = (const float*)d_in[0];
  const int*   ei    = (const int*)d_in[1];
  const float* coord = (const float*)d_in[2];
  const float* quat  = (const float*)d_in[3];
  const float* We1 = (const float*)d_in[4];  const float* be1 = (const float*)d_in[5];
  const float* We2 = (const float*)d_in[6];  const float* be2 = (const float*)d_in[7];
  const float* Wn1 = (const float*)d_in[8];  const float* bn1 = (const float*)d_in[9];
  const float* Wn2 = (const float*)d_in[10]; const float* bn2 = (const float*)d_in[11];
  const float* Wc1 = (const float*)d_in[12]; const float* bc1 = (const float*)d_in[13];
  const float* wc2 = (const float*)d_in[14];
  const float* Wq1 = (const float*)d_in[15]; const float* bq1 = (const float*)d_in[16];
  const float* Wq2 = (const float*)d_in[17]; const float* bq2 = (const float*)d_in[18];

  // Compact layout — total ~18.0 MB (R4-proven safe envelope).
  char* ws = (char*)d_ws;
  unsigned int* agg32  = (unsigned int*)(ws);           // bf16x2 [N][64]: 12,800,000
  unsigned short* aggb = (unsigned short*)(ws);         // same bytes as bf16 [N][128]
  float* transS = (float*)(ws + 12800000);              //    600,000
  float* tanS   = (float*)(ws + 13400000);              //    600,000
  float* cnt    = (float*)(ws + 14000000);              //    200,000
  int*   cursor = (int*)  (ws + 14200000);              //    200,000 (memset ends 14.4MB)
  int*   offs   = (int*)  (ws + 14400000);              //    200,004
  int*   perm   = (int*)  (ws + 14600064);              //  3,200,000
  unsigned short* We1b = (unsigned short*)(ws + 17800064);
  unsigned short* We2b = We1b + 5*8*64*8;
  unsigned short* Wc1b = We2b + 4*8*64*8;
  unsigned short* Wq1b = Wc1b + 4*8*64*8;
  unsigned short* Wn1b = Wq1b + 4*8*64*8;
  unsigned short* Wn2b = Wn1b + 6*8*64*8;               // ends ~18.0 MB

  hipMemsetAsync(ws, 0, 14400000, stream);  // agg+transS+tanS+cnt+cursor
  swz_kernel<<<(5*8*64 + 255)/256, 256, 0, stream>>>(We1, We1b, 136, 128, 5, 8);
  swz_kernel<<<(4*8*64 + 255)/256, 256, 0, stream>>>(We2, We2b, 128, 128, 4, 8);
  swz_kernel<<<(4*8*64 + 255)/256, 256, 0, stream>>>(Wc1, Wc1b, 128, 128, 4, 8);
  swz_kernel<<<(4*8*64 + 255)/256, 256, 0, stream>>>(Wq1, Wq1b, 128, 128, 4, 8);
  swz_kernel<<<(6*8*64 + 255)/256, 256, 0, stream>>>(Wn1, Wn1b, 192, 128, 6, 8);
  swz_kernel<<<(4*4*64 + 255)/256, 256, 0, stream>>>(Wn2, Wn2b, 128, 64, 4, 4);
  hist_kernel<<<(N_EDGES + 255)/256, 256, 0, stream>>>(ei, cursor);
  scan_kernel<<<1, 1024, 0, stream>>>(cursor, offs);
  scatter_kernel<<<(N_EDGES + 255)/256, 256, 0, stream>>>(ei, cursor, perm);

  edge_kernel<<<N_EDGES/64, 256, 0, stream>>>(
      h, ei, coord, quat, perm, We1b, We2b, Wc1b, Wq1b,
      be1, be2, bc1, wc2, bq1, Wq2, bq2, agg32, transS, tanS, cnt);

  float* out_h = (float*)d_out;
  float* out_c = out_h + (size_t)N_NODES*64;
  float* out_q = out_c + (size_t)N_NODES*3;
  node_kernel<<<(N_NODES + 63)/64, 256, 0, stream>>>(
      h, coord, quat, aggb, transS, tanS, cnt, Wn1b, Wn2b, bn1, bn2,
      out_h, out_c, out_q);
}

// Round 8
// 631.954 us; speedup vs baseline: 9.0678x; 1.0423x over previous
//
#include <hip/hip_runtime.h>
#include <hip/hip_bf16.h>
#include <math.h>

// FEGCL_46127948759594 — E(3)-equivariant GCL on MI355X.
// R8: agg accumulation via fire-and-forget global_atomic_pk_add_bf16 (kills
// CAS read+retry round trips -> ~450MB/dispatch of HBM line ping-pong), plus
// bijective block swizzle (bid*2003 mod 12500) so concurrent blocks hit
// disjoint agg rows. 7 blocks/CU. Rest identical to R7.

#define N_NODES 50000
#define N_EDGES 800000
#define ASTR 172   // single A/H/F row stride in shorts
#define NSTR 204   // node A stride (in-place H too)

typedef __attribute__((ext_vector_type(4))) float f32x4;
typedef __attribute__((ext_vector_type(8))) short bf16x8;
typedef __attribute__((ext_vector_type(4))) unsigned short u16x4;
typedef __attribute__((ext_vector_type(8))) unsigned short u16x8;

static __device__ __forceinline__ unsigned short f2bf(float f) {
  return __builtin_bit_cast(unsigned short, __float2bfloat16(f));
}
static __device__ __forceinline__ float bf2f(unsigned short s) {
  unsigned int u = ((unsigned int)s) << 16;
  return __builtin_bit_cast(float, u);
}
// silu via v_rcp_f32 (R7-proven)
static __device__ __forceinline__ float silu_f(float x) {
  return x * __builtin_amdgcn_rcpf(1.0f + __expf(-x));
}
// Fire-and-forget packed-bf16 atomic add (no return -> no fetch, no retry).
static __device__ __forceinline__ void atomic_pk_add_bf16(unsigned int* addr,
                                                          float lo, float hi) {
  const unsigned int pk = ((unsigned int)f2bf(hi) << 16) | (unsigned int)f2bf(lo);
  asm volatile("global_atomic_pk_add_bf16 %0, %1, off"
               :: "v"((unsigned long long)(uintptr_t)addr), "v"(pk)
               : "memory");
}

// ---------------------------------------------------------------- prep ----
__global__ void hist_kernel(const int* __restrict__ ei, int* __restrict__ cursor) {
  int e = blockIdx.x * blockDim.x + threadIdx.x;
  if (e < N_EDGES) atomicAdd(&cursor[ei[e]], 1);
}

__global__ void scan_kernel(int* __restrict__ cursor, int* __restrict__ offsets) {
  __shared__ int s[1024];
  const int t = threadIdx.x;
  const int C = 49;
  const int base = t * C;
  int sum = 0;
  for (int i = 0; i < C; ++i) {
    int n = base + i;
    if (n < N_NODES) sum += cursor[n];
  }
  s[t] = sum;
  __syncthreads();
  for (int d = 1; d < 1024; d <<= 1) {
    int v = (t >= d) ? s[t - d] : 0;
    __syncthreads();
    s[t] += v;
    __syncthreads();
  }
  int run = s[t] - sum;
  for (int i = 0; i < C; ++i) {
    int n = base + i;
    if (n < N_NODES) {
      int d = cursor[n];
      offsets[n] = run;
      cursor[n] = run;
      run += d;
    }
  }
  if (t == 1023) offsets[N_NODES] = run;
}

__global__ void scatter_kernel(const int* __restrict__ ei, int* __restrict__ cursor,
                               int* __restrict__ perm) {
  int e = blockIdx.x * blockDim.x + threadIdx.x;
  if (e < N_EDGES) {
    int r = ei[e];
    int pos = atomicAdd(&cursor[r], 1);
    perm[pos] = e;
  }
}

__global__ void swz_kernel(const float* __restrict__ src, unsigned short* __restrict__ dst,
                           int K, int NOUT, int KT, int NCT) {
  int idx = blockIdx.x * blockDim.x + threadIdx.x;
  if (idx >= KT * NCT * 64) return;
  int lane = idx & 63, blk = idx >> 6;
  int ct = blk % NCT, kt = blk / NCT;
  int col = ct * 16 + (lane & 15);
  int kb = kt * 32 + (lane >> 4) * 8;
  u16x8 o;
  #pragma unroll
  for (int j = 0; j < 8; ++j) {
    int k = kb + j;
    o[j] = (k < K) ? f2bf(src[(size_t)k * NOUT + col]) : (unsigned short)0;
  }
  *(u16x8*)(dst + (size_t)idx * 8) = o;
}

// Weights-as-A GEMM (R5-proven): D col = edge (lane&15),
// D rows = outcols ct*16 + (lane>>4)*4 + i.
template <int KT, int NCT>
static __device__ __forceinline__ void mmW(const unsigned short* __restrict__ arow, int lk,
                                           const unsigned short* __restrict__ Wb, int lane,
                                           f32x4* acc) {
  const f32x4 zero = {0.f, 0.f, 0.f, 0.f};
  #pragma unroll
  for (int ct = 0; ct < NCT; ++ct) acc[ct] = zero;
  __builtin_amdgcn_s_setprio(1);
  #pragma unroll
  for (int kt = 0; kt < KT; ++kt) {
    bf16x8 act = *(const bf16x8*)(arow + kt*32 + lk*8);
    const u16x8* bb = (const u16x8*)Wb + (size_t)(kt*NCT)*64 + lane;
    #pragma unroll
    for (int ct = 0; ct < NCT; ++ct) {
      bf16x8 w = *(const bf16x8*)(bb + (size_t)ct*64);
      acc[ct] = __builtin_amdgcn_mfma_f32_16x16x32_bf16(w, act, acc[ct], 0, 0, 0);
    }
  }
  __builtin_amdgcn_s_setprio(0);
}

// ---------------------------------------------------------------- edge ----
__global__ __launch_bounds__(256, 7) void edge_kernel(
    const float* __restrict__ h, const int* __restrict__ ei,
    const float* __restrict__ coord, const float* __restrict__ quat,
    const int* __restrict__ perm,
    const unsigned short* __restrict__ We1b, const unsigned short* __restrict__ We2b,
    const unsigned short* __restrict__ Wc1b, const unsigned short* __restrict__ Wq1b,
    const float* __restrict__ be1, const float* __restrict__ be2,
    const float* __restrict__ bc1, const float* __restrict__ wc2,
    const float* __restrict__ bq1, const float* __restrict__ Wq2,
    const float* __restrict__ bq2,
    unsigned int* __restrict__ agg32, float* __restrict__ transS,
    float* __restrict__ tanS, float* __restrict__ cnt)
{
  // ONE LDS region: ein (160 cols) -> H (128, in-place) -> F (128, in-place).
  // All rows wave-private -> zero barriers (R6/R7-proven).
  __shared__ __align__(16) unsigned short AF[64 * ASTR];  // 22016 B

  const int tid = threadIdx.x;
  const int wv = tid >> 6, lane = tid & 63;
  const int lr = lane & 15, lk = lane >> 4;
  const int erow = wv*16 + lr;
  // bijective swizzle: concurrent blocks -> distant sorted-edge ranges ->
  // disjoint agg rows (kills cross-block atomic line contention).
  const int nb = N_EDGES / 64;                        // 12500
  const int bid = (int)(((long long)blockIdx.x * 2003) % nb);
  const int e0 = bid * 64;

  const int ge = perm[e0 + erow];
  const int r = ei[ge], c = ei[N_EDGES + ge];

  // ---- h staging: lane (lr,lk) writes 32-col chunk lk of edge erow
  {
    const float* hs = h + (size_t)(lk < 2 ? r : c) * 64 + (lk & 1) * 32;
    const int cb = lk * 32;
    #pragma unroll
    for (int j = 0; j < 32; j += 4) {
      f32x4 v = *(const f32x4*)(hs + j);
      u16x4 p;
      p[0] = f2bf(v[0]); p[1] = f2bf(v[1]); p[2] = f2bf(v[2]); p[3] = f2bf(v[3]);
      *(u16x4*)&AF[erow*ASTR + cb + j] = p;
    }
  }
  const float cdx = coord[r*3+0] - coord[c*3+0];
  const float cdy = coord[r*3+1] - coord[c*3+1];
  const float cdz = coord[r*3+2] - coord[c*3+2];
  if (lk == 0) {
    // geometry for this wave's edge erow; qinv = conj(quat[r]) (unit quats)
    const float radial = cdx*cdx + cdy*cdy + cdz*cdz;
    const float nrm = sqrtf(radial) + 1e-8f;
    const f32x4 qr4 = *(const f32x4*)&quat[r*4];
    const f32x4 qc4 = *(const f32x4*)&quat[c*4];
    const float qix = -qr4[0], qiy = -qr4[1], qiz = -qr4[2], qiw = qr4[3];
    const float qcx = qc4[0], qcy = qc4[1], qcz = qc4[2], qcw = qc4[3];
    const float qpx = qiw*qcx + qix*qcw + qiy*qcz - qiz*qcy;
    const float qpy = qiw*qcy - qix*qcz + qiy*qcw + qiz*qcx;
    const float qpz = qiw*qcz + qix*qcy - qiy*qcx + qiz*qcw;
    const float qpw = qiw*qcw - qix*qcx - qiy*qcy - qiz*qcz;
    const float rinv = __builtin_amdgcn_rcpf(nrm);
    const float vx = cdx*rinv, vy = cdy*rinv, vz = cdz*rinv;
    const float tx = 2.f*(qiy*vz - qiz*vy);
    const float ty = 2.f*(qiz*vx - qix*vz);
    const float tz = 2.f*(qix*vy - qiy*vx);
    const float ux = -(vx + qiw*tx + (qiy*tz - qiz*ty));
    const float uy = -(vy + qiw*ty + (qiz*tx - qix*tz));
    const float uz = -(vz + qiw*tz + (qix*ty - qiy*tx));
    u16x4 f0, f1;
    f0[0] = f2bf(radial); f0[1] = f2bf(qpx); f0[2] = f2bf(qpy); f0[3] = f2bf(qpz);
    f1[0] = f2bf(qpw);    f1[1] = f2bf(ux);  f1[2] = f2bf(uy);  f1[3] = f2bf(uz);
    *(u16x4*)&AF[erow*ASTR + 128] = f0;
    *(u16x4*)&AF[erow*ASTR + 132] = f1;
    const u16x4 z4 = {0, 0, 0, 0};
    #pragma unroll
    for (int j = 136; j < 160; j += 4) *(u16x4*)&AF[erow*ASTR + j] = z4;
  }

  f32x4 acc[8];

  // ---- GEMM1: silu(ein @ We1 + be1) -> H (in place over A[0:128])
  mmW<5,8>(AF + erow*ASTR, lk, We1b, lane, acc);
  #pragma unroll
  for (int ct = 0; ct < 8; ++ct) {
    const int ocb = ct*16 + lk*4;
    const f32x4 b4 = *(const f32x4*)&be1[ocb];
    u16x4 pk;
    #pragma unroll
    for (int i = 0; i < 4; ++i) pk[i] = f2bf(silu_f(acc[ct][i] + b4[i]));
    *(u16x4*)&AF[erow*ASTR + ocb] = pk;
  }

  // ---- GEMM2: silu(H @ We2 + be2) -> F (in place again)
  mmW<4,8>(AF + erow*ASTR, lk, We2b, lane, acc);
  #pragma unroll
  for (int ct = 0; ct < 8; ++ct) {
    const int ocb = ct*16 + lk*4;
    const f32x4 b4 = *(const f32x4*)&be2[ocb];
    u16x4 pk;
    #pragma unroll
    for (int i = 0; i < 4; ++i) pk[i] = f2bf(silu_f(acc[ct][i] + b4[i]));
    *(u16x4*)&AF[erow*ASTR + ocb] = pk;
  }

  // ---- GEMM3: (silu(F @ Wc1 + bc1)) . wc2 -> per-edge scalar
  float pcs = 0.f;
  mmW<4,8>(AF + erow*ASTR, lk, Wc1b, lane, acc);
  #pragma unroll
  for (int ct = 0; ct < 8; ++ct) {
    const int ocb = ct*16 + lk*4;
    const f32x4 b4 = *(const f32x4*)&bc1[ocb];
    const f32x4 w4 = *(const f32x4*)&wc2[ocb];
    #pragma unroll
    for (int i = 0; i < 4; ++i) pcs += silu_f(acc[ct][i] + b4[i]) * w4[i];
  }
  pcs += __shfl_xor(pcs, 16);
  pcs += __shfl_xor(pcs, 32);

  // ---- GEMM4: silu(F @ Wq1 + bq1) @ Wq2 -> per-edge 3-vec
  float p0 = 0.f, p1 = 0.f, p2 = 0.f;
  mmW<4,8>(AF + erow*ASTR, lk, Wq1b, lane, acc);
  #pragma unroll
  for (int ct = 0; ct < 8; ++ct) {
    const int ocb = ct*16 + lk*4;
    const f32x4 b4 = *(const f32x4*)&bq1[ocb];
    const float* wq = &Wq2[ocb*3];
    const f32x4 qa = *(const f32x4*)(wq);
    const f32x4 qb = *(const f32x4*)(wq + 4);
    const f32x4 qc = *(const f32x4*)(wq + 8);
    const float v0 = silu_f(acc[ct][0] + b4[0]);
    const float v1 = silu_f(acc[ct][1] + b4[1]);
    const float v2 = silu_f(acc[ct][2] + b4[2]);
    const float v3 = silu_f(acc[ct][3] + b4[3]);
    p0 += v0*qa[0] + v1*qa[3] + v2*qb[2] + v3*qc[1];
    p1 += v0*qa[1] + v1*qb[0] + v2*qb[3] + v3*qc[2];
    p2 += v0*qa[2] + v1*qb[1] + v2*qc[0] + v3*qc[3];
  }
  p0 += __shfl_xor(p0, 16);  p0 += __shfl_xor(p0, 32);
  p1 += __shfl_xor(p1, 16);  p1 += __shfl_xor(p1, 32);
  p2 += __shfl_xor(p2, 16);  p2 += __shfl_xor(p2, 32);

  // ---- scalar side: 16-lane segmented scan, tail-lane atomics
  {
    const int rUp = __shfl_up(r, 1, 16);
    const int rDn = __shfl_down(r, 1, 16);
    const bool head = (lr == 0) || (rUp != r);
    const bool tail = (lr == 15) || (rDn != r);
    float v1, v2;
    if (lk == 3) { v1 = 1.0f; v2 = 0.f; }
    else {
      const float cdj = (lk == 0) ? cdx : ((lk == 1) ? cdy : cdz);
      const float pj  = (lk == 0) ? p0  : ((lk == 1) ? p1  : p2);
      v1 = cdj * pcs;
      v2 = pj + bq2[lk];
    }
    int f = head ? 1 : 0;
    #pragma unroll
    for (int d = 1; d < 16; d <<= 1) {
      const float o1 = __shfl_up(v1, d, 16);
      const float o2 = __shfl_up(v2, d, 16);
      const int   of = __shfl_up(f,  d, 16);
      if (lr >= d) {
        if (!f) { v1 += o1; v2 += o2; }
        f |= of;
      }
    }
    if (tail) {
      if (lk == 3) {
        atomicAdd(&cnt[r], v1);
      } else {
        atomicAdd(&transS[r*3 + lk], v1);
        atomicAdd(&tanS[r*3 + lk], v2);
      }
    }
  }

  // ---- column reduce: per-wave segmented accumulate of F into agg
  // (fire-and-forget pk_add_bf16, one packet per segment per col-pair)
  {
    float rl_ = 0.f, rh_ = 0.f;
    int prev = __shfl(r, 0, 16);
    #pragma unroll
    for (int k2 = 0; k2 < 16; ++k2) {
      const int rr = __shfl(r, k2, 16);
      if (rr != prev) {
        atomic_pk_add_bf16(&agg32[(size_t)prev*64 + lane], rl_, rh_);
        rl_ = 0.f; rh_ = 0.f; prev = rr;
      }
      const unsigned int u = *(const unsigned int*)&AF[(wv*16 + k2)*ASTR + 2*lane];
      rl_ += bf2f((unsigned short)(u & 0xffffu));
      rh_ += bf2f((unsigned short)(u >> 16));
    }
    atomic_pk_add_bf16(&agg32[(size_t)prev*64 + lane], rl_, rh_);
  }
}

// ---------------------------------------------------------------- node ----
__global__ __launch_bounds__(256, 4) void node_kernel(
    const float* __restrict__ h, const float* __restrict__ coord,
    const float* __restrict__ quat,
    const unsigned short* __restrict__ aggb, const float* __restrict__ transS,
    const float* __restrict__ tanS, const float* __restrict__ cnt,
    const unsigned short* __restrict__ Wn1b, const unsigned short* __restrict__ Wn2b,
    const float* __restrict__ bn1, const float* __restrict__ bn2,
    float* __restrict__ out_h, float* __restrict__ out_c, float* __restrict__ out_q)
{
  __shared__ unsigned short A_[64][NSTR];   // [h(64)|agg(128)], H in place
  const int tid = threadIdx.x;
  const int n0 = blockIdx.x * 64;

  {
    const int row = tid >> 2, sub = tid & 3;
    const int n = n0 + row;
    if (n < N_NODES) {
      if (sub < 2) {
        const float* hp = h + (size_t)n*64 + sub*32;
        #pragma unroll
        for (int j = 0; j < 32; j += 4) {
          f32x4 v = *(const f32x4*)(hp + j);
          u16x4 p;
          p[0] = f2bf(v[0]); p[1] = f2bf(v[1]); p[2] = f2bf(v[2]); p[3] = f2bf(v[3]);
          *(u16x4*)&A_[row][sub*32 + j] = p;
        }
      } else {
        const unsigned short* ap = aggb + (size_t)n*128 + (sub - 2)*64;
        #pragma unroll
        for (int j = 0; j < 64; j += 8)
          *(u16x8*)&A_[row][64 + (sub - 2)*64 + j] = *(const u16x8*)(ap + j);
      }
    } else {
      const u16x4 z4 = {0, 0, 0, 0};
      if (sub < 2) {
        #pragma unroll
        for (int j = 0; j < 32; j += 4) *(u16x4*)&A_[row][sub*32 + j] = z4;
      } else {
        #pragma unroll
        for (int j = 0; j < 64; j += 4) *(u16x4*)&A_[row][64 + (sub - 2)*64 + j] = z4;
      }
    }
  }
  __syncthreads();   // build used 4 lanes/row across wave boundaries

  const int wv = tid >> 6, lane = tid & 63;
  const int lr = lane & 15, lk = lane >> 4;
  const int nrow = wv*16 + lr;
  f32x4 acc[8];

  mmW<6,8>(&A_[nrow][0], lk, Wn1b, lane, acc);
  #pragma unroll
  for (int ct = 0; ct < 8; ++ct) {
    const int ocb = ct*16 + lk*4;
    const f32x4 b4 = *(const f32x4*)&bn1[ocb];
    u16x4 pk;
    #pragma unroll
    for (int i = 0; i < 4; ++i) pk[i] = f2bf(silu_f(acc[ct][i] + b4[i]));
    *(u16x4*)&A_[nrow][ocb] = pk;    // H in place over A[0:128]
  }

  f32x4 acc2[4];
  mmW<4,4>(&A_[nrow][0], lk, Wn2b, lane, acc2);
  const int n = n0 + nrow;
  if (n < N_NODES) {
    #pragma unroll
    for (int ct = 0; ct < 4; ++ct) {
      const int ocb = ct*16 + lk*4;
      const f32x4 b4 = *(const f32x4*)&bn2[ocb];
      const f32x4 h4 = *(const f32x4*)&h[(size_t)n*64 + ocb];
      f32x4 o;
      #pragma unroll
      for (int i = 0; i < 4; ++i) o[i] = h4[i] + acc2[ct][i] + b4[i];
      *(f32x4*)&out_h[(size_t)n*64 + ocb] = o;
    }
  }

  if (tid < 64) {
    const int nn = n0 + tid;
    if (nn < N_NODES) {
      const float cm = fmaxf(cnt[nn], 1.0f);
      const float inv = 1.0f / cm;
      out_c[nn*3+0] = coord[nn*3+0] + transS[nn*3+0]*inv;
      out_c[nn*3+1] = coord[nn*3+1] + transS[nn*3+1]*inv;
      out_c[nn*3+2] = coord[nn*3+2] + transS[nn*3+2]*inv;
      const float ix = tanS[nn*3+0]*inv, iy = tanS[nn*3+1]*inv, iz = tanS[nn*3+2]*inv;
      const float rr = sqrtf(ix*ix + iy*iy + iz*iz);
      const float s = sinf(rr) / rr;
      const float rx = ix*s, ry = iy*s, rz = iz*s, rw = cosf(rr);
      const float px = quat[nn*4+0], py = quat[nn*4+1], pz = quat[nn*4+2], pw = quat[nn*4+3];
      out_q[nn*4+0] = pw*rx + px*rw + py*rz - pz*ry;
      out_q[nn*4+1] = pw*ry - px*rz + py*rw + pz*rx;
      out_q[nn*4+2] = pw*rz + px*ry - py*rx + pz*rw;
      out_q[nn*4+3] = pw*rw - px*rx - py*ry - pz*rz;
    }
  }
}

// -------------------------------------------------------------- launch ----
extern "C" void kernel_launch(void* const* d_in, const int* in_sizes, int n_in,
                              void* d_out, int out_size, void* d_ws, size_t ws_size,
                              hipStream_t stream) {
  (void)in_sizes; (void)n_in; (void)out_size; (void)ws_size;
  const float* h     = (const float*)d_in[0];
  const int*   ei    = (const int*)d_in[1];
  const float* coord = (const float*)d_in[2];
  const float* quat  = (const float*)d_in[3];
  const float* We1 = (const float*)d_in[4];  const float* be1 = (const float*)d_in[5];
  const float* We2 = (const float*)d_in[6];  const float* be2 = (const float*)d_in[7];
  const float* Wn1 = (const float*)d_in[8];  const float* bn1 = (const float*)d_in[9];
  const float* Wn2 = (const float*)d_in[10]; const float* bn2 = (const float*)d_in[11];
  const float* Wc1 = (const float*)d_in[12]; const float* bc1 = (const float*)d_in[13];
  const float* wc2 = (const float*)d_in[14];
  const float* Wq1 = (const float*)d_in[15]; const float* bq1 = (const float*)d_in[16];
  const float* Wq2 = (const float*)d_in[17]; const float* bq2 = (const float*)d_in[18];

  // Compact layout — total ~18.0 MB (R4-proven safe envelope).
  char* ws = (char*)d_ws;
  unsigned int* agg32  = (unsigned int*)(ws);           // bf16x2 [N][64]: 12,800,000
  unsigned short* aggb = (unsigned short*)(ws);         // same bytes as bf16 [N][128]
  float* transS = (float*)(ws + 12800000);              //    600,000
  float* tanS   = (float*)(ws + 13400000);              //    600,000
  float* cnt    = (float*)(ws + 14000000);              //    200,000
  int*   cursor = (int*)  (ws + 14200000);              //    200,000 (memset ends 14.4MB)
  int*   offs   = (int*)  (ws + 14400000);              //    200,004
  int*   perm   = (int*)  (ws + 14600064);              //  3,200,000
  unsigned short* We1b = (unsigned short*)(ws + 17800064);
  unsigned short* We2b = We1b + 5*8*64*8;
  unsigned short* Wc1b = We2b + 4*8*64*8;
  unsigned short* Wq1b = Wc1b + 4*8*64*8;
  unsigned short* Wn1b = Wq1b + 4*8*64*8;
  unsigned short* Wn2b = Wn1b + 6*8*64*8;               // ends ~18.0 MB

  hipMemsetAsync(ws, 0, 14400000, stream);  // agg+transS+tanS+cnt+cursor
  swz_kernel<<<(5*8*64 + 255)/256, 256, 0, stream>>>(We1, We1b, 136, 128, 5, 8);
  swz_kernel<<<(4*8*64 + 255)/256, 256, 0, stream>>>(We2, We2b, 128, 128, 4, 8);
  swz_kernel<<<(4*8*64 + 255)/256, 256, 0, stream>>>(Wc1, Wc1b, 128, 128, 4, 8);
  swz_kernel<<<(4*8*64 + 255)/256, 256, 0, stream>>>(Wq1, Wq1b, 128, 128, 4, 8);
  swz_kernel<<<(6*8*64 + 255)/256, 256, 0, stream>>>(Wn1, Wn1b, 192, 128, 6, 8);
  swz_kernel<<<(4*4*64 + 255)/256, 256, 0, stream>>>(Wn2, Wn2b, 128, 64, 4, 4);
  hist_kernel<<<(N_EDGES + 255)/256, 256, 0, stream>>>(ei, cursor);
  scan_kernel<<<1, 1024, 0, stream>>>(cursor, offs);
  scatter_kernel<<<(N_EDGES + 255)/256, 256, 0, stream>>>(ei, cursor, perm);

  edge_kernel<<<N_EDGES/64, 256, 0, stream>>>(
      h, ei, coord, quat, perm, We1b, We2b, Wc1b, Wq1b,
      be1, be2, bc1, wc2, bq1, Wq2, bq2, agg32, transS, tanS, cnt);

  float* out_h = (float*)d_out;
  float* out_c = out_h + (size_t)N_NODES*64;
  float* out_q = out_c + (size_t)N_NODES*3;
  node_kernel<<<(N_NODES + 63)/64, 256, 0, stream>>>(
      h, coord, quat, aggb, transS, tanS, cnt, Wn1b, Wn2b, bn1, bn2,
      out_h, out_c, out_q);
}

// Round 9
// 524.292 us; speedup vs baseline: 10.9299x; 1.2053x over previous
//
#include <hip/hip_runtime.h>
#include <hip/hip_bf16.h>
#include <math.h>

// FEGCL_46127948759594 — E(3)-equivariant GCL on MI355X.
// R9: dual-edge-group waves (32 edges/wave, weight fragment reused 2x ->
// halves ~8GB/dispatch L2 weight traffic, doubles MFMA ILP), XCD-chunked
// bijective block swizzle (h + agg L2 locality; replaces *2003), rc2 packed
// (row,col) array from scatter (kills perm->ei gather chain).

#define N_NODES 50000
#define N_EDGES 800000
#define ASTR 172   // A/H/F row stride in shorts
#define NSTR 204   // node A stride

typedef __attribute__((ext_vector_type(4))) float f32x4;
typedef __attribute__((ext_vector_type(8))) short bf16x8;
typedef __attribute__((ext_vector_type(4))) unsigned short u16x4;
typedef __attribute__((ext_vector_type(8))) unsigned short u16x8;

static __device__ __forceinline__ unsigned short f2bf(float f) {
  return __builtin_bit_cast(unsigned short, __float2bfloat16(f));
}
static __device__ __forceinline__ float bf2f(unsigned short s) {
  unsigned int u = ((unsigned int)s) << 16;
  return __builtin_bit_cast(float, u);
}
static __device__ __forceinline__ float silu_f(float x) {
  return x * __builtin_amdgcn_rcpf(1.0f + __expf(-x));
}
static __device__ __forceinline__ void atomic_pk_add_bf16(unsigned int* addr,
                                                          float lo, float hi) {
  const unsigned int pk = ((unsigned int)f2bf(hi) << 16) | (unsigned int)f2bf(lo);
  asm volatile("global_atomic_pk_add_bf16 %0, %1, off"
               :: "v"((unsigned long long)(uintptr_t)addr), "v"(pk)
               : "memory");
}

// ---------------------------------------------------------------- prep ----
__global__ void hist_kernel(const int* __restrict__ ei, int* __restrict__ cursor) {
  int e = blockIdx.x * blockDim.x + threadIdx.x;
  if (e < N_EDGES) atomicAdd(&cursor[ei[e]], 1);
}

__global__ void scan_kernel(int* __restrict__ cursor, int* __restrict__ offsets) {
  __shared__ int s[1024];
  const int t = threadIdx.x;
  const int C = 49;
  const int base = t * C;
  int sum = 0;
  for (int i = 0; i < C; ++i) {
    int n = base + i;
    if (n < N_NODES) sum += cursor[n];
  }
  s[t] = sum;
  __syncthreads();
  for (int d = 1; d < 1024; d <<= 1) {
    int v = (t >= d) ? s[t - d] : 0;
    __syncthreads();
    s[t] += v;
    __syncthreads();
  }
  int run = s[t] - sum;
  for (int i = 0; i < C; ++i) {
    int n = base + i;
    if (n < N_NODES) {
      int d = cursor[n];
      offsets[n] = run;
      cursor[n] = run;
      run += d;
    }
  }
  if (t == 1023) offsets[N_NODES] = run;
}

// scatter writes packed (row,col) at the sorted position — edge kernel
// then needs a single 8B load per edge (no perm->ei indirection).
__global__ void scatter_kernel(const int* __restrict__ ei, int* __restrict__ cursor,
                               int2* __restrict__ rc2) {
  int e = blockIdx.x * blockDim.x + threadIdx.x;
  if (e < N_EDGES) {
    int r = ei[e];
    int pos = atomicAdd(&cursor[r], 1);
    int2 v; v.x = r; v.y = ei[N_EDGES + e];
    rc2[pos] = v;
  }
}

__global__ void swz_kernel(const float* __restrict__ src, unsigned short* __restrict__ dst,
                           int K, int NOUT, int KT, int NCT) {
  int idx = blockIdx.x * blockDim.x + threadIdx.x;
  if (idx >= KT * NCT * 64) return;
  int lane = idx & 63, blk = idx >> 6;
  int ct = blk % NCT, kt = blk / NCT;
  int col = ct * 16 + (lane & 15);
  int kb = kt * 32 + (lane >> 4) * 8;
  u16x8 o;
  #pragma unroll
  for (int j = 0; j < 8; ++j) {
    int k = kb + j;
    o[j] = (k < K) ? f2bf(src[(size_t)k * NOUT + col]) : (unsigned short)0;
  }
  *(u16x8*)(dst + (size_t)idx * 8) = o;
}

// Dual-group weights-as-A GEMM: one weight fragment feeds two MFMAs
// (edge groups g0/g1). D col = edge (lane&15), D rows = ct*16+(lane>>4)*4+i.
template <int KT, int NCT>
static __device__ __forceinline__ void mmW2(const unsigned short* __restrict__ a0,
                                            const unsigned short* __restrict__ a1,
                                            int lk,
                                            const unsigned short* __restrict__ Wb,
                                            int lane, f32x4* acc0, f32x4* acc1) {
  const f32x4 zero = {0.f, 0.f, 0.f, 0.f};
  #pragma unroll
  for (int ct = 0; ct < NCT; ++ct) { acc0[ct] = zero; acc1[ct] = zero; }
  __builtin_amdgcn_s_setprio(1);
  #pragma unroll
  for (int kt = 0; kt < KT; ++kt) {
    bf16x8 x0 = *(const bf16x8*)(a0 + kt*32 + lk*8);
    bf16x8 x1 = *(const bf16x8*)(a1 + kt*32 + lk*8);
    const u16x8* bb = (const u16x8*)Wb + (size_t)(kt*NCT)*64 + lane;
    #pragma unroll
    for (int ct = 0; ct < NCT; ++ct) {
      bf16x8 w = *(const bf16x8*)(bb + (size_t)ct*64);
      acc0[ct] = __builtin_amdgcn_mfma_f32_16x16x32_bf16(w, x0, acc0[ct], 0, 0, 0);
      acc1[ct] = __builtin_amdgcn_mfma_f32_16x16x32_bf16(w, x1, acc1[ct], 0, 0, 0);
    }
  }
  __builtin_amdgcn_s_setprio(0);
}

// ---------------------------------------------------------------- edge ----
__global__ __launch_bounds__(256, 3) void edge_kernel(
    const float* __restrict__ h,
    const float* __restrict__ coord, const float* __restrict__ quat,
    const int2* __restrict__ rc2,
    const unsigned short* __restrict__ We1b, const unsigned short* __restrict__ We2b,
    const unsigned short* __restrict__ Wc1b, const unsigned short* __restrict__ Wq1b,
    const float* __restrict__ be1, const float* __restrict__ be2,
    const float* __restrict__ bc1, const float* __restrict__ wc2,
    const float* __restrict__ bq1, const float* __restrict__ Wq2,
    const float* __restrict__ bq2,
    unsigned int* __restrict__ agg32, float* __restrict__ transS,
    float* __restrict__ tanS, float* __restrict__ cnt)
{
  // 128 edges/block; wave wv owns rows wv*32..wv*32+31 (two 16-row groups).
  // All rows wave-private -> zero barriers (R6-R8-proven in-place scheme).
  __shared__ __align__(16) unsigned short AF[128 * ASTR];  // 44032 B

  const int tid = threadIdx.x;
  const int wv = tid >> 6, lane = tid & 63;
  const int lr = lane & 15, lk = lane >> 4;
  const int row0 = wv*32 + lr, row1 = row0 + 16;

  // XCD-chunked bijective swizzle (nb=6250, q=781, rem=2): each XCD gets a
  // contiguous sorted-edge range -> h-gather + agg-atomic L2 locality.
  const int xcd = blockIdx.x & 7, idx = blockIdx.x >> 3;
  const int q = 781, rem = 2;
  const int bid = (xcd < rem ? xcd*(q+1) : rem*(q+1) + (xcd-rem)*q) + idx;
  const int e0 = bid * 128;

  const int2 p0v = rc2[e0 + row0];
  const int2 p1v = rc2[e0 + row1];
  const int r0 = p0v.x, c0 = p0v.y, r1 = p1v.x, c1 = p1v.y;

  // ---- h staging: lane (lr,lk) writes 32-col chunk lk of both its edges
  {
    const float* hs0 = h + (size_t)(lk < 2 ? r0 : c0) * 64 + (lk & 1) * 32;
    const float* hs1 = h + (size_t)(lk < 2 ? r1 : c1) * 64 + (lk & 1) * 32;
    const int cb = lk * 32;
    #pragma unroll
    for (int j = 0; j < 32; j += 4) {
      f32x4 v0 = *(const f32x4*)(hs0 + j);
      f32x4 v1 = *(const f32x4*)(hs1 + j);
      u16x4 q0, q1;
      #pragma unroll
      for (int i = 0; i < 4; ++i) { q0[i] = f2bf(v0[i]); q1[i] = f2bf(v1[i]); }
      *(u16x4*)&AF[row0*ASTR + cb + j] = q0;
      *(u16x4*)&AF[row1*ASTR + cb + j] = q1;
    }
  }
  const float cdx0 = coord[r0*3+0] - coord[c0*3+0];
  const float cdy0 = coord[r0*3+1] - coord[c0*3+1];
  const float cdz0 = coord[r0*3+2] - coord[c0*3+2];
  const float cdx1 = coord[r1*3+0] - coord[c1*3+0];
  const float cdy1 = coord[r1*3+1] - coord[c1*3+1];
  const float cdz1 = coord[r1*3+2] - coord[c1*3+2];
  if (lk < 2) {
    // lk==0 lanes: geometry for g0; lk==1 lanes: geometry for g1.
    const int gr = lk ? r1 : r0, gc = lk ? c1 : c0, grow = lk ? row1 : row0;
    const float gx = lk ? cdx1 : cdx0, gy = lk ? cdy1 : cdy0, gz = lk ? cdz1 : cdz0;
    const float radial = gx*gx + gy*gy + gz*gz;
    const float nrm = sqrtf(radial) + 1e-8f;
    const f32x4 qr4 = *(const f32x4*)&quat[gr*4];
    const f32x4 qc4 = *(const f32x4*)&quat[gc*4];
    const float qix = -qr4[0], qiy = -qr4[1], qiz = -qr4[2], qiw = qr4[3];
    const float qcx = qc4[0], qcy = qc4[1], qcz = qc4[2], qcw = qc4[3];
    const float qpx = qiw*qcx + qix*qcw + qiy*qcz - qiz*qcy;
    const float qpy = qiw*qcy - qix*qcz + qiy*qcw + qiz*qcx;
    const float qpz = qiw*qcz + qix*qcy - qiy*qcx + qiz*qcw;
    const float qpw = qiw*qcw - qix*qcx - qiy*qcy - qiz*qcz;
    const float rinv = __builtin_amdgcn_rcpf(nrm);
    const float vx = gx*rinv, vy = gy*rinv, vz = gz*rinv;
    const float tx = 2.f*(qiy*vz - qiz*vy);
    const float ty = 2.f*(qiz*vx - qix*vz);
    const float tz = 2.f*(qix*vy - qiy*vx);
    const float ux = -(vx + qiw*tx + (qiy*tz - qiz*ty));
    const float uy = -(vy + qiw*ty + (qiz*tx - qix*tz));
    const float uz = -(vz + qiw*tz + (qix*ty - qiy*tx));
    u16x4 f0, f1;
    f0[0] = f2bf(radial); f0[1] = f2bf(qpx); f0[2] = f2bf(qpy); f0[3] = f2bf(qpz);
    f1[0] = f2bf(qpw);    f1[1] = f2bf(ux);  f1[2] = f2bf(uy);  f1[3] = f2bf(uz);
    *(u16x4*)&AF[grow*ASTR + 128] = f0;
    *(u16x4*)&AF[grow*ASTR + 132] = f1;
    const u16x4 z4 = {0, 0, 0, 0};
    #pragma unroll
    for (int j = 136; j < 160; j += 4) *(u16x4*)&AF[grow*ASTR + j] = z4;
  }

  f32x4 acc0[8], acc1[8];

  // ---- GEMM1: silu(ein @ We1 + be1) -> H (in place)
  mmW2<5,8>(AF + row0*ASTR, AF + row1*ASTR, lk, We1b, lane, acc0, acc1);
  #pragma unroll
  for (int ct = 0; ct < 8; ++ct) {
    const int ocb = ct*16 + lk*4;
    const f32x4 b4 = *(const f32x4*)&be1[ocb];
    u16x4 k0, k1;
    #pragma unroll
    for (int i = 0; i < 4; ++i) {
      k0[i] = f2bf(silu_f(acc0[ct][i] + b4[i]));
      k1[i] = f2bf(silu_f(acc1[ct][i] + b4[i]));
    }
    *(u16x4*)&AF[row0*ASTR + ocb] = k0;
    *(u16x4*)&AF[row1*ASTR + ocb] = k1;
  }

  // ---- GEMM2: silu(H @ We2 + be2) -> F (in place)
  mmW2<4,8>(AF + row0*ASTR, AF + row1*ASTR, lk, We2b, lane, acc0, acc1);
  #pragma unroll
  for (int ct = 0; ct < 8; ++ct) {
    const int ocb = ct*16 + lk*4;
    const f32x4 b4 = *(const f32x4*)&be2[ocb];
    u16x4 k0, k1;
    #pragma unroll
    for (int i = 0; i < 4; ++i) {
      k0[i] = f2bf(silu_f(acc0[ct][i] + b4[i]));
      k1[i] = f2bf(silu_f(acc1[ct][i] + b4[i]));
    }
    *(u16x4*)&AF[row0*ASTR + ocb] = k0;
    *(u16x4*)&AF[row1*ASTR + ocb] = k1;
  }

  // ---- GEMM3: (silu(F @ Wc1 + bc1)) . wc2
  float pcs0 = 0.f, pcs1 = 0.f;
  mmW2<4,8>(AF + row0*ASTR, AF + row1*ASTR, lk, Wc1b, lane, acc0, acc1);
  #pragma unroll
  for (int ct = 0; ct < 8; ++ct) {
    const int ocb = ct*16 + lk*4;
    const f32x4 b4 = *(const f32x4*)&bc1[ocb];
    const f32x4 w4 = *(const f32x4*)&wc2[ocb];
    #pragma unroll
    for (int i = 0; i < 4; ++i) {
      pcs0 += silu_f(acc0[ct][i] + b4[i]) * w4[i];
      pcs1 += silu_f(acc1[ct][i] + b4[i]) * w4[i];
    }
  }
  pcs0 += __shfl_xor(pcs0, 16);  pcs0 += __shfl_xor(pcs0, 32);
  pcs1 += __shfl_xor(pcs1, 16);  pcs1 += __shfl_xor(pcs1, 32);

  // ---- GEMM4: silu(F @ Wq1 + bq1) @ Wq2
  float p00 = 0.f, p10 = 0.f, p20 = 0.f;
  float p01 = 0.f, p11 = 0.f, p21 = 0.f;
  mmW2<4,8>(AF + row0*ASTR, AF + row1*ASTR, lk, Wq1b, lane, acc0, acc1);
  #pragma unroll
  for (int ct = 0; ct < 8; ++ct) {
    const int ocb = ct*16 + lk*4;
    const f32x4 b4 = *(const f32x4*)&bq1[ocb];
    const float* wq = &Wq2[ocb*3];
    const f32x4 qa = *(const f32x4*)(wq);
    const f32x4 qb = *(const f32x4*)(wq + 4);
    const f32x4 qc = *(const f32x4*)(wq + 8);
    {
      const float v0 = silu_f(acc0[ct][0] + b4[0]);
      const float v1 = silu_f(acc0[ct][1] + b4[1]);
      const float v2 = silu_f(acc0[ct][2] + b4[2]);
      const float v3 = silu_f(acc0[ct][3] + b4[3]);
      p00 += v0*qa[0] + v1*qa[3] + v2*qb[2] + v3*qc[1];
      p10 += v0*qa[1] + v1*qb[0] + v2*qb[3] + v3*qc[2];
      p20 += v0*qa[2] + v1*qb[1] + v2*qc[0] + v3*qc[3];
    }
    {
      const float v0 = silu_f(acc1[ct][0] + b4[0]);
      const float v1 = silu_f(acc1[ct][1] + b4[1]);
      const float v2 = silu_f(acc1[ct][2] + b4[2]);
      const float v3 = silu_f(acc1[ct][3] + b4[3]);
      p01 += v0*qa[0] + v1*qa[3] + v2*qb[2] + v3*qc[1];
      p11 += v0*qa[1] + v1*qb[0] + v2*qb[3] + v3*qc[2];
      p21 += v0*qa[2] + v1*qb[1] + v2*qc[0] + v3*qc[3];
    }
  }
  p00 += __shfl_xor(p00, 16);  p00 += __shfl_xor(p00, 32);
  p10 += __shfl_xor(p10, 16);  p10 += __shfl_xor(p10, 32);
  p20 += __shfl_xor(p20, 16);  p20 += __shfl_xor(p20, 32);
  p01 += __shfl_xor(p01, 16);  p01 += __shfl_xor(p01, 32);
  p11 += __shfl_xor(p11, 16);  p11 += __shfl_xor(p11, 32);
  p21 += __shfl_xor(p21, 16);  p21 += __shfl_xor(p21, 32);

  // ---- scalar side: per-group 16-lane segmented scan, tail-lane atomics
  #pragma unroll
  for (int g = 0; g < 2; ++g) {
    const int rg = g ? r1 : r0;
    const int rUp = __shfl_up(rg, 1, 16);
    const int rDn = __shfl_down(rg, 1, 16);
    const bool head = (lr == 0) || (rUp != rg);
    const bool tail = (lr == 15) || (rDn != rg);
    float v1, v2;
    if (lk == 3) { v1 = 1.0f; v2 = 0.f; }
    else {
      const float cdj = (lk == 0) ? (g ? cdx1 : cdx0)
                      : (lk == 1) ? (g ? cdy1 : cdy0) : (g ? cdz1 : cdz0);
      const float pj  = (lk == 0) ? (g ? p01 : p00)
                      : (lk == 1) ? (g ? p11 : p10) : (g ? p21 : p20);
      v1 = cdj * (g ? pcs1 : pcs0);
      v2 = pj + bq2[lk];
    }
    int f = head ? 1 : 0;
    #pragma unroll
    for (int d = 1; d < 16; d <<= 1) {
      const float o1 = __shfl_up(v1, d, 16);
      const float o2 = __shfl_up(v2, d, 16);
      const int   of = __shfl_up(f,  d, 16);
      if (lr >= d) {
        if (!f) { v1 += o1; v2 += o2; }
        f |= of;
      }
    }
    if (tail) {
      if (lk == 3) {
        atomicAdd(&cnt[rg], v1);
      } else {
        atomicAdd(&transS[rg*3 + lk], v1);
        atomicAdd(&tanS[rg*3 + lk], v2);
      }
    }
  }

  // ---- column reduce over the wave's 32 row-sorted edges (pk_add flushes)
  {
    float rl_ = 0.f, rh_ = 0.f;
    int prev = __shfl(r0, 0, 16);
    #pragma unroll
    for (int k2 = 0; k2 < 32; ++k2) {
      const int rr = (k2 < 16) ? __shfl(r0, k2, 16) : __shfl(r1, k2 - 16, 16);
      if (rr != prev) {
        atomic_pk_add_bf16(&agg32[(size_t)prev*64 + lane], rl_, rh_);
        rl_ = 0.f; rh_ = 0.f; prev = rr;
      }
      const unsigned int u = *(const unsigned int*)&AF[(wv*32 + k2)*ASTR + 2*lane];
      rl_ += bf2f((unsigned short)(u & 0xffffu));
      rh_ += bf2f((unsigned short)(u >> 16));
    }
    atomic_pk_add_bf16(&agg32[(size_t)prev*64 + lane], rl_, rh_);
  }
}

// ---------------------------------------------------------------- node ----
__global__ __launch_bounds__(256, 4) void node_kernel(
    const float* __restrict__ h, const float* __restrict__ coord,
    const float* __restrict__ quat,
    const unsigned short* __restrict__ aggb, const float* __restrict__ transS,
    const float* __restrict__ tanS, const float* __restrict__ cnt,
    const unsigned short* __restrict__ Wn1b, const unsigned short* __restrict__ Wn2b,
    const float* __restrict__ bn1, const float* __restrict__ bn2,
    float* __restrict__ out_h, float* __restrict__ out_c, float* __restrict__ out_q)
{
  __shared__ unsigned short A_[64][NSTR];   // [h(64)|agg(128)], H in place
  const int tid = threadIdx.x;
  const int n0 = blockIdx.x * 64;

  {
    const int row = tid >> 2, sub = tid & 3;
    const int n = n0 + row;
    if (n < N_NODES) {
      if (sub < 2) {
        const float* hp = h + (size_t)n*64 + sub*32;
        #pragma unroll
        for (int j = 0; j < 32; j += 4) {
          f32x4 v = *(const f32x4*)(hp + j);
          u16x4 p;
          p[0] = f2bf(v[0]); p[1] = f2bf(v[1]); p[2] = f2bf(v[2]); p[3] = f2bf(v[3]);
          *(u16x4*)&A_[row][sub*32 + j] = p;
        }
      } else {
        const unsigned short* ap = aggb + (size_t)n*128 + (sub - 2)*64;
        #pragma unroll
        for (int j = 0; j < 64; j += 8)
          *(u16x8*)&A_[row][64 + (sub - 2)*64 + j] = *(const u16x8*)(ap + j);
      }
    } else {
      const u16x4 z4 = {0, 0, 0, 0};
      if (sub < 2) {
        #pragma unroll
        for (int j = 0; j < 32; j += 4) *(u16x4*)&A_[row][sub*32 + j] = z4;
      } else {
        #pragma unroll
        for (int j = 0; j < 64; j += 4) *(u16x4*)&A_[row][64 + (sub - 2)*64 + j] = z4;
      }
    }
  }
  __syncthreads();

  const int wv = tid >> 6, lane = tid & 63;
  const int lr = lane & 15, lk = lane >> 4;
  const int nrow = wv*16 + lr;
  f32x4 acc[8];

  // single-group helper inline (node GEMMs are cheap)
  {
    const f32x4 zero = {0.f, 0.f, 0.f, 0.f};
    #pragma unroll
    for (int ct = 0; ct < 8; ++ct) acc[ct] = zero;
    #pragma unroll
    for (int kt = 0; kt < 6; ++kt) {
      bf16x8 act = *(const bf16x8*)&A_[nrow][kt*32 + lk*8];
      const u16x8* bb = (const u16x8*)Wn1b + (size_t)(kt*8)*64 + lane;
      #pragma unroll
      for (int ct = 0; ct < 8; ++ct) {
        bf16x8 w = *(const bf16x8*)(bb + (size_t)ct*64);
        acc[ct] = __builtin_amdgcn_mfma_f32_16x16x32_bf16(w, act, acc[ct], 0, 0, 0);
      }
    }
  }
  #pragma unroll
  for (int ct = 0; ct < 8; ++ct) {
    const int ocb = ct*16 + lk*4;
    const f32x4 b4 = *(const f32x4*)&bn1[ocb];
    u16x4 pk;
    #pragma unroll
    for (int i = 0; i < 4; ++i) pk[i] = f2bf(silu_f(acc[ct][i] + b4[i]));
    *(u16x4*)&A_[nrow][ocb] = pk;
  }

  f32x4 acc2[4];
  {
    const f32x4 zero = {0.f, 0.f, 0.f, 0.f};
    #pragma unroll
    for (int ct = 0; ct < 4; ++ct) acc2[ct] = zero;
    #pragma unroll
    for (int kt = 0; kt < 4; ++kt) {
      bf16x8 act = *(const bf16x8*)&A_[nrow][kt*32 + lk*8];
      const u16x8* bb = (const u16x8*)Wn2b + (size_t)(kt*4)*64 + lane;
      #pragma unroll
      for (int ct = 0; ct < 4; ++ct) {
        bf16x8 w = *(const bf16x8*)(bb + (size_t)ct*64);
        acc2[ct] = __builtin_amdgcn_mfma_f32_16x16x32_bf16(w, act, acc2[ct], 0, 0, 0);
      }
    }
  }
  const int n = n0 + nrow;
  if (n < N_NODES) {
    #pragma unroll
    for (int ct = 0; ct < 4; ++ct) {
      const int ocb = ct*16 + lk*4;
      const f32x4 b4 = *(const f32x4*)&bn2[ocb];
      const f32x4 h4 = *(const f32x4*)&h[(size_t)n*64 + ocb];
      f32x4 o;
      #pragma unroll
      for (int i = 0; i < 4; ++i) o[i] = h4[i] + acc2[ct][i] + b4[i];
      *(f32x4*)&out_h[(size_t)n*64 + ocb] = o;
    }
  }

  if (tid < 64) {
    const int nn = n0 + tid;
    if (nn < N_NODES) {
      const float cm = fmaxf(cnt[nn], 1.0f);
      const float inv = 1.0f / cm;
      out_c[nn*3+0] = coord[nn*3+0] + transS[nn*3+0]*inv;
      out_c[nn*3+1] = coord[nn*3+1] + transS[nn*3+1]*inv;
      out_c[nn*3+2] = coord[nn*3+2] + transS[nn*3+2]*inv;
      const float ix = tanS[nn*3+0]*inv, iy = tanS[nn*3+1]*inv, iz = tanS[nn*3+2]*inv;
      const float rr = sqrtf(ix*ix + iy*iy + iz*iz);
      const float s = sinf(rr) / rr;
      const float rx = ix*s, ry = iy*s, rz = iz*s, rw = cosf(rr);
      const float px = quat[nn*4+0], py = quat[nn*4+1], pz = quat[nn*4+2], pw = quat[nn*4+3];
      out_q[nn*4+0] = pw*rx + px*rw + py*rz - pz*ry;
      out_q[nn*4+1] = pw*ry - px*rz + py*rw + pz*rx;
      out_q[nn*4+2] = pw*rz + px*ry - py*rx + pz*rw;
      out_q[nn*4+3] = pw*rw - px*rx - py*ry - pz*rz;
    }
  }
}

// -------------------------------------------------------------- launch ----
extern "C" void kernel_launch(void* const* d_in, const int* in_sizes, int n_in,
                              void* d_out, int out_size, void* d_ws, size_t ws_size,
                              hipStream_t stream) {
  (void)in_sizes; (void)n_in; (void)out_size; (void)ws_size;
  const float* h     = (const float*)d_in[0];
  const int*   ei    = (const int*)d_in[1];
  const float* coord = (const float*)d_in[2];
  const float* quat  = (const float*)d_in[3];
  const float* We1 = (const float*)d_in[4];  const float* be1 = (const float*)d_in[5];
  const float* We2 = (const float*)d_in[6];  const float* be2 = (const float*)d_in[7];
  const float* Wn1 = (const float*)d_in[8];  const float* bn1 = (const float*)d_in[9];
  const float* Wn2 = (const float*)d_in[10]; const float* bn2 = (const float*)d_in[11];
  const float* Wc1 = (const float*)d_in[12]; const float* bc1 = (const float*)d_in[13];
  const float* wc2 = (const float*)d_in[14];
  const float* Wq1 = (const float*)d_in[15]; const float* bq1 = (const float*)d_in[16];
  const float* Wq2 = (const float*)d_in[17]; const float* bq2 = (const float*)d_in[18];

  // Compact layout — total ~21.2 MB (< R1-proven 28 MB envelope).
  char* ws = (char*)d_ws;
  unsigned int* agg32  = (unsigned int*)(ws);           // bf16x2 [N][64]: 12,800,000
  unsigned short* aggb = (unsigned short*)(ws);         // same bytes as bf16 [N][128]
  float* transS = (float*)(ws + 12800000);              //    600,000
  float* tanS   = (float*)(ws + 13400000);              //    600,000
  float* cnt    = (float*)(ws + 14000000);              //    200,000
  int*   cursor = (int*)  (ws + 14200000);              //    200,000 (memset ends 14.4MB)
  int*   offs   = (int*)  (ws + 14400000);              //    200,004
  int2*  rc2    = (int2*) (ws + 14600064);              //  6,400,000
  unsigned short* We1b = (unsigned short*)(ws + 21000064);
  unsigned short* We2b = We1b + 5*8*64*8;
  unsigned short* Wc1b = We2b + 4*8*64*8;
  unsigned short* Wq1b = Wc1b + 4*8*64*8;
  unsigned short* Wn1b = Wq1b + 4*8*64*8;
  unsigned short* Wn2b = Wn1b + 6*8*64*8;               // ends ~21.2 MB

  hipMemsetAsync(ws, 0, 14400000, stream);  // agg+transS+tanS+cnt+cursor
  swz_kernel<<<(5*8*64 + 255)/256, 256, 0, stream>>>(We1, We1b, 136, 128, 5, 8);
  swz_kernel<<<(4*8*64 + 255)/256, 256, 0, stream>>>(We2, We2b, 128, 128, 4, 8);
  swz_kernel<<<(4*8*64 + 255)/256, 256, 0, stream>>>(Wc1, Wc1b, 128, 128, 4, 8);
  swz_kernel<<<(4*8*64 + 255)/256, 256, 0, stream>>>(Wq1, Wq1b, 128, 128, 4, 8);
  swz_kernel<<<(6*8*64 + 255)/256, 256, 0, stream>>>(Wn1, Wn1b, 192, 128, 6, 8);
  swz_kernel<<<(4*4*64 + 255)/256, 256, 0, stream>>>(Wn2, Wn2b, 128, 64, 4, 4);
  hist_kernel<<<(N_EDGES + 255)/256, 256, 0, stream>>>(ei, cursor);
  scan_kernel<<<1, 1024, 0, stream>>>(cursor, offs);
  scatter_kernel<<<(N_EDGES + 255)/256, 256, 0, stream>>>(ei, cursor, rc2);

  edge_kernel<<<N_EDGES/128, 256, 0, stream>>>(
      h, coord, quat, rc2, We1b, We2b, Wc1b, Wq1b,
      be1, be2, bc1, wc2, bq1, Wq2, bq2, agg32, transS, tanS, cnt);

  float* out_h = (float*)d_out;
  float* out_c = out_h + (size_t)N_NODES*64;
  float* out_q = out_c + (size_t)N_NODES*3;
  node_kernel<<<(N_NODES + 63)/64, 256, 0, stream>>>(
      h, coord, quat, aggb, transS, tanS, cnt, Wn1b, Wn2b, bn1, bn2,
      out_h, out_c, out_q);
}

// Round 10
// 477.195 us; speedup vs baseline: 12.0086x; 1.0987x over previous
//
#include <hip/hip_runtime.h>
#include <hip/hip_bf16.h>
#include <math.h>

// FEGCL_46127948759594 — E(3)-equivariant GCL on MI355X.
// R10: prep consolidation (6 swz + hist -> one prep1 kernel; 11 -> 6
// dispatches), 2-wave edge blocks (22KB LDS -> 7 blocks/CU, 14 waves/CU),
// readlane row-broadcast in column reduce (kills 32 dependent ds_bpermutes).

#define N_NODES 50000
#define N_EDGES 800000
#define ASTR 172   // A/H/F row stride in shorts
#define NSTR 204   // node A stride

typedef __attribute__((ext_vector_type(4))) float f32x4;
typedef __attribute__((ext_vector_type(8))) short bf16x8;
typedef __attribute__((ext_vector_type(4))) unsigned short u16x4;
typedef __attribute__((ext_vector_type(8))) unsigned short u16x8;

static __device__ __forceinline__ unsigned short f2bf(float f) {
  return __builtin_bit_cast(unsigned short, __float2bfloat16(f));
}
static __device__ __forceinline__ float bf2f(unsigned short s) {
  unsigned int u = ((unsigned int)s) << 16;
  return __builtin_bit_cast(float, u);
}
static __device__ __forceinline__ float silu_f(float x) {
  return x * __builtin_amdgcn_rcpf(1.0f + __expf(-x));
}
static __device__ __forceinline__ void atomic_pk_add_bf16(unsigned int* addr,
                                                          float lo, float hi) {
  const unsigned int pk = ((unsigned int)f2bf(hi) << 16) | (unsigned int)f2bf(lo);
  asm volatile("global_atomic_pk_add_bf16 %0, %1, off"
               :: "v"((unsigned long long)(uintptr_t)addr), "v"(pk)
               : "memory");
}

// ---------------------------------------------------------------- prep ----
static __device__ __forceinline__ void swz_do(const float* __restrict__ src,
                                              unsigned short* __restrict__ dst,
                                              int K, int NOUT, int NCT, int idx) {
  int lane = idx & 63, blk = idx >> 6;
  int ct = blk % NCT, kt = blk / NCT;
  int col = ct * 16 + (lane & 15);
  int kb = kt * 32 + (lane >> 4) * 8;
  u16x8 o;
  #pragma unroll
  for (int j = 0; j < 8; ++j) {
    int k = kb + j;
    o[j] = (k < K) ? f2bf(src[(size_t)k * NOUT + col]) : (unsigned short)0;
  }
  *(u16x8*)(dst + (size_t)idx * 8) = o;
}

// blocks 0..49: weight swizzles; blocks 50..3174: edge-row histogram.
__global__ __launch_bounds__(256) void prep1_kernel(
    const float* __restrict__ We1, const float* __restrict__ We2,
    const float* __restrict__ Wc1, const float* __restrict__ Wq1,
    const float* __restrict__ Wn1, const float* __restrict__ Wn2,
    unsigned short* __restrict__ We1b, unsigned short* __restrict__ We2b,
    unsigned short* __restrict__ Wc1b, unsigned short* __restrict__ Wq1b,
    unsigned short* __restrict__ Wn1b, unsigned short* __restrict__ Wn2b,
    const int* __restrict__ ei, int* __restrict__ cursor)
{
  const int b = blockIdx.x, t = threadIdx.x;
  if (b >= 50) {
    const int e = (b - 50) * 256 + t;
    if (e < N_EDGES) atomicAdd(&cursor[ei[e]], 1);
    return;
  }
  if (b < 10)       swz_do(We1, We1b, 136, 128, 8, b*256 + t);          // 2560
  else if (b < 18)  swz_do(We2, We2b, 128, 128, 8, (b-10)*256 + t);     // 2048
  else if (b < 26)  swz_do(Wc1, Wc1b, 128, 128, 8, (b-18)*256 + t);
  else if (b < 34)  swz_do(Wq1, Wq1b, 128, 128, 8, (b-26)*256 + t);
  else if (b < 46) { int i = (b-34)*256 + t; if (i < 3072) swz_do(Wn1, Wn1b, 192, 128, 8, i); }
  else              swz_do(Wn2, Wn2b, 128, 64, 4, (b-46)*256 + t);      // 1024
}

__global__ void scan_kernel(int* __restrict__ cursor) {
  __shared__ int s[1024];
  const int t = threadIdx.x;
  const int C = 49;
  const int base = t * C;
  int sum = 0;
  for (int i = 0; i < C; ++i) {
    int n = base + i;
    if (n < N_NODES) sum += cursor[n];
  }
  s[t] = sum;
  __syncthreads();
  for (int d = 1; d < 1024; d <<= 1) {
    int v = (t >= d) ? s[t - d] : 0;
    __syncthreads();
    s[t] += v;
    __syncthreads();
  }
  int run = s[t] - sum;
  for (int i = 0; i < C; ++i) {
    int n = base + i;
    if (n < N_NODES) {
      int d = cursor[n];
      cursor[n] = run;
      run += d;
    }
  }
}

__global__ void scatter_kernel(const int* __restrict__ ei, int* __restrict__ cursor,
                               int2* __restrict__ rc2) {
  int e = blockIdx.x * blockDim.x + threadIdx.x;
  if (e < N_EDGES) {
    int r = ei[e];
    int pos = atomicAdd(&cursor[r], 1);
    int2 v; v.x = r; v.y = ei[N_EDGES + e];
    rc2[pos] = v;
  }
}

// Dual-group weights-as-A GEMM (R9-proven): one weight fragment, two MFMAs.
template <int KT, int NCT>
static __device__ __forceinline__ void mmW2(const unsigned short* __restrict__ a0,
                                            const unsigned short* __restrict__ a1,
                                            int lk,
                                            const unsigned short* __restrict__ Wb,
                                            int lane, f32x4* acc0, f32x4* acc1) {
  const f32x4 zero = {0.f, 0.f, 0.f, 0.f};
  #pragma unroll
  for (int ct = 0; ct < NCT; ++ct) { acc0[ct] = zero; acc1[ct] = zero; }
  __builtin_amdgcn_s_setprio(1);
  #pragma unroll
  for (int kt = 0; kt < KT; ++kt) {
    bf16x8 x0 = *(const bf16x8*)(a0 + kt*32 + lk*8);
    bf16x8 x1 = *(const bf16x8*)(a1 + kt*32 + lk*8);
    const u16x8* bb = (const u16x8*)Wb + (size_t)(kt*NCT)*64 + lane;
    #pragma unroll
    for (int ct = 0; ct < NCT; ++ct) {
      bf16x8 w = *(const bf16x8*)(bb + (size_t)ct*64);
      acc0[ct] = __builtin_amdgcn_mfma_f32_16x16x32_bf16(w, x0, acc0[ct], 0, 0, 0);
      acc1[ct] = __builtin_amdgcn_mfma_f32_16x16x32_bf16(w, x1, acc1[ct], 0, 0, 0);
    }
  }
  __builtin_amdgcn_s_setprio(0);
}

// ---------------------------------------------------------------- edge ----
// 128 threads = 2 waves; 64 edges/block; wave wv owns rows wv*32..wv*32+31.
__global__ __launch_bounds__(128, 3) void edge_kernel(
    const float* __restrict__ h,
    const float* __restrict__ coord, const float* __restrict__ quat,
    const int2* __restrict__ rc2,
    const unsigned short* __restrict__ We1b, const unsigned short* __restrict__ We2b,
    const unsigned short* __restrict__ Wc1b, const unsigned short* __restrict__ Wq1b,
    const float* __restrict__ be1, const float* __restrict__ be2,
    const float* __restrict__ bc1, const float* __restrict__ wc2,
    const float* __restrict__ bq1, const float* __restrict__ Wq2,
    const float* __restrict__ bq2,
    unsigned int* __restrict__ agg32, float* __restrict__ transS,
    float* __restrict__ tanS, float* __restrict__ cnt)
{
  __shared__ __align__(16) unsigned short AF[64 * ASTR];  // 22016 B -> 7 blk/CU

  const int tid = threadIdx.x;
  const int wv = tid >> 6, lane = tid & 63;
  const int lr = lane & 15, lk = lane >> 4;
  const int row0 = wv*32 + lr, row1 = row0 + 16;

  // XCD-chunked bijective swizzle, nb=12500: q=1562, rem=4.
  const int xcd = blockIdx.x & 7, idx = blockIdx.x >> 3;
  const int q = 1562, rem = 4;
  const int bid = (xcd < rem ? xcd*(q+1) : rem*(q+1) + (xcd-rem)*q) + idx;
  const int e0 = bid * 64;

  const int2 p0v = rc2[e0 + row0];
  const int2 p1v = rc2[e0 + row1];
  const int r0 = p0v.x, c0 = p0v.y, r1 = p1v.x, c1 = p1v.y;

  // ---- h staging
  {
    const float* hs0 = h + (size_t)(lk < 2 ? r0 : c0) * 64 + (lk & 1) * 32;
    const float* hs1 = h + (size_t)(lk < 2 ? r1 : c1) * 64 + (lk & 1) * 32;
    const int cb = lk * 32;
    #pragma unroll
    for (int j = 0; j < 32; j += 4) {
      f32x4 v0 = *(const f32x4*)(hs0 + j);
      f32x4 v1 = *(const f32x4*)(hs1 + j);
      u16x4 q0, q1;
      #pragma unroll
      for (int i = 0; i < 4; ++i) { q0[i] = f2bf(v0[i]); q1[i] = f2bf(v1[i]); }
      *(u16x4*)&AF[row0*ASTR + cb + j] = q0;
      *(u16x4*)&AF[row1*ASTR + cb + j] = q1;
    }
  }
  const float cdx0 = coord[r0*3+0] - coord[c0*3+0];
  const float cdy0 = coord[r0*3+1] - coord[c0*3+1];
  const float cdz0 = coord[r0*3+2] - coord[c0*3+2];
  const float cdx1 = coord[r1*3+0] - coord[c1*3+0];
  const float cdy1 = coord[r1*3+1] - coord[c1*3+1];
  const float cdz1 = coord[r1*3+2] - coord[c1*3+2];
  if (lk < 2) {
    const int gr = lk ? r1 : r0, gc = lk ? c1 : c0, grow = lk ? row1 : row0;
    const float gx = lk ? cdx1 : cdx0, gy = lk ? cdy1 : cdy0, gz = lk ? cdz1 : cdz0;
    const float radial = gx*gx + gy*gy + gz*gz;
    const float nrm = sqrtf(radial) + 1e-8f;
    const f32x4 qr4 = *(const f32x4*)&quat[gr*4];
    const f32x4 qc4 = *(const f32x4*)&quat[gc*4];
    const float qix = -qr4[0], qiy = -qr4[1], qiz = -qr4[2], qiw = qr4[3];
    const float qcx = qc4[0], qcy = qc4[1], qcz = qc4[2], qcw = qc4[3];
    const float qpx = qiw*qcx + qix*qcw + qiy*qcz - qiz*qcy;
    const float qpy = qiw*qcy - qix*qcz + qiy*qcw + qiz*qcx;
    const float qpz = qiw*qcz + qix*qcy - qiy*qcx + qiz*qcw;
    const float qpw = qiw*qcw - qix*qcx - qiy*qcy - qiz*qcz;
    const float rinv = __builtin_amdgcn_rcpf(nrm);
    const float vx = gx*rinv, vy = gy*rinv, vz = gz*rinv;
    const float tx = 2.f*(qiy*vz - qiz*vy);
    const float ty = 2.f*(qiz*vx - qix*vz);
    const float tz = 2.f*(qix*vy - qiy*vx);
    const float ux = -(vx + qiw*tx + (qiy*tz - qiz*ty));
    const float uy = -(vy + qiw*ty + (qiz*tx - qix*tz));
    const float uz = -(vz + qiw*tz + (qix*ty - qiy*tx));
    u16x4 f0, f1;
    f0[0] = f2bf(radial); f0[1] = f2bf(qpx); f0[2] = f2bf(qpy); f0[3] = f2bf(qpz);
    f1[0] = f2bf(qpw);    f1[1] = f2bf(ux);  f1[2] = f2bf(uy);  f1[3] = f2bf(uz);
    *(u16x4*)&AF[grow*ASTR + 128] = f0;
    *(u16x4*)&AF[grow*ASTR + 132] = f1;
    const u16x4 z4 = {0, 0, 0, 0};
    #pragma unroll
    for (int j = 136; j < 160; j += 4) *(u16x4*)&AF[grow*ASTR + j] = z4;
  }

  f32x4 acc0[8], acc1[8];

  // ---- GEMM1: silu(ein @ We1 + be1) -> H (in place)
  mmW2<5,8>(AF + row0*ASTR, AF + row1*ASTR, lk, We1b, lane, acc0, acc1);
  #pragma unroll
  for (int ct = 0; ct < 8; ++ct) {
    const int ocb = ct*16 + lk*4;
    const f32x4 b4 = *(const f32x4*)&be1[ocb];
    u16x4 k0, k1;
    #pragma unroll
    for (int i = 0; i < 4; ++i) {
      k0[i] = f2bf(silu_f(acc0[ct][i] + b4[i]));
      k1[i] = f2bf(silu_f(acc1[ct][i] + b4[i]));
    }
    *(u16x4*)&AF[row0*ASTR + ocb] = k0;
    *(u16x4*)&AF[row1*ASTR + ocb] = k1;
  }

  // ---- GEMM2: silu(H @ We2 + be2) -> F (in place)
  mmW2<4,8>(AF + row0*ASTR, AF + row1*ASTR, lk, We2b, lane, acc0, acc1);
  #pragma unroll
  for (int ct = 0; ct < 8; ++ct) {
    const int ocb = ct*16 + lk*4;
    const f32x4 b4 = *(const f32x4*)&be2[ocb];
    u16x4 k0, k1;
    #pragma unroll
    for (int i = 0; i < 4; ++i) {
      k0[i] = f2bf(silu_f(acc0[ct][i] + b4[i]));
      k1[i] = f2bf(silu_f(acc1[ct][i] + b4[i]));
    }
    *(u16x4*)&AF[row0*ASTR + ocb] = k0;
    *(u16x4*)&AF[row1*ASTR + ocb] = k1;
  }

  // ---- GEMM3: (silu(F @ Wc1 + bc1)) . wc2
  float pcs0 = 0.f, pcs1 = 0.f;
  mmW2<4,8>(AF + row0*ASTR, AF + row1*ASTR, lk, Wc1b, lane, acc0, acc1);
  #pragma unroll
  for (int ct = 0; ct < 8; ++ct) {
    const int ocb = ct*16 + lk*4;
    const f32x4 b4 = *(const f32x4*)&bc1[ocb];
    const f32x4 w4 = *(const f32x4*)&wc2[ocb];
    #pragma unroll
    for (int i = 0; i < 4; ++i) {
      pcs0 += silu_f(acc0[ct][i] + b4[i]) * w4[i];
      pcs1 += silu_f(acc1[ct][i] + b4[i]) * w4[i];
    }
  }
  pcs0 += __shfl_xor(pcs0, 16);  pcs0 += __shfl_xor(pcs0, 32);
  pcs1 += __shfl_xor(pcs1, 16);  pcs1 += __shfl_xor(pcs1, 32);

  // ---- GEMM4: silu(F @ Wq1 + bq1) @ Wq2
  float p00 = 0.f, p10 = 0.f, p20 = 0.f;
  float p01 = 0.f, p11 = 0.f, p21 = 0.f;
  mmW2<4,8>(AF + row0*ASTR, AF + row1*ASTR, lk, Wq1b, lane, acc0, acc1);
  #pragma unroll
  for (int ct = 0; ct < 8; ++ct) {
    const int ocb = ct*16 + lk*4;
    const f32x4 b4 = *(const f32x4*)&bq1[ocb];
    const float* wq = &Wq2[ocb*3];
    const f32x4 qa = *(const f32x4*)(wq);
    const f32x4 qb = *(const f32x4*)(wq + 4);
    const f32x4 qc = *(const f32x4*)(wq + 8);
    {
      const float v0 = silu_f(acc0[ct][0] + b4[0]);
      const float v1 = silu_f(acc0[ct][1] + b4[1]);
      const float v2 = silu_f(acc0[ct][2] + b4[2]);
      const float v3 = silu_f(acc0[ct][3] + b4[3]);
      p00 += v0*qa[0] + v1*qa[3] + v2*qb[2] + v3*qc[1];
      p10 += v0*qa[1] + v1*qb[0] + v2*qb[3] + v3*qc[2];
      p20 += v0*qa[2] + v1*qb[1] + v2*qc[0] + v3*qc[3];
    }
    {
      const float v0 = silu_f(acc1[ct][0] + b4[0]);
      const float v1 = silu_f(acc1[ct][1] + b4[1]);
      const float v2 = silu_f(acc1[ct][2] + b4[2]);
      const float v3 = silu_f(acc1[ct][3] + b4[3]);
      p01 += v0*qa[0] + v1*qa[3] + v2*qb[2] + v3*qc[1];
      p11 += v0*qa[1] + v1*qb[0] + v2*qb[3] + v3*qc[2];
      p21 += v0*qa[2] + v1*qb[1] + v2*qc[0] + v3*qc[3];
    }
  }
  p00 += __shfl_xor(p00, 16);  p00 += __shfl_xor(p00, 32);
  p10 += __shfl_xor(p10, 16);  p10 += __shfl_xor(p10, 32);
  p20 += __shfl_xor(p20, 16);  p20 += __shfl_xor(p20, 32);
  p01 += __shfl_xor(p01, 16);  p01 += __shfl_xor(p01, 32);
  p11 += __shfl_xor(p11, 16);  p11 += __shfl_xor(p11, 32);
  p21 += __shfl_xor(p21, 16);  p21 += __shfl_xor(p21, 32);

  // ---- scalar side: per-group 16-lane segmented scan, tail-lane atomics
  #pragma unroll
  for (int g = 0; g < 2; ++g) {
    const int rg = g ? r1 : r0;
    const int rUp = __shfl_up(rg, 1, 16);
    const int rDn = __shfl_down(rg, 1, 16);
    const bool head = (lr == 0) || (rUp != rg);
    const bool tail = (lr == 15) || (rDn != rg);
    float v1, v2;
    if (lk == 3) { v1 = 1.0f; v2 = 0.f; }
    else {
      const float cdj = (lk == 0) ? (g ? cdx1 : cdx0)
                      : (lk == 1) ? (g ? cdy1 : cdy0) : (g ? cdz1 : cdz0);
      const float pj  = (lk == 0) ? (g ? p01 : p00)
                      : (lk == 1) ? (g ? p11 : p10) : (g ? p21 : p20);
      v1 = cdj * (g ? pcs1 : pcs0);
      v2 = pj + bq2[lk];
    }
    int f = head ? 1 : 0;
    #pragma unroll
    for (int d = 1; d < 16; d <<= 1) {
      const float o1 = __shfl_up(v1, d, 16);
      const float o2 = __shfl_up(v2, d, 16);
      const int   of = __shfl_up(f,  d, 16);
      if (lr >= d) {
        if (!f) { v1 += o1; v2 += o2; }
        f |= of;
      }
    }
    if (tail) {
      if (lk == 3) {
        atomicAdd(&cnt[rg], v1);
      } else {
        atomicAdd(&transS[rg*3 + lk], v1);
        atomicAdd(&tanS[rg*3 + lk], v2);
      }
    }
  }

  // ---- column reduce over the wave's 32 row-sorted edges.
  // Rows are identical across lk groups -> readlane (SGPR broadcast,
  // uniform branch) instead of 32 dependent ds_bpermutes.
  {
    float rl_ = 0.f, rh_ = 0.f;
    int prev = __builtin_amdgcn_readlane(r0, 0);
    #pragma unroll
    for (int k2 = 0; k2 < 32; ++k2) {
      const int rr = (k2 < 16) ? __builtin_amdgcn_readlane(r0, k2)
                               : __builtin_amdgcn_readlane(r1, k2 - 16);
      if (rr != prev) {
        atomic_pk_add_bf16(&agg32[(size_t)prev*64 + lane], rl_, rh_);
        rl_ = 0.f; rh_ = 0.f; prev = rr;
      }
      const unsigned int u = *(const unsigned int*)&AF[(wv*32 + k2)*ASTR + 2*lane];
      rl_ += bf2f((unsigned short)(u & 0xffffu));
      rh_ += bf2f((unsigned short)(u >> 16));
    }
    atomic_pk_add_bf16(&agg32[(size_t)prev*64 + lane], rl_, rh_);
  }
}

// ---------------------------------------------------------------- node ----
__global__ __launch_bounds__(256, 4) void node_kernel(
    const float* __restrict__ h, const float* __restrict__ coord,
    const float* __restrict__ quat,
    const unsigned short* __restrict__ aggb, const float* __restrict__ transS,
    const float* __restrict__ tanS, const float* __restrict__ cnt,
    const unsigned short* __restrict__ Wn1b, const unsigned short* __restrict__ Wn2b,
    const float* __restrict__ bn1, const float* __restrict__ bn2,
    float* __restrict__ out_h, float* __restrict__ out_c, float* __restrict__ out_q)
{
  __shared__ unsigned short A_[64][NSTR];   // [h(64)|agg(128)], H in place
  const int tid = threadIdx.x;
  const int n0 = blockIdx.x * 64;

  {
    const int row = tid >> 2, sub = tid & 3;
    const int n = n0 + row;
    if (n < N_NODES) {
      if (sub < 2) {
        const float* hp = h + (size_t)n*64 + sub*32;
        #pragma unroll
        for (int j = 0; j < 32; j += 4) {
          f32x4 v = *(const f32x4*)(hp + j);
          u16x4 p;
          p[0] = f2bf(v[0]); p[1] = f2bf(v[1]); p[2] = f2bf(v[2]); p[3] = f2bf(v[3]);
          *(u16x4*)&A_[row][sub*32 + j] = p;
        }
      } else {
        const unsigned short* ap = aggb + (size_t)n*128 + (sub - 2)*64;
        #pragma unroll
        for (int j = 0; j < 64; j += 8)
          *(u16x8*)&A_[row][64 + (sub - 2)*64 + j] = *(const u16x8*)(ap + j);
      }
    } else {
      const u16x4 z4 = {0, 0, 0, 0};
      if (sub < 2) {
        #pragma unroll
        for (int j = 0; j < 32; j += 4) *(u16x4*)&A_[row][sub*32 + j] = z4;
      } else {
        #pragma unroll
        for (int j = 0; j < 64; j += 4) *(u16x4*)&A_[row][64 + (sub - 2)*64 + j] = z4;
      }
    }
  }
  __syncthreads();

  const int wv = tid >> 6, lane = tid & 63;
  const int lr = lane & 15, lk = lane >> 4;
  const int nrow = wv*16 + lr;
  f32x4 acc[8];

  {
    const f32x4 zero = {0.f, 0.f, 0.f, 0.f};
    #pragma unroll
    for (int ct = 0; ct < 8; ++ct) acc[ct] = zero;
    #pragma unroll
    for (int kt = 0; kt < 6; ++kt) {
      bf16x8 act = *(const bf16x8*)&A_[nrow][kt*32 + lk*8];
      const u16x8* bb = (const u16x8*)Wn1b + (size_t)(kt*8)*64 + lane;
      #pragma unroll
      for (int ct = 0; ct < 8; ++ct) {
        bf16x8 w = *(const bf16x8*)(bb + (size_t)ct*64);
        acc[ct] = __builtin_amdgcn_mfma_f32_16x16x32_bf16(w, act, acc[ct], 0, 0, 0);
      }
    }
  }
  #pragma unroll
  for (int ct = 0; ct < 8; ++ct) {
    const int ocb = ct*16 + lk*4;
    const f32x4 b4 = *(const f32x4*)&bn1[ocb];
    u16x4 pk;
    #pragma unroll
    for (int i = 0; i < 4; ++i) pk[i] = f2bf(silu_f(acc[ct][i] + b4[i]));
    *(u16x4*)&A_[nrow][ocb] = pk;
  }

  f32x4 acc2[4];
  {
    const f32x4 zero = {0.f, 0.f, 0.f, 0.f};
    #pragma unroll
    for (int ct = 0; ct < 4; ++ct) acc2[ct] = zero;
    #pragma unroll
    for (int kt = 0; kt < 4; ++kt) {
      bf16x8 act = *(const bf16x8*)&A_[nrow][kt*32 + lk*8];
      const u16x8* bb = (const u16x8*)Wn2b + (size_t)(kt*4)*64 + lane;
      #pragma unroll
      for (int ct = 0; ct < 4; ++ct) {
        bf16x8 w = *(const bf16x8*)(bb + (size_t)ct*64);
        acc2[ct] = __builtin_amdgcn_mfma_f32_16x16x32_bf16(w, act, acc2[ct], 0, 0, 0);
      }
    }
  }
  const int n = n0 + nrow;
  if (n < N_NODES) {
    #pragma unroll
    for (int ct = 0; ct < 4; ++ct) {
      const int ocb = ct*16 + lk*4;
      const f32x4 b4 = *(const f32x4*)&bn2[ocb];
      const f32x4 h4 = *(const f32x4*)&h[(size_t)n*64 + ocb];
      f32x4 o;
      #pragma unroll
      for (int i = 0; i < 4; ++i) o[i] = h4[i] + acc2[ct][i] + b4[i];
      *(f32x4*)&out_h[(size_t)n*64 + ocb] = o;
    }
  }

  if (tid < 64) {
    const int nn = n0 + tid;
    if (nn < N_NODES) {
      const float cm = fmaxf(cnt[nn], 1.0f);
      const float inv = 1.0f / cm;
      out_c[nn*3+0] = coord[nn*3+0] + transS[nn*3+0]*inv;
      out_c[nn*3+1] = coord[nn*3+1] + transS[nn*3+1]*inv;
      out_c[nn*3+2] = coord[nn*3+2] + transS[nn*3+2]*inv;
      const float ix = tanS[nn*3+0]*inv, iy = tanS[nn*3+1]*inv, iz = tanS[nn*3+2]*inv;
      const float rr = sqrtf(ix*ix + iy*iy + iz*iz);
      const float s = sinf(rr) / rr;
      const float rx = ix*s, ry = iy*s, rz = iz*s, rw = cosf(rr);
      const float px = quat[nn*4+0], py = quat[nn*4+1], pz = quat[nn*4+2], pw = quat[nn*4+3];
      out_q[nn*4+0] = pw*rx + px*rw + py*rz - pz*ry;
      out_q[nn*4+1] = pw*ry - px*rz + py*rw + pz*rx;
      out_q[nn*4+2] = pw*rz + px*ry - py*rx + pz*rw;
      out_q[nn*4+3] = pw*rw - px*rx - py*ry - pz*rz;
    }
  }
}

// -------------------------------------------------------------- launch ----
extern "C" void kernel_launch(void* const* d_in, const int* in_sizes, int n_in,
                              void* d_out, int out_size, void* d_ws, size_t ws_size,
                              hipStream_t stream) {
  (void)in_sizes; (void)n_in; (void)out_size; (void)ws_size;
  const float* h     = (const float*)d_in[0];
  const int*   ei    = (const int*)d_in[1];
  const float* coord = (const float*)d_in[2];
  const float* quat  = (const float*)d_in[3];
  const float* We1 = (const float*)d_in[4];  const float* be1 = (const float*)d_in[5];
  const float* We2 = (const float*)d_in[6];  const float* be2 = (const float*)d_in[7];
  const float* Wn1 = (const float*)d_in[8];  const float* bn1 = (const float*)d_in[9];
  const float* Wn2 = (const float*)d_in[10]; const float* bn2 = (const float*)d_in[11];
  const float* Wc1 = (const float*)d_in[12]; const float* bc1 = (const float*)d_in[13];
  const float* wc2 = (const float*)d_in[14];
  const float* Wq1 = (const float*)d_in[15]; const float* bq1 = (const float*)d_in[16];
  const float* Wq2 = (const float*)d_in[17]; const float* bq2 = (const float*)d_in[18];

  // Compact layout — total ~21.2 MB (< R1-proven 28 MB envelope).
  char* ws = (char*)d_ws;
  unsigned int* agg32  = (unsigned int*)(ws);           // bf16x2 [N][64]: 12,800,000
  unsigned short* aggb = (unsigned short*)(ws);         // same bytes as bf16 [N][128]
  float* transS = (float*)(ws + 12800000);              //    600,000
  float* tanS   = (float*)(ws + 13400000);              //    600,000
  float* cnt    = (float*)(ws + 14000000);              //    200,000
  int*   cursor = (int*)  (ws + 14200000);              //    200,000 (memset ends 14.4MB)
  int2*  rc2    = (int2*) (ws + 14600064);              //  6,400,000
  unsigned short* We1b = (unsigned short*)(ws + 21000064);
  unsigned short* We2b = We1b + 5*8*64*8;
  unsigned short* Wc1b = We2b + 4*8*64*8;
  unsigned short* Wq1b = Wc1b + 4*8*64*8;
  unsigned short* Wn1b = Wq1b + 4*8*64*8;
  unsigned short* Wn2b = Wn1b + 6*8*64*8;               // ends ~21.2 MB

  hipMemsetAsync(ws, 0, 14400000, stream);  // agg+transS+tanS+cnt+cursor
  prep1_kernel<<<50 + (N_EDGES + 255)/256, 256, 0, stream>>>(
      We1, We2, Wc1, Wq1, Wn1, Wn2, We1b, We2b, Wc1b, Wq1b, Wn1b, Wn2b,
      ei, cursor);
  scan_kernel<<<1, 1024, 0, stream>>>(cursor);
  scatter_kernel<<<(N_EDGES + 255)/256, 256, 0, stream>>>(ei, cursor, rc2);

  edge_kernel<<<N_EDGES/64, 128, 0, stream>>>(
      h, coord, quat, rc2, We1b, We2b, Wc1b, Wq1b,
      be1, be2, bc1, wc2, bq1, Wq2, bq2, agg32, transS, tanS, cnt);

  float* out_h = (float*)d_out;
  float* out_c = out_h + (size_t)N_NODES*64;
  float* out_q = out_c + (size_t)N_NODES*3;
  node_kernel<<<(N_NODES + 63)/64, 256, 0, stream>>>(
      h, coord, quat, aggb, transS, tanS, cnt, Wn1b, Wn2b, bn1, bn2,
      out_h, out_c, out_q);
}

// Round 11
// 459.123 us; speedup vs baseline: 12.4812x; 1.0394x over previous
//
#include <hip/hip_runtime.h>
#include <hip/hip_bf16.h>
#include <math.h>

// FEGCL_46127948759594 — E(3)-equivariant GCL on MI355X.
// R11: bias-init MFMA accumulators (C-in is free; -256 VALU adds/thread),
// bf16 h table (staging = pure u16x4 copies, h-gather bytes halved),
// mega-prep kernel (hconvert + zeroing + swz + hist in one dispatch),
// deg from cursor end-offsets (cnt buffer + lk==3 atomics deleted).

#define N_NODES 50000
#define N_EDGES 800000
#define ASTR 172   // A/H/F row stride in shorts (conflict-free, 8B-aligned)
#define NSTR 204   // node A stride

typedef __attribute__((ext_vector_type(4))) float f32x4;
typedef __attribute__((ext_vector_type(8))) short bf16x8;
typedef __attribute__((ext_vector_type(4))) unsigned short u16x4;
typedef __attribute__((ext_vector_type(8))) unsigned short u16x8;

static __device__ __forceinline__ unsigned short f2bf(float f) {
  return __builtin_bit_cast(unsigned short, __float2bfloat16(f));
}
static __device__ __forceinline__ float bf2f(unsigned short s) {
  unsigned int u = ((unsigned int)s) << 16;
  return __builtin_bit_cast(float, u);
}
static __device__ __forceinline__ float silu_f(float x) {
  return x * __builtin_amdgcn_rcpf(1.0f + __expf(-x));
}
static __device__ __forceinline__ void atomic_pk_add_bf16(unsigned int* addr,
                                                          float lo, float hi) {
  const unsigned int pk = ((unsigned int)f2bf(hi) << 16) | (unsigned int)f2bf(lo);
  asm volatile("global_atomic_pk_add_bf16 %0, %1, off"
               :: "v"((unsigned long long)(uintptr_t)addr), "v"(pk)
               : "memory");
}

// ---------------------------------------------------------------- prep ----
static __device__ __forceinline__ void swz_do(const float* __restrict__ src,
                                              unsigned short* __restrict__ dst,
                                              int K, int NOUT, int NCT, int idx) {
  int lane = idx & 63, blk = idx >> 6;
  int ct = blk % NCT, kt = blk / NCT;
  int col = ct * 16 + (lane & 15);
  int kb = kt * 32 + (lane >> 4) * 8;
  u16x8 o;
  #pragma unroll
  for (int j = 0; j < 8; ++j) {
    int k = kb + j;
    o[j] = (k < K) ? f2bf(src[(size_t)k * NOUT + col]) : (unsigned short)0;
  }
  *(u16x8*)(dst + (size_t)idx * 8) = o;
}

// blocks [0,50): swizzles; [50,1613): h->bf16; [1613,5031): zero 14MB;
// [5031,8156): edge-row histogram. cursor pre-zeroed by tiny memset.
__global__ __launch_bounds__(256) void prep1_kernel(
    const float* __restrict__ We1, const float* __restrict__ We2,
    const float* __restrict__ Wc1, const float* __restrict__ Wq1,
    const float* __restrict__ Wn1, const float* __restrict__ Wn2,
    const float* __restrict__ h,
    unsigned short* __restrict__ We1b, unsigned short* __restrict__ We2b,
    unsigned short* __restrict__ Wc1b, unsigned short* __restrict__ Wq1b,
    unsigned short* __restrict__ Wn1b, unsigned short* __restrict__ Wn2b,
    unsigned short* __restrict__ hb, uint4* __restrict__ zbase,
    const int* __restrict__ ei, int* __restrict__ cursor)
{
  const int b = blockIdx.x, t = threadIdx.x;
  if (b < 50) {
    if (b < 10)       swz_do(We1, We1b, 136, 128, 8, b*256 + t);
    else if (b < 18)  swz_do(We2, We2b, 128, 128, 8, (b-10)*256 + t);
    else if (b < 26)  swz_do(Wc1, Wc1b, 128, 128, 8, (b-18)*256 + t);
    else if (b < 34)  swz_do(Wq1, Wq1b, 128, 128, 8, (b-26)*256 + t);
    else if (b < 46) { int i = (b-34)*256 + t; if (i < 3072) swz_do(Wn1, Wn1b, 192, 128, 8, i); }
    else              swz_do(Wn2, Wn2b, 128, 64, 4, (b-46)*256 + t);
    return;
  }
  if (b < 1613) {                       // h -> bf16 table
    const int i8 = (b - 50) * 2048 + t * 8;
    if (i8 < N_NODES * 64) {
      f32x4 v0 = *(const f32x4*)(h + i8);
      f32x4 v1 = *(const f32x4*)(h + i8 + 4);
      u16x8 o;
      #pragma unroll
      for (int i = 0; i < 4; ++i) { o[i] = f2bf(v0[i]); o[i+4] = f2bf(v1[i]); }
      *(u16x8*)(hb + i8) = o;
    }
    return;
  }
  if (b < 5031) {                       // zero agg + transS + tanS (14.0 MB)
    const int i = (b - 1613) * 256 + t;
    if (i < 875000) { uint4 z; z.x = z.y = z.z = z.w = 0u; zbase[i] = z; }
    return;
  }
  const int e = (b - 5031) * 256 + t;   // histogram
  if (e < N_EDGES) atomicAdd(&cursor[ei[e]], 1);
}

__global__ void scan_kernel(int* __restrict__ cursor) {
  __shared__ int s[1024];
  const int t = threadIdx.x;
  const int C = 49;
  const int base = t * C;
  int sum = 0;
  for (int i = 0; i < C; ++i) {
    int n = base + i;
    if (n < N_NODES) sum += cursor[n];
  }
  s[t] = sum;
  __syncthreads();
  for (int d = 1; d < 1024; d <<= 1) {
    int v = (t >= d) ? s[t - d] : 0;
    __syncthreads();
    s[t] += v;
    __syncthreads();
  }
  int run = s[t] - sum;
  for (int i = 0; i < C; ++i) {
    int n = base + i;
    if (n < N_NODES) {
      int d = cursor[n];
      cursor[n] = run;
      run += d;
    }
  }
}

__global__ void scatter_kernel(const int* __restrict__ ei, int* __restrict__ cursor,
                               int2* __restrict__ rc2) {
  int e = blockIdx.x * blockDim.x + threadIdx.x;
  if (e < N_EDGES) {
    int r = ei[e];
    int pos = atomicAdd(&cursor[r], 1);
    int2 v; v.x = r; v.y = ei[N_EDGES + e];
    rc2[pos] = v;
  }
}

// Dual-group weights-as-A GEMM, bias-initialized accumulators (C-in free).
template <int KT, int NCT>
static __device__ __forceinline__ void mmW2(const unsigned short* __restrict__ a0,
                                            const unsigned short* __restrict__ a1,
                                            int lk,
                                            const unsigned short* __restrict__ Wb,
                                            const float* __restrict__ bias,
                                            int lane, f32x4* acc0, f32x4* acc1) {
  #pragma unroll
  for (int ct = 0; ct < NCT; ++ct) {
    const f32x4 b = *(const f32x4*)&bias[ct*16 + lk*4];
    acc0[ct] = b; acc1[ct] = b;
  }
  __builtin_amdgcn_s_setprio(1);
  #pragma unroll
  for (int kt = 0; kt < KT; ++kt) {
    bf16x8 x0 = *(const bf16x8*)(a0 + kt*32 + lk*8);
    bf16x8 x1 = *(const bf16x8*)(a1 + kt*32 + lk*8);
    const u16x8* bb = (const u16x8*)Wb + (size_t)(kt*NCT)*64 + lane;
    #pragma unroll
    for (int ct = 0; ct < NCT; ++ct) {
      bf16x8 w = *(const bf16x8*)(bb + (size_t)ct*64);
      acc0[ct] = __builtin_amdgcn_mfma_f32_16x16x32_bf16(w, x0, acc0[ct], 0, 0, 0);
      acc1[ct] = __builtin_amdgcn_mfma_f32_16x16x32_bf16(w, x1, acc1[ct], 0, 0, 0);
    }
  }
  __builtin_amdgcn_s_setprio(0);
}

// ---------------------------------------------------------------- edge ----
// 128 threads = 2 waves; 64 edges/block; wave wv owns rows wv*32..wv*32+31.
__global__ __launch_bounds__(128, 3) void edge_kernel(
    const unsigned short* __restrict__ hb,
    const float* __restrict__ coord, const float* __restrict__ quat,
    const int2* __restrict__ rc2,
    const unsigned short* __restrict__ We1b, const unsigned short* __restrict__ We2b,
    const unsigned short* __restrict__ Wc1b, const unsigned short* __restrict__ Wq1b,
    const float* __restrict__ be1, const float* __restrict__ be2,
    const float* __restrict__ bc1, const float* __restrict__ wc2,
    const float* __restrict__ bq1, const float* __restrict__ Wq2,
    const float* __restrict__ bq2,
    unsigned int* __restrict__ agg32, float* __restrict__ transS,
    float* __restrict__ tanS)
{
  __shared__ __align__(16) unsigned short AF[64 * ASTR];  // 22016 B

  const int tid = threadIdx.x;
  const int wv = tid >> 6, lane = tid & 63;
  const int lr = lane & 15, lk = lane >> 4;
  const int row0 = wv*32 + lr, row1 = row0 + 16;

  // XCD-chunked bijective swizzle, nb=12500: q=1562, rem=4.
  const int xcd = blockIdx.x & 7, idx = blockIdx.x >> 3;
  const int q = 1562, rem = 4;
  const int bid = (xcd < rem ? xcd*(q+1) : rem*(q+1) + (xcd-rem)*q) + idx;
  const int e0 = bid * 64;

  const int2 p0v = rc2[e0 + row0];
  const int2 p1v = rc2[e0 + row1];
  const int r0 = p0v.x, c0 = p0v.y, r1 = p1v.x, c1 = p1v.y;

  // ---- h staging: pure bf16 copies from hb (no cvt)
  {
    const unsigned short* hs0 = hb + (size_t)(lk < 2 ? r0 : c0) * 64 + (lk & 1) * 32;
    const unsigned short* hs1 = hb + (size_t)(lk < 2 ? r1 : c1) * 64 + (lk & 1) * 32;
    const int cb = lk * 32;
    #pragma unroll
    for (int j = 0; j < 32; j += 4) {
      *(u16x4*)&AF[row0*ASTR + cb + j] = *(const u16x4*)(hs0 + j);
      *(u16x4*)&AF[row1*ASTR + cb + j] = *(const u16x4*)(hs1 + j);
    }
  }
  const float cdx0 = coord[r0*3+0] - coord[c0*3+0];
  const float cdy0 = coord[r0*3+1] - coord[c0*3+1];
  const float cdz0 = coord[r0*3+2] - coord[c0*3+2];
  const float cdx1 = coord[r1*3+0] - coord[c1*3+0];
  const float cdy1 = coord[r1*3+1] - coord[c1*3+1];
  const float cdz1 = coord[r1*3+2] - coord[c1*3+2];
  if (lk < 2) {
    const int gr = lk ? r1 : r0, gc = lk ? c1 : c0, grow = lk ? row1 : row0;
    const float gx = lk ? cdx1 : cdx0, gy = lk ? cdy1 : cdy0, gz = lk ? cdz1 : cdz0;
    const float radial = gx*gx + gy*gy + gz*gz;
    const float nrm = sqrtf(radial) + 1e-8f;
    const f32x4 qr4 = *(const f32x4*)&quat[gr*4];
    const f32x4 qc4 = *(const f32x4*)&quat[gc*4];
    const float qix = -qr4[0], qiy = -qr4[1], qiz = -qr4[2], qiw = qr4[3];
    const float qcx = qc4[0], qcy = qc4[1], qcz = qc4[2], qcw = qc4[3];
    const float qpx = qiw*qcx + qix*qcw + qiy*qcz - qiz*qcy;
    const float qpy = qiw*qcy - qix*qcz + qiy*qcw + qiz*qcx;
    const float qpz = qiw*qcz + qix*qcy - qiy*qcx + qiz*qcw;
    const float qpw = qiw*qcw - qix*qcx - qiy*qcy - qiz*qcz;
    const float rinv = __builtin_amdgcn_rcpf(nrm);
    const float vx = gx*rinv, vy = gy*rinv, vz = gz*rinv;
    const float tx = 2.f*(qiy*vz - qiz*vy);
    const float ty = 2.f*(qiz*vx - qix*vz);
    const float tz = 2.f*(qix*vy - qiy*vx);
    const float ux = -(vx + qiw*tx + (qiy*tz - qiz*ty));
    const float uy = -(vy + qiw*ty + (qiz*tx - qix*tz));
    const float uz = -(vz + qiw*tz + (qix*ty - qiy*tx));
    u16x4 f0, f1;
    f0[0] = f2bf(radial); f0[1] = f2bf(qpx); f0[2] = f2bf(qpy); f0[3] = f2bf(qpz);
    f1[0] = f2bf(qpw);    f1[1] = f2bf(ux);  f1[2] = f2bf(uy);  f1[3] = f2bf(uz);
    *(u16x4*)&AF[grow*ASTR + 128] = f0;
    *(u16x4*)&AF[grow*ASTR + 132] = f1;
    const u16x4 z4 = {0, 0, 0, 0};
    #pragma unroll
    for (int j = 136; j < 160; j += 4) *(u16x4*)&AF[grow*ASTR + j] = z4;
  }

  f32x4 acc0[8], acc1[8];

  // ---- GEMM1: silu(ein @ We1 + be1) -> H (in place; bias in acc init)
  mmW2<5,8>(AF + row0*ASTR, AF + row1*ASTR, lk, We1b, be1, lane, acc0, acc1);
  #pragma unroll
  for (int ct = 0; ct < 8; ++ct) {
    const int ocb = ct*16 + lk*4;
    u16x4 k0, k1;
    #pragma unroll
    for (int i = 0; i < 4; ++i) {
      k0[i] = f2bf(silu_f(acc0[ct][i]));
      k1[i] = f2bf(silu_f(acc1[ct][i]));
    }
    *(u16x4*)&AF[row0*ASTR + ocb] = k0;
    *(u16x4*)&AF[row1*ASTR + ocb] = k1;
  }

  // ---- GEMM2: silu(H @ We2 + be2) -> F (in place)
  mmW2<4,8>(AF + row0*ASTR, AF + row1*ASTR, lk, We2b, be2, lane, acc0, acc1);
  #pragma unroll
  for (int ct = 0; ct < 8; ++ct) {
    const int ocb = ct*16 + lk*4;
    u16x4 k0, k1;
    #pragma unroll
    for (int i = 0; i < 4; ++i) {
      k0[i] = f2bf(silu_f(acc0[ct][i]));
      k1[i] = f2bf(silu_f(acc1[ct][i]));
    }
    *(u16x4*)&AF[row0*ASTR + ocb] = k0;
    *(u16x4*)&AF[row1*ASTR + ocb] = k1;
  }

  // ---- GEMM3: (silu(F @ Wc1 + bc1)) . wc2
  float pcs0 = 0.f, pcs1 = 0.f;
  mmW2<4,8>(AF + row0*ASTR, AF + row1*ASTR, lk, Wc1b, bc1, lane, acc0, acc1);
  #pragma unroll
  for (int ct = 0; ct < 8; ++ct) {
    const int ocb = ct*16 + lk*4;
    const f32x4 w4 = *(const f32x4*)&wc2[ocb];
    #pragma unroll
    for (int i = 0; i < 4; ++i) {
      pcs0 += silu_f(acc0[ct][i]) * w4[i];
      pcs1 += silu_f(acc1[ct][i]) * w4[i];
    }
  }
  pcs0 += __shfl_xor(pcs0, 16);  pcs0 += __shfl_xor(pcs0, 32);
  pcs1 += __shfl_xor(pcs1, 16);  pcs1 += __shfl_xor(pcs1, 32);

  // ---- GEMM4: silu(F @ Wq1 + bq1) @ Wq2
  float p00 = 0.f, p10 = 0.f, p20 = 0.f;
  float p01 = 0.f, p11 = 0.f, p21 = 0.f;
  mmW2<4,8>(AF + row0*ASTR, AF + row1*ASTR, lk, Wq1b, bq1, lane, acc0, acc1);
  #pragma unroll
  for (int ct = 0; ct < 8; ++ct) {
    const int ocb = ct*16 + lk*4;
    const float* wq = &Wq2[ocb*3];
    const f32x4 qa = *(const f32x4*)(wq);
    const f32x4 qb = *(const f32x4*)(wq + 4);
    const f32x4 qc = *(const f32x4*)(wq + 8);
    {
      const float v0 = silu_f(acc0[ct][0]);
      const float v1 = silu_f(acc0[ct][1]);
      const float v2 = silu_f(acc0[ct][2]);
      const float v3 = silu_f(acc0[ct][3]);
      p00 += v0*qa[0] + v1*qa[3] + v2*qb[2] + v3*qc[1];
      p10 += v0*qa[1] + v1*qb[0] + v2*qb[3] + v3*qc[2];
      p20 += v0*qa[2] + v1*qb[1] + v2*qc[0] + v3*qc[3];
    }
    {
      const float v0 = silu_f(acc1[ct][0]);
      const float v1 = silu_f(acc1[ct][1]);
      const float v2 = silu_f(acc1[ct][2]);
      const float v3 = silu_f(acc1[ct][3]);
      p01 += v0*qa[0] + v1*qa[3] + v2*qb[2] + v3*qc[1];
      p11 += v0*qa[1] + v1*qb[0] + v2*qb[3] + v3*qc[2];
      p21 += v0*qa[2] + v1*qb[1] + v2*qc[0] + v3*qc[3];
    }
  }
  p00 += __shfl_xor(p00, 16);  p00 += __shfl_xor(p00, 32);
  p10 += __shfl_xor(p10, 16);  p10 += __shfl_xor(p10, 32);
  p20 += __shfl_xor(p20, 16);  p20 += __shfl_xor(p20, 32);
  p01 += __shfl_xor(p01, 16);  p01 += __shfl_xor(p01, 32);
  p11 += __shfl_xor(p11, 16);  p11 += __shfl_xor(p11, 32);
  p21 += __shfl_xor(p21, 16);  p21 += __shfl_xor(p21, 32);

  // ---- scalar side: 16-lane segmented scans on lk groups 0..2 only
  if (lk < 3) {
    #pragma unroll
    for (int g = 0; g < 2; ++g) {
      const int rg = g ? r1 : r0;
      const int rUp = __shfl_up(rg, 1, 16);
      const int rDn = __shfl_down(rg, 1, 16);
      const bool head = (lr == 0) || (rUp != rg);
      const bool tail = (lr == 15) || (rDn != rg);
      const float cdj = (lk == 0) ? (g ? cdx1 : cdx0)
                      : (lk == 1) ? (g ? cdy1 : cdy0) : (g ? cdz1 : cdz0);
      const float pj  = (lk == 0) ? (g ? p01 : p00)
                      : (lk == 1) ? (g ? p11 : p10) : (g ? p21 : p20);
      float v1 = cdj * (g ? pcs1 : pcs0);
      float v2 = pj + bq2[lk];
      int f = head ? 1 : 0;
      #pragma unroll
      for (int d = 1; d < 16; d <<= 1) {
        const float o1 = __shfl_up(v1, d, 16);
        const float o2 = __shfl_up(v2, d, 16);
        const int   of = __shfl_up(f,  d, 16);
        if (lr >= d) {
          if (!f) { v1 += o1; v2 += o2; }
          f |= of;
        }
      }
      if (tail) {
        atomicAdd(&transS[rg*3 + lk], v1);
        atomicAdd(&tanS[rg*3 + lk], v2);
      }
    }
  }

  // ---- column reduce over the wave's 32 row-sorted edges (readlane + pk_add)
  {
    float rl_ = 0.f, rh_ = 0.f;
    int prev = __builtin_amdgcn_readlane(r0, 0);
    #pragma unroll
    for (int k2 = 0; k2 < 32; ++k2) {
      const int rr = (k2 < 16) ? __builtin_amdgcn_readlane(r0, k2)
                               : __builtin_amdgcn_readlane(r1, k2 - 16);
      if (rr != prev) {
        atomic_pk_add_bf16(&agg32[(size_t)prev*64 + lane], rl_, rh_);
        rl_ = 0.f; rh_ = 0.f; prev = rr;
      }
      const unsigned int u = *(const unsigned int*)&AF[(wv*32 + k2)*ASTR + 2*lane];
      rl_ += bf2f((unsigned short)(u & 0xffffu));
      rh_ += bf2f((unsigned short)(u >> 16));
    }
    atomic_pk_add_bf16(&agg32[(size_t)prev*64 + lane], rl_, rh_);
  }
}

// ---------------------------------------------------------------- node ----
__global__ __launch_bounds__(256, 4) void node_kernel(
    const float* __restrict__ h, const unsigned short* __restrict__ hb,
    const float* __restrict__ coord, const float* __restrict__ quat,
    const unsigned short* __restrict__ aggb, const float* __restrict__ transS,
    const float* __restrict__ tanS, const int* __restrict__ cursor,
    const unsigned short* __restrict__ Wn1b, const unsigned short* __restrict__ Wn2b,
    const float* __restrict__ bn1, const float* __restrict__ bn2,
    float* __restrict__ out_h, float* __restrict__ out_c, float* __restrict__ out_q)
{
  __shared__ unsigned short A_[64][NSTR];   // [h(64)|agg(128)], H in place
  const int tid = threadIdx.x;
  const int n0 = blockIdx.x * 64;

  {
    const int row = tid >> 2, sub = tid & 3;
    const int n = n0 + row;
    if (n < N_NODES) {
      if (sub < 2) {
        const unsigned short* hp = hb + (size_t)n*64 + sub*32;
        #pragma unroll
        for (int j = 0; j < 32; j += 4)
          *(u16x4*)&A_[row][sub*32 + j] = *(const u16x4*)(hp + j);
      } else {
        const unsigned short* ap = aggb + (size_t)n*128 + (sub - 2)*64;
        #pragma unroll
        for (int j = 0; j < 64; j += 8)
          *(u16x8*)&A_[row][64 + (sub - 2)*64 + j] = *(const u16x8*)(ap + j);
      }
    } else {
      const u16x4 z4 = {0, 0, 0, 0};
      if (sub < 2) {
        #pragma unroll
        for (int j = 0; j < 32; j += 4) *(u16x4*)&A_[row][sub*32 + j] = z4;
      } else {
        #pragma unroll
        for (int j = 0; j < 64; j += 4) *(u16x4*)&A_[row][64 + (sub - 2)*64 + j] = z4;
      }
    }
  }
  __syncthreads();

  const int wv = tid >> 6, lane = tid & 63;
  const int lr = lane & 15, lk = lane >> 4;
  const int nrow = wv*16 + lr;
  f32x4 acc[8];

  {
    #pragma unroll
    for (int ct = 0; ct < 8; ++ct)
      acc[ct] = *(const f32x4*)&bn1[ct*16 + lk*4];
    #pragma unroll
    for (int kt = 0; kt < 6; ++kt) {
      bf16x8 act = *(const bf16x8*)&A_[nrow][kt*32 + lk*8];
      const u16x8* bb = (const u16x8*)Wn1b + (size_t)(kt*8)*64 + lane;
      #pragma unroll
      for (int ct = 0; ct < 8; ++ct) {
        bf16x8 w = *(const bf16x8*)(bb + (size_t)ct*64);
        acc[ct] = __builtin_amdgcn_mfma_f32_16x16x32_bf16(w, act, acc[ct], 0, 0, 0);
      }
    }
  }
  #pragma unroll
  for (int ct = 0; ct < 8; ++ct) {
    const int ocb = ct*16 + lk*4;
    u16x4 pk;
    #pragma unroll
    for (int i = 0; i < 4; ++i) pk[i] = f2bf(silu_f(acc[ct][i]));
    *(u16x4*)&A_[nrow][ocb] = pk;
  }

  f32x4 acc2[4];
  {
    #pragma unroll
    for (int ct = 0; ct < 4; ++ct)
      acc2[ct] = *(const f32x4*)&bn2[ct*16 + lk*4];
    #pragma unroll
    for (int kt = 0; kt < 4; ++kt) {
      bf16x8 act = *(const bf16x8*)&A_[nrow][kt*32 + lk*8];
      const u16x8* bb = (const u16x8*)Wn2b + (size_t)(kt*4)*64 + lane;
      #pragma unroll
      for (int ct = 0; ct < 4; ++ct) {
        bf16x8 w = *(const bf16x8*)(bb + (size_t)ct*64);
        acc2[ct] = __builtin_amdgcn_mfma_f32_16x16x32_bf16(w, act, acc2[ct], 0, 0, 0);
      }
    }
  }
  const int n = n0 + nrow;
  if (n < N_NODES) {
    #pragma unroll
    for (int ct = 0; ct < 4; ++ct) {
      const int ocb = ct*16 + lk*4;
      const f32x4 h4 = *(const f32x4*)&h[(size_t)n*64 + ocb];
      f32x4 o;
      #pragma unroll
      for (int i = 0; i < 4; ++i) o[i] = h4[i] + acc2[ct][i];
      *(f32x4*)&out_h[(size_t)n*64 + ocb] = o;
    }
  }

  if (tid < 64) {
    const int nn = n0 + tid;
    if (nn < N_NODES) {
      const int deg = cursor[nn] - (nn ? cursor[nn-1] : 0);
      const float inv = 1.0f / fmaxf((float)deg, 1.0f);
      out_c[nn*3+0] = coord[nn*3+0] + transS[nn*3+0]*inv;
      out_c[nn*3+1] = coord[nn*3+1] + transS[nn*3+1]*inv;
      out_c[nn*3+2] = coord[nn*3+2] + transS[nn*3+2]*inv;
      const float ix = tanS[nn*3+0]*inv, iy = tanS[nn*3+1]*inv, iz = tanS[nn*3+2]*inv;
      const float rr = sqrtf(ix*ix + iy*iy + iz*iz);
      const float s = sinf(rr) / rr;
      const float rx = ix*s, ry = iy*s, rz = iz*s, rw = cosf(rr);
      const float px = quat[nn*4+0], py = quat[nn*4+1], pz = quat[nn*4+2], pw = quat[nn*4+3];
      out_q[nn*4+0] = pw*rx + px*rw + py*rz - pz*ry;
      out_q[nn*4+1] = pw*ry - px*rz + py*rw + pz*rx;
      out_q[nn*4+2] = pw*rz + px*ry - py*rx + pz*rw;
      out_q[nn*4+3] = pw*rw - px*rx - py*ry - pz*rz;
    }
  }
}

// -------------------------------------------------------------- launch ----
extern "C" void kernel_launch(void* const* d_in, const int* in_sizes, int n_in,
                              void* d_out, int out_size, void* d_ws, size_t ws_size,
                              hipStream_t stream) {
  (void)in_sizes; (void)n_in; (void)out_size; (void)ws_size;
  const float* h     = (const float*)d_in[0];
  const int*   ei    = (const int*)d_in[1];
  const float* coord = (const float*)d_in[2];
  const float* quat  = (const float*)d_in[3];
  const float* We1 = (const float*)d_in[4];  const float* be1 = (const float*)d_in[5];
  const float* We2 = (const float*)d_in[6];  const float* be2 = (const float*)d_in[7];
  const float* Wn1 = (const float*)d_in[8];  const float* bn1 = (const float*)d_in[9];
  const float* Wn2 = (const float*)d_in[10]; const float* bn2 = (const float*)d_in[11];
  const float* Wc1 = (const float*)d_in[12]; const float* bc1 = (const float*)d_in[13];
  const float* wc2 = (const float*)d_in[14];
  const float* Wq1 = (const float*)d_in[15]; const float* bq1 = (const float*)d_in[16];
  const float* Wq2 = (const float*)d_in[17]; const float* bq2 = (const float*)d_in[18];

  // Layout — total ~27.6 MB (R1-proven 28.0 MB envelope).
  char* ws = (char*)d_ws;
  unsigned int* agg32  = (unsigned int*)(ws);           // bf16x2 [N][64]: 12,800,000
  unsigned short* aggb = (unsigned short*)(ws);         // same bytes as bf16 [N][128]
  float* transS = (float*)(ws + 12800000);              //    600,000
  float* tanS   = (float*)(ws + 13400000);              //    600,000
  int*   cursor = (int*)  (ws + 14200000);              //    200,000
  int2*  rc2    = (int2*) (ws + 14600064);              //  6,400,000
  unsigned short* We1b = (unsigned short*)(ws + 21000064);
  unsigned short* We2b = We1b + 5*8*64*8;
  unsigned short* Wc1b = We2b + 4*8*64*8;
  unsigned short* Wq1b = Wc1b + 4*8*64*8;
  unsigned short* Wn1b = Wq1b + 4*8*64*8;
  unsigned short* Wn2b = Wn1b + 6*8*64*8;               // ends 21,204,864
  unsigned short* hb   = (unsigned short*)(ws + 21204864);  // 6,400,000 -> 27.6MB

  hipMemsetAsync(cursor, 0, 200000, stream);            // cursor only
  prep1_kernel<<<8156, 256, 0, stream>>>(
      We1, We2, Wc1, Wq1, Wn1, Wn2, h,
      We1b, We2b, Wc1b, Wq1b, Wn1b, Wn2b, hb, (uint4*)ws, ei, cursor);
  scan_kernel<<<1, 1024, 0, stream>>>(cursor);
  scatter_kernel<<<(N_EDGES + 255)/256, 256, 0, stream>>>(ei, cursor, rc2);

  edge_kernel<<<N_EDGES/64, 128, 0, stream>>>(
      hb, coord, quat, rc2, We1b, We2b, Wc1b, Wq1b,
      be1, be2, bc1, wc2, bq1, Wq2, bq2, agg32, transS, tanS);

  float* out_h = (float*)d_out;
  float* out_c = out_h + (size_t)N_NODES*64;
  float* out_q = out_c + (size_t)N_NODES*3;
  node_kernel<<<(N_NODES + 63)/64, 256, 0, stream>>>(
      h, hb, coord, quat, aggb, transS, tanS, cursor, Wn1b, Wn2b, bn1, bn2,
      out_h, out_c, out_q);
}